// Round 9
// baseline (3392.936 us; speedup 1.0000x reference)
//
#include <hip/hip_runtime.h>
#include <hip/hip_bf16.h>
#include <math.h>

#define B_   128
#define P_   196
#define ENC_ 2048
#define A_   512
#define H_   512
#define E_   512
#define V_   10000
#define T_   20
#define NDF_ 2560   /* [W_dec rows 0..511 | W_fbeta rows 512..2559] */
#define XK_  3072   /* Wcat K: E + ENC + H */
#define GK_  2560   /* per-step gates K: ENC + H (emb part precomputed) */
#define NBLK_ 256   /* coop grid */

typedef __attribute__((ext_vector_type(8))) short bf16x8;
typedef __attribute__((ext_vector_type(4))) short bf16x4;
typedef __attribute__((ext_vector_type(2))) short bf16x2;
typedef __attribute__((ext_vector_type(4))) float f32x4;

__device__ __forceinline__ float sigmoidf_(float x) { return 1.0f / (1.0f + expf(-x)); }

__device__ __forceinline__ short f2bf(float f) {
    unsigned u = __float_as_uint(f);
    u += 0x7fffu + ((u >> 16) & 1u);
    return (short)(u >> 16);
}
__device__ __forceinline__ float bf2f(short s) {
    return __uint_as_float(((unsigned)(unsigned short)s) << 16);
}
__device__ __forceinline__ void gload_lds16(const void* g, void* l) {
    __builtin_amdgcn_global_load_lds(
        (const __attribute__((address_space(1))) void*)g,
        (__attribute__((address_space(3))) void*)l, 16, 0, 0);
}

#define BM 128
#define BN 64
#define BK 64

// shared MFMA inner compute: 64-K slab from As/Bs (XOR-swizzled layout)
#define COMPUTE64(ASP, BSP, CUR)                                               \
    _Pragma("unroll")                                                          \
    for (int kk = 0; kk < BK; kk += 32) {                                      \
        const int kb = (kk >> 3) + (lane >> 4);                                \
        bf16x8 av[4], bv[2];                                                   \
        _Pragma("unroll")                                                      \
        for (int i = 0; i < 4; i++) {                                          \
            int rr = wr * 64 + i * 16 + (lane & 15);                           \
            av[i] = *(const bf16x8*)&(ASP)[(CUR) * (BM * BK) + rr * BK         \
                    + ((kb ^ (rr & 7)) << 3)];                                 \
        }                                                                      \
        _Pragma("unroll")                                                      \
        for (int j = 0; j < 2; j++) {                                          \
            int cc = wc * 32 + j * 16 + (lane & 15);                           \
            bv[j] = *(const bf16x8*)&(BSP)[(CUR) * (BN * BK) + cc * BK         \
                    + ((kb ^ (cc & 7)) << 3)];                                 \
        }                                                                      \
        _Pragma("unroll")                                                      \
        for (int i = 0; i < 4; i++)                                            \
            _Pragma("unroll")                                                  \
            for (int j = 0; j < 2; j++)                                        \
                acc[i][j] = __builtin_amdgcn_mfma_f32_16x16x32_bf16(           \
                    av[i], bv[j], acc[i][j], 0, 0, 0);                         \
    }

// ---------------------------------------------------------------------------
// Generic GEMM: C[M,N] = A_bf16[M,K] @ B_bf16[N,K]^T + bias[N]
// mode 0: plain store; mode 1: pred remap (length-masked); mode 2: init split.
// ---------------------------------------------------------------------------
__global__ __launch_bounds__(256) void gemm_bf(
    const short* __restrict__ A, const short* __restrict__ Bw,
    float* __restrict__ Cf, short* __restrict__ Cb,
    const float* __restrict__ bias,
    int N, int K, int lda, int ldb, int ldc,
    int mtiles, int ntiles, int mode,
    const int* __restrict__ lengths)
{
    __shared__ __attribute__((aligned(16))) short As[2][BM * BK];
    __shared__ __attribute__((aligned(16))) short Bs[2][BN * BK];
    int pm, pn;
    if (mtiles == 1) { pm = 0; pn = blockIdx.x; }
    else {
        int xcd = blockIdx.x & 7, s = blockIdx.x >> 3;
        pn = s % ntiles;
        pm = (s / ntiles) * 8 + xcd;
        if (pm >= mtiles) return;
    }
    const int bm = pm * BM, bn = pn * BN;
    const int tid = threadIdx.x, w = tid >> 6, lane = tid & 63;
    const int wr = w >> 1, wc = w & 1;
    const int lr8 = lane >> 3, lk = lane & 7;

    f32x4 zero4 = {0.f, 0.f, 0.f, 0.f};
    f32x4 acc[4][2];
    #pragma unroll
    for (int i = 0; i < 4; i++)
        #pragma unroll
        for (int j = 0; j < 2; j++) acc[i][j] = zero4;

#define STAGE(buf, k0) {                                                        \
    _Pragma("unroll")                                                           \
    for (int i = 0; i < 4; i++) {                                               \
        int row0 = w * 32 + i * 8; int row = row0 + lr8;                        \
        gload_lds16(A + (size_t)(bm + row) * lda + (k0)                         \
                    + ((lk ^ (row & 7)) << 3), &As[buf][row0 * BK]);            \
    }                                                                           \
    _Pragma("unroll")                                                           \
    for (int i = 0; i < 2; i++) {                                               \
        int row0 = w * 16 + i * 8; int row = row0 + lr8;                        \
        int gn = bn + row; if (gn > N - 1) gn = N - 1;                          \
        gload_lds16(Bw + (size_t)gn * ldb + (k0)                                \
                    + ((lk ^ (row & 7)) << 3), &Bs[buf][row0 * BK]);            \
    } }

    STAGE(0, 0);
    __syncthreads();
    int cur = 0;
    for (int k0 = 0; k0 < K; k0 += BK) {
        if (k0 + BK < K) STAGE(cur ^ 1, k0 + BK);
        COMPUTE64(&As[0][0], &Bs[0][0], cur);
        __syncthreads();
        cur ^= 1;
    }
#undef STAGE

    const int lr = lane >> 4, lc = lane & 15;
    #pragma unroll
    for (int i = 0; i < 4; i++) {
        #pragma unroll
        for (int r = 0; r < 4; r++) {
            int row = bm + wr * 64 + i * 16 + lr * 4 + r;
            #pragma unroll
            for (int j = 0; j < 2; j++) {
                int col = bn + wc * 32 + j * 16 + lc;
                if (col >= N) continue;
                float v = acc[i][j][r] + bias[col];
                if (mode == 1) {
                    int tt = row >> 7, bb = row & 127;
                    float rs = (tt < lengths[bb] - 1) ? 1.0f : 0.0f;
                    Cf[(size_t)bb * T_ * V_ + (size_t)tt * V_ + col] = v * rs;
                } else if (mode == 2) {
                    if (col < H_) Cb[(size_t)row * H_ + col] = f2bf(v);
                    else          Cf[(size_t)row * H_ + (col - H_)] = v;
                } else if (Cb) {
                    Cb[(size_t)row * ldc + col] = f2bf(v);
                } else {
                    Cf[(size_t)row * ldc + col] = v;
                }
            }
        }
    }
}

// ---------------------------------------------------------------------------
// Persistent cooperative loop kernel. 256 blocks x 512 threads (1 per CU).
// Per step: A) attf GEMM (blk<40)  B) e+softmax+ctx (all)  C) gates+LSTM (blk<32)
// Grid barrier: leader-only release/acquire agent-scope atomics (NO per-thread
// threadfence — that was R5's 3x regression).
// ---------------------------------------------------------------------------
__device__ __forceinline__ void gbar(unsigned* cnt, unsigned target) {
    __syncthreads();
    if (threadIdx.x == 0) {
        __hip_atomic_fetch_add(cnt, 1u, __ATOMIC_RELEASE, __HIP_MEMORY_SCOPE_AGENT);
        while (__hip_atomic_fetch_add(cnt, 0u, __ATOMIC_RELAXED, __HIP_MEMORY_SCOPE_AGENT) < target)
            __builtin_amdgcn_s_sleep(8);
        (void)__hip_atomic_load(cnt, __ATOMIC_ACQUIRE, __HIP_MEMORY_SCOPE_AGENT);
    }
    __syncthreads();
}

__global__ __launch_bounds__(512) void loop_kernel(
    const short* __restrict__ att1_bf, const short* __restrict__ enc_bf,
    const short* __restrict__ Wdf, const float* __restrict__ bdf,
    const float* __restrict__ wfull, const short* __restrict__ Wcat,
    const float* __restrict__ gates_pre,
    short* __restrict__ hbufs, float* __restrict__ cbuf,
    short* __restrict__ hn_all, float* __restrict__ attf,
    short* __restrict__ ctxbuf, const int* __restrict__ lengths,
    unsigned* __restrict__ cnt)
{
    __shared__ __attribute__((aligned(16))) char smem[49152];
    const int blk = blockIdx.x, tid = threadIdx.x;
    const int lane = tid & 63;
    const bool act = tid < 256;            // 4-wave GEMM phases
    const int w4 = (tid >> 6) & 3;
    const int wr = w4 >> 1, wc = w4 & 1;
    const int lr8 = lane >> 3, lk = lane & 7;
    const int lr = lane >> 4, lc = lane & 15;
    unsigned bar = 0;

#define STAGE_A(buf, k0) if (act) {                                             \
    _Pragma("unroll")                                                           \
    for (int i = 0; i < 4; i++) {                                               \
        int row0 = w4 * 32 + i * 8; int row = row0 + lr8;                       \
        gload_lds16(hcur + (size_t)row * H_ + (k0) + ((lk ^ (row & 7)) << 3),   \
                    &As0[(buf) * (BM * BK) + row0 * BK]);                       \
    }                                                                           \
    _Pragma("unroll")                                                           \
    for (int i = 0; i < 2; i++) {                                               \
        int row0 = w4 * 16 + i * 8; int row = row0 + lr8;                       \
        gload_lds16(Wdf + (size_t)(bn + row) * H_ + (k0)                        \
                    + ((lk ^ (row & 7)) << 3),                                  \
                    &Bs0[(buf) * (BN * BK) + row0 * BK]);                       \
    } }

#define STAGE_C(buf, k0) if (act) {                                             \
    const short* Ap; int Al, kk0;                                               \
    if ((k0) < ENC_) { Ap = ctxbuf; Al = ENC_; kk0 = (k0); }                    \
    else             { Ap = hcur;   Al = H_;   kk0 = (k0) - ENC_; }             \
    _Pragma("unroll")                                                           \
    for (int i = 0; i < 4; i++) {                                               \
        int row0 = w4 * 32 + i * 8; int row = row0 + lr8;                       \
        gload_lds16(Ap + (size_t)row * Al + kk0 + ((lk ^ (row & 7)) << 3),      \
                    &As0[(buf) * (BM * BK) + row0 * BK]);                       \
    }                                                                           \
    _Pragma("unroll")                                                           \
    for (int i = 0; i < 2; i++) {                                               \
        int row0 = w4 * 16 + i * 8; int row = row0 + lr8;                       \
        gload_lds16(Wcat + (size_t)(bn + row) * XK_ + E_ + (k0)                 \
                    + ((lk ^ (row & 7)) << 3),                                  \
                    &Bs0[(buf) * (BN * BK) + row0 * BK]);                       \
    } }

    for (int t = 0; t < T_; t++) {
        const short* hcur = hbufs + (size_t)(t & 1) * B_ * H_;
        short* hnxt = hbufs + (size_t)((t & 1) ^ 1) * B_ * H_;

        // ---------------- Phase A: attf = h @ Wdf^T + bdf  [128 x 2560, K=512]
        if (blk < NDF_ / BN) {
            short* As0 = (short*)smem;
            short* Bs0 = (short*)(smem + 32768);
            const int bn = blk * BN;
            f32x4 acc[4][2];
            if (act) {
                f32x4 z = {0.f, 0.f, 0.f, 0.f};
                #pragma unroll
                for (int i = 0; i < 4; i++)
                    #pragma unroll
                    for (int j = 0; j < 2; j++) acc[i][j] = z;
            }
            STAGE_A(0, 0);
            __syncthreads();
            int cur = 0;
            for (int k0 = 0; k0 < H_; k0 += BK) {
                if (k0 + BK < H_) STAGE_A(cur ^ 1, k0 + BK);
                if (act) { COMPUTE64(As0, Bs0, cur); }
                __syncthreads();
                cur ^= 1;
            }
            if (act) {
                #pragma unroll
                for (int i = 0; i < 4; i++)
                    #pragma unroll
                    for (int r = 0; r < 4; r++) {
                        int row = wr * 64 + i * 16 + lr * 4 + r;
                        #pragma unroll
                        for (int j = 0; j < 2; j++) {
                            int col = bn + wc * 32 + j * 16 + lc;
                            attf[(size_t)row * NDF_ + col] = acc[i][j][r] + bdf[col];
                        }
                    }
            }
        }
        bar++; gbar(cnt, bar * NBLK_);

        // ---------------- Phase B: e + softmax + context (b = blk>>1, half = blk&1)
        {
            const int b = blk >> 1, half = blk & 1;
            if (t < lengths[b] - 1) {
                float* es  = (float*)smem;
                float* red = es + 256;
                float* al  = red + 256;
                float* st  = al + 256;
                float a2v[8], wv8[8];
                const float* a2 = attf + (size_t)b * NDF_;
                #pragma unroll
                for (int i = 0; i < 8; i++) {
                    a2v[i] = a2[lane * 8 + i];
                    wv8[i] = wfull[lane * 8 + i];
                }
                for (int row = tid >> 6; row < P_; row += 8) {
                    bf16x8 a1 = *(const bf16x8*)(att1_bf + ((size_t)b * P_ + row) * A_ + lane * 8);
                    float s = 0.0f;
                    #pragma unroll
                    for (int i = 0; i < 8; i++) {
                        float v = bf2f(a1[i]) + a2v[i];
                        s += fmaxf(v, 0.0f) * wv8[i];
                    }
                    #pragma unroll
                    for (int off = 32; off > 0; off >>= 1) s += __shfl_down(s, off, 64);
                    if (lane == 0) es[row] = s;
                }
                __syncthreads();
                float v = (tid < P_) ? es[tid] : -1e30f;
                if (tid < 256) red[tid] = v;
                __syncthreads();
                for (int rs = 128; rs > 0; rs >>= 1) {
                    if (tid < rs) red[tid] = fmaxf(red[tid], red[tid + rs]);
                    __syncthreads();
                }
                if (tid == 0) st[0] = red[0];
                __syncthreads();
                float ex = (tid < P_) ? expf(v - st[0]) : 0.0f;
                if (tid < 256) red[tid] = ex;
                __syncthreads();
                for (int rs = 128; rs > 0; rs >>= 1) {
                    if (tid < rs) red[tid] += red[tid + rs];
                    __syncthreads();
                }
                if (tid == 0) st[1] = red[0];
                __syncthreads();
                if (tid < P_) al[tid] = ex / st[1];
                __syncthreads();

                const int c0 = half * 1024 + tid * 2;
                const short* eb = enc_bf + (size_t)b * P_ * ENC_ + c0;
                float s0 = 0, s1 = 0;
                for (int p = 0; p < P_; p++) {
                    bf16x2 ev = *(const bf16x2*)(eb + (size_t)p * ENC_);
                    float a = al[p];
                    s0 += a * bf2f(ev[0]); s1 += a * bf2f(ev[1]);
                }
                const float* fb = attf + (size_t)b * NDF_ + A_;
                bf16x2 o;
                o[0] = f2bf(sigmoidf_(fb[c0 + 0]) * s0);
                o[1] = f2bf(sigmoidf_(fb[c0 + 1]) * s1);
                *(bf16x2*)(ctxbuf + (size_t)b * ENC_ + c0) = o;
            }
        }
        bar++; gbar(cnt, bar * NBLK_);

        // ---------------- Phase C: gates [128 x 2048, K=2560] + LSTM
        if (blk < (4 * H_) / BN) {
            short* As0 = (short*)smem;
            short* Bs0 = (short*)(smem + 32768);
            short* hn_t = hn_all + (size_t)t * B_ * H_;
            const int bn = blk * BN;
            const float* gpre = gates_pre + (size_t)t * B_ * 4 * H_;
            f32x4 acc[4][2];
            if (act) {
                f32x4 z = {0.f, 0.f, 0.f, 0.f};
                #pragma unroll
                for (int i = 0; i < 4; i++)
                    #pragma unroll
                    for (int j = 0; j < 2; j++) acc[i][j] = z;
            }
            STAGE_C(0, 0);
            __syncthreads();
            int cur = 0;
            for (int k0 = 0; k0 < GK_; k0 += BK) {
                if (k0 + BK < GK_) STAGE_C(cur ^ 1, k0 + BK);
                if (act) { COMPUTE64(As0, Bs0, cur); }
                __syncthreads();
                cur ^= 1;
            }
            float* gl = (float*)smem;     // 128*68*4 = 34816 B
            if (act) {
                #pragma unroll
                for (int i = 0; i < 4; i++)
                    #pragma unroll
                    for (int r = 0; r < 4; r++) {
                        int row = wr * 64 + i * 16 + lr * 4 + r;
                        #pragma unroll
                        for (int j = 0; j < 2; j++) {
                            int col = wc * 32 + j * 16 + lc;
                            gl[row * 68 + col] = acc[i][j][r] + gpre[(size_t)row * (4 * H_) + bn + col];
                        }
                    }
            }
            __syncthreads();
            if (act) {
                #pragma unroll
                for (int q = 0; q < 8; q++) {
                    int id  = tid * 8 + q;
                    int row = id >> 4;
                    int j   = id & 15;
                    int jg  = (bn >> 2) + j;
                    float i_ = sigmoidf_(gl[row * 68 + 4 * j + 0]);
                    float f_ = sigmoidf_(gl[row * 68 + 4 * j + 1]);
                    float g_ = tanhf    (gl[row * 68 + 4 * j + 2]);
                    float o_ = sigmoidf_(gl[row * 68 + 4 * j + 3]);
                    float cn = f_ * cbuf[row * H_ + jg] + i_ * g_;
                    float hv = o_ * tanhf(cn);
                    hn_t[row * H_ + jg] = f2bf(hv);
                    bool m = t < lengths[row] - 1;
                    if (m) cbuf[row * H_ + jg] = cn;
                    hnxt[row * H_ + jg] = m ? f2bf(hv) : hcur[row * H_ + jg];
                }
            }
        }
        bar++; gbar(cnt, bar * NBLK_);
    }
#undef STAGE_A
#undef STAGE_C
}

// ---------------------------------------------------------------------------
// Fallback per-step kernels (used only if cooperative launch fails)
// ---------------------------------------------------------------------------
__global__ __launch_bounds__(512) void esmctx_kernel(
    const short* __restrict__ att1_bf, const float* __restrict__ attf,
    const float* __restrict__ wfull, const short* __restrict__ enc_bf,
    short* __restrict__ ctxbuf, const int* __restrict__ lengths, int t)
{
    __shared__ float es[P_];
    __shared__ float red[256];
    __shared__ float al[P_];
    __shared__ float sm, ss;
    const int b = blockIdx.y, half = blockIdx.x;
    if (t >= lengths[b] - 1) return;
    const int tid = threadIdx.x, wv = tid >> 6, lane = tid & 63;

    float a2v[8], wv8[8];
    const float* a2 = attf + (size_t)b * NDF_;
    #pragma unroll
    for (int i = 0; i < 8; i++) {
        a2v[i] = a2[lane * 8 + i];
        wv8[i] = wfull[lane * 8 + i];
    }
    for (int row = wv; row < P_; row += 8) {
        bf16x8 a1 = *(const bf16x8*)(att1_bf + ((size_t)b * P_ + row) * A_ + lane * 8);
        float s = 0.0f;
        #pragma unroll
        for (int i = 0; i < 8; i++) {
            float v = bf2f(a1[i]) + a2v[i];
            s += fmaxf(v, 0.0f) * wv8[i];
        }
        #pragma unroll
        for (int off = 32; off > 0; off >>= 1) s += __shfl_down(s, off, 64);
        if (lane == 0) es[row] = s;
    }
    __syncthreads();
    float v = (tid < P_) ? es[tid] : -1e30f;
    if (tid < 256) red[tid] = v;
    __syncthreads();
    for (int rs = 128; rs > 0; rs >>= 1) {
        if (tid < rs) red[tid] = fmaxf(red[tid], red[tid + rs]);
        __syncthreads();
    }
    if (tid == 0) sm = red[0];
    __syncthreads();
    float ex = (tid < P_) ? expf(v - sm) : 0.0f;
    if (tid < 256) red[tid] = ex;
    __syncthreads();
    for (int rs = 128; rs > 0; rs >>= 1) {
        if (tid < rs) red[tid] += red[tid + rs];
        __syncthreads();
    }
    if (tid == 0) ss = red[0];
    __syncthreads();
    if (tid < P_) al[tid] = ex / ss;
    __syncthreads();

    const int c0 = half * 1024 + tid * 2;
    const short* eb = enc_bf + (size_t)b * P_ * ENC_ + c0;
    float s0 = 0, s1 = 0;
    for (int p = 0; p < P_; p++) {
        bf16x2 ev = *(const bf16x2*)(eb + (size_t)p * ENC_);
        float a = al[p];
        s0 += a * bf2f(ev[0]); s1 += a * bf2f(ev[1]);
    }
    const float* fb = attf + (size_t)b * NDF_ + A_;
    bf16x2 o;
    o[0] = f2bf(sigmoidf_(fb[c0 + 0]) * s0);
    o[1] = f2bf(sigmoidf_(fb[c0 + 1]) * s1);
    *(bf16x2*)(ctxbuf + (size_t)b * ENC_ + c0) = o;
}

__global__ __launch_bounds__(256) void gates_lstm(
    const short* __restrict__ ctxbuf, const short* __restrict__ hcur,
    short* __restrict__ hnxt,
    const short* __restrict__ Wcat, const float* __restrict__ gpre,
    float* __restrict__ cbuf, short* __restrict__ hn_t,
    const int* __restrict__ lengths, int t)
{
    __shared__ __attribute__((aligned(16))) char smem[49152];
    short* As0 = (short*)smem;
    short* Bs0 = (short*)(smem + 32768);
    const int bn = blockIdx.x * BN;
    const int tid = threadIdx.x, w = tid >> 6, lane = tid & 63;
    const int wr = w >> 1, wc = w & 1;
    const int lr8 = lane >> 3, lk = lane & 7;

    f32x4 zero4 = {0.f, 0.f, 0.f, 0.f};
    f32x4 acc[4][2];
    #pragma unroll
    for (int i = 0; i < 4; i++)
        #pragma unroll
        for (int j = 0; j < 2; j++) acc[i][j] = zero4;

#define STAGE_G(buf, k0) {                                                      \
    const short* Ap; int Al, kk0;                                               \
    if ((k0) < ENC_) { Ap = ctxbuf; Al = ENC_; kk0 = (k0); }                    \
    else             { Ap = hcur;   Al = H_;   kk0 = (k0) - ENC_; }             \
    _Pragma("unroll")                                                           \
    for (int i = 0; i < 4; i++) {                                               \
        int row0 = w * 32 + i * 8; int row = row0 + lr8;                        \
        gload_lds16(Ap + (size_t)row * Al + kk0 + ((lk ^ (row & 7)) << 3),      \
                    &As0[(buf) * (BM * BK) + row0 * BK]);                       \
    }                                                                           \
    _Pragma("unroll")                                                           \
    for (int i = 0; i < 2; i++) {                                               \
        int row0 = w * 16 + i * 8; int row = row0 + lr8;                        \
        gload_lds16(Wcat + (size_t)(bn + row) * XK_ + E_ + (k0)                 \
                    + ((lk ^ (row & 7)) << 3),                                  \
                    &Bs0[(buf) * (BN * BK) + row0 * BK]);                       \
    } }

    STAGE_G(0, 0);
    __syncthreads();
    int cur = 0;
    for (int k0 = 0; k0 < GK_; k0 += BK) {
        if (k0 + BK < GK_) STAGE_G(cur ^ 1, k0 + BK);
        COMPUTE64(As0, Bs0, cur);
        __syncthreads();
        cur ^= 1;
    }
#undef STAGE_G

    float* gl = (float*)smem;
    const int lr = lane >> 4, lc = lane & 15;
    #pragma unroll
    for (int i = 0; i < 4; i++)
        #pragma unroll
        for (int r = 0; r < 4; r++) {
            int row = wr * 64 + i * 16 + lr * 4 + r;
            #pragma unroll
            for (int j = 0; j < 2; j++) {
                int col = wc * 32 + j * 16 + lc;
                gl[row * 68 + col] = acc[i][j][r] + gpre[(size_t)row * (4 * H_) + bn + col];
            }
        }
    __syncthreads();
    #pragma unroll
    for (int q = 0; q < 8; q++) {
        int id  = tid * 8 + q;
        int row = id >> 4;
        int j   = id & 15;
        int jg  = (bn >> 2) + j;
        float i_ = sigmoidf_(gl[row * 68 + 4 * j + 0]);
        float f_ = sigmoidf_(gl[row * 68 + 4 * j + 1]);
        float g_ = tanhf    (gl[row * 68 + 4 * j + 2]);
        float o_ = sigmoidf_(gl[row * 68 + 4 * j + 3]);
        float cn = f_ * cbuf[row * H_ + jg] + i_ * g_;
        float hv = o_ * tanhf(cn);
        hn_t[row * H_ + jg] = f2bf(hv);
        bool m = t < lengths[row] - 1;
        if (m) cbuf[row * H_ + jg] = cn;
        hnxt[row * H_ + jg] = m ? f2bf(hv) : hcur[row * H_ + jg];
    }
}

// ---------------------------------------------------------------------------
// Fused enc cast + mean: grid (2, B), 256 threads, 4 cols/thread.
// ---------------------------------------------------------------------------
__global__ __launch_bounds__(256) void castenc_mean(const float* __restrict__ enc,
                                                    short* __restrict__ enc_bf,
                                                    short* __restrict__ meanE_bf)
{
    const int b = blockIdx.y;
    const int c0 = blockIdx.x * 1024 + threadIdx.x * 4;
    const float* src = enc + (size_t)b * P_ * ENC_ + c0;
    short* dst = enc_bf + (size_t)b * P_ * ENC_ + c0;
    float s0 = 0, s1 = 0, s2 = 0, s3 = 0;
    for (int p = 0; p < P_; p++) {
        float4 f = *(const float4*)(src + (size_t)p * ENC_);
        bf16x4 v;
        v[0] = f2bf(f.x); v[1] = f2bf(f.y); v[2] = f2bf(f.z); v[3] = f2bf(f.w);
        *(bf16x4*)(dst + (size_t)p * ENC_) = v;
        s0 += f.x; s1 += f.y; s2 += f.z; s3 += f.w;
    }
    const float inv = 1.0f / (float)P_;
    bf16x4 m;
    m[0] = f2bf(s0 * inv); m[1] = f2bf(s1 * inv);
    m[2] = f2bf(s2 * inv); m[3] = f2bf(s3 * inv);
    *(bf16x4*)(meanE_bf + (size_t)b * ENC_ + c0) = m;
}

// ---------------------------------------------------------------------------
// Mega-prep: all weight casts/concats/biases/embedding in ONE kernel.
// ---------------------------------------------------------------------------
#define PB0 1024               /* W_enc cast: 512*2048          */
#define PB1 (PB0 + 2048)       /* Winit cat : 1024*2048         */
#define PB2 (PB1 + 5000)       /* W_fc cast : 10000*512         */
#define PB3 (PB2 + 1280)       /* Wdf cat   : 2560*512          */
#define PB4 (PB3 + 6144)       /* Wcat      : 2048*3072         */
#define PB5 (PB4 + 1280)       /* emb_all   : 20*128*512        */
#define PB6 (PB5 + 3)          /* bdf 2560                      */
#define PB7 (PB6 + 2)          /* bcat 2048                     */
#define PB8 (PB7 + 1)          /* binit 1024 + counter zero     */

__device__ __forceinline__ void cast4(const float* __restrict__ in,
                                      short* __restrict__ out, int i4) {
    float4 f = *(const float4*)(in + i4);
    bf16x4 v;
    v[0] = f2bf(f.x); v[1] = f2bf(f.y); v[2] = f2bf(f.z); v[3] = f2bf(f.w);
    *(bf16x4*)(out + i4) = v;
}
__device__ __forceinline__ void cast4p(const float* __restrict__ src,
                                       short* __restrict__ out, int i4) {
    float4 f = *(const float4*)src;
    bf16x4 v;
    v[0] = f2bf(f.x); v[1] = f2bf(f.y); v[2] = f2bf(f.z); v[3] = f2bf(f.w);
    *(bf16x4*)(out + i4) = v;
}

__global__ __launch_bounds__(256) void prep_kernel(
    const float* __restrict__ W_enc,    const float* __restrict__ W_init_h,
    const float* __restrict__ W_init_c, const float* __restrict__ W_fc,
    const float* __restrict__ W_dec,    const float* __restrict__ W_fbeta,
    const float* __restrict__ W_ih,     const float* __restrict__ W_hh,
    const int*   __restrict__ captions, const float* __restrict__ emb_tab,
    const float* __restrict__ b_dec,    const float* __restrict__ b_fbeta,
    const float* __restrict__ b_ih,     const float* __restrict__ b_hh,
    const float* __restrict__ b_init_h, const float* __restrict__ b_init_c,
    short* __restrict__ Wenc_bf,  short* __restrict__ Winit_bf,
    short* __restrict__ Wfc_bf,   short* __restrict__ Wdf_bf,
    short* __restrict__ Wcat_bf,  short* __restrict__ emb_all,
    float* __restrict__ bdf,      float* __restrict__ bcat,
    float* __restrict__ binit,    unsigned* __restrict__ cnt)
{
    const int blk = blockIdx.x, tid = threadIdx.x;
    if (blk < PB0) {
        cast4(W_enc, Wenc_bf, blk * 1024 + tid * 4);
    } else if (blk < PB1) {
        int i4 = (blk - PB0) * 1024 + tid * 4;
        int n = i4 >> 11, k = i4 & 2047;
        const float* src = (n < H_) ? W_init_h + (size_t)n * ENC_ + k
                                    : W_init_c + (size_t)(n - H_) * ENC_ + k;
        cast4p(src, Winit_bf, i4);
    } else if (blk < PB2) {
        cast4(W_fc, Wfc_bf, (blk - PB1) * 1024 + tid * 4);
    } else if (blk < PB3) {
        int i4 = (blk - PB2) * 1024 + tid * 4;
        int n = i4 >> 9, k = i4 & 511;
        const float* src = (n < A_) ? W_dec + (size_t)n * H_ + k
                                    : W_fbeta + (size_t)(n - A_) * H_ + k;
        cast4p(src, Wdf_bf, i4);
    } else if (blk < PB4) {
        int i4 = (blk - PB3) * 1024 + tid * 4;
        int n = i4 / XK_, k = i4 - n * XK_;
        int srow = (n & 3) * H_ + (n >> 2);
        const float* src = (k < E_ + ENC_) ? W_ih + (size_t)srow * (E_ + ENC_) + k
                                           : W_hh + (size_t)srow * H_ + (k - (E_ + ENC_));
        cast4p(src, Wcat_bf, i4);
    } else if (blk < PB5) {
        int i4 = (blk - PB4) * 1024 + tid * 4;
        int col = i4 & 511;
        int bt  = i4 >> 9;
        int b   = bt & 127;
        int tt  = bt >> 7;
        int tok = captions[b * (T_ + 1) + tt];
        cast4p(emb_tab + (size_t)tok * E_ + col, emb_all, i4);
    } else if (blk < PB6) {
        int j = (blk - PB5) * 1024 + tid * 4;
        #pragma unroll
        for (int q = 0; q < 4; q++, j++)
            if (j < NDF_) bdf[j] = (j < A_) ? b_dec[j] : b_fbeta[j - A_];
    } else if (blk < PB7) {
        int j = (blk - PB6) * 1024 + tid * 4;
        #pragma unroll
        for (int q = 0; q < 4; q++, j++) {
            int srow = (j & 3) * H_ + (j >> 2);
            bcat[j] = b_ih[srow] + b_hh[srow];
        }
    } else {
        int j = tid * 4;
        #pragma unroll
        for (int q = 0; q < 4; q++, j++)
            binit[j] = (j < H_) ? b_init_h[j] : b_init_c[j - H_];
        if (tid == 0)
            __hip_atomic_store(cnt, 0u, __ATOMIC_RELEASE, __HIP_MEMORY_SCOPE_AGENT);
    }
}

extern "C" void kernel_launch(void* const* d_in, const int* in_sizes, int n_in,
                              void* d_out, int out_size, void* d_ws, size_t ws_size,
                              hipStream_t stream)
{
    const float* enc      = (const float*)d_in[0];
    const int*   captions = (const int*)  d_in[1];
    const int*   lengths  = (const int*)  d_in[2];
    const float* W_enc    = (const float*)d_in[3];
    const float* b_enc    = (const float*)d_in[4];
    const float* W_dec    = (const float*)d_in[5];
    const float* b_dec    = (const float*)d_in[6];
    const float* w_full   = (const float*)d_in[7];
    const float* emb_tab  = (const float*)d_in[9];
    const float* W_ih     = (const float*)d_in[10];
    const float* b_ih     = (const float*)d_in[11];
    const float* W_hh     = (const float*)d_in[12];
    const float* b_hh     = (const float*)d_in[13];
    const float* W_init_h = (const float*)d_in[14];
    const float* b_init_h = (const float*)d_in[15];
    const float* W_init_c = (const float*)d_in[16];
    const float* b_init_c = (const float*)d_in[17];
    const float* W_fbeta  = (const float*)d_in[18];
    const float* b_fbeta  = (const float*)d_in[19];
    const float* W_fc     = (const float*)d_in[20];
    const float* b_fc     = (const float*)d_in[21];
    float* out = (float*)d_out;

    char* ws = (char*)d_ws;
    size_t off = 0;
    auto alloc = [&](size_t bytes) { void* p = ws + off; off += (bytes + 255) & ~(size_t)255; return p; };
    short* enc_bf    = (short*)alloc((size_t)B_ * P_ * ENC_ * 2);
    short* att1_bf   = (short*)alloc((size_t)B_ * P_ * A_ * 2);
    short* Wenc_bf   = (short*)alloc((size_t)A_ * ENC_ * 2);
    short* Winit_bf  = (short*)alloc((size_t)2 * H_ * ENC_ * 2);
    short* Wdf_bf    = (short*)alloc((size_t)NDF_ * H_ * 2);
    short* Wcat_bf   = (short*)alloc((size_t)4 * H_ * XK_ * 2);
    short* Wfc_bf    = (short*)alloc((size_t)V_ * H_ * 2);
    float* bdf       = (float*)alloc(NDF_ * 4);
    float* bcat      = (float*)alloc(4 * H_ * 4);
    float* binit     = (float*)alloc(2 * H_ * 4);
    short* meanE_bf  = (short*)alloc((size_t)B_ * ENC_ * 2);
    float* cbuf      = (float*)alloc((size_t)B_ * H_ * 4);
    short* hbufs     = (short*)alloc((size_t)2 * B_ * H_ * 2);
    short* emb_all   = (short*)alloc((size_t)T_ * B_ * E_ * 2);
    short* hn_all    = (short*)alloc((size_t)T_ * B_ * H_ * 2);
    float* attf      = (float*)alloc((size_t)B_ * NDF_ * 4);
    short* ctxbuf    = (short*)alloc((size_t)B_ * ENC_ * 2);
    float* gates_pre = (float*)alloc((size_t)T_ * B_ * 4 * H_ * 4);  // 21 MB
    unsigned* cnt    = (unsigned*)alloc(256);
    (void)ws_size;

    // ---- one-time prep (also zeroes the grid-barrier counter)
    prep_kernel<<<PB8, 256, 0, stream>>>(
        W_enc, W_init_h, W_init_c, W_fc, W_dec, W_fbeta, W_ih, W_hh,
        captions, emb_tab, b_dec, b_fbeta, b_ih, b_hh, b_init_h, b_init_c,
        Wenc_bf, Winit_bf, Wfc_bf, Wdf_bf, Wcat_bf, emb_all, bdf, bcat, binit, cnt);
    // enc cast + mean first, so att1 reads bf16 (R7 evidence: fp32-direct is slower)
    castenc_mean<<<dim3(2, B_), 256, 0, stream>>>(enc, enc_bf, meanE_bf);
    // att1 = enc_bf @ W_enc^T + b_enc -> bf16, XCD-grouped
    gemm_bf<<<8 * 8 * ((196 + 7) / 8), 256, 0, stream>>>(
        enc_bf, Wenc_bf, nullptr, att1_bf, b_enc,
        A_, ENC_, ENC_, ENC_, A_, 196, 8, 0, nullptr);
    // gates_pre[T*B, 2048] = emb_all @ Wcat[:, :512]^T + bcat  (fp32)
    gemm_bf<<<8 * 32 * (((T_ * B_) / BM + 7) / 8), 256, 0, stream>>>(
        emb_all, Wcat_bf, gates_pre, nullptr, bcat,
        4 * H_, E_, E_, XK_, 4 * H_, (T_ * B_) / BM, 32, 0, nullptr);
    // h0 -> hbufs[0] (bf16) and c0 -> cbuf (fp32) in ONE GEMM (mode 2)
    gemm_bf<<<(2 * H_) / BN, 256, 0, stream>>>(
        meanE_bf, Winit_bf, cbuf, hbufs, binit,
        2 * H_, ENC_, ENC_, ENC_, 0, 1, (2 * H_) / BN, 2, nullptr);

    // ---- the T=20 recurrence: persistent cooperative kernel
    {
        void* kargs[] = {
            (void*)&att1_bf, (void*)&enc_bf, (void*)&Wdf_bf, (void*)&bdf,
            (void*)&w_full, (void*)&Wcat_bf, (void*)&gates_pre,
            (void*)&hbufs, (void*)&cbuf, (void*)&hn_all, (void*)&attf,
            (void*)&ctxbuf, (void*)&lengths, (void*)&cnt
        };
        hipError_t cerr = hipLaunchCooperativeKernel(
            (const void*)loop_kernel, dim3(NBLK_), dim3(512), kargs, 0, stream);
        if (cerr != hipSuccess) {
            for (int t = 0; t < T_; t++) {
                short* hcur = hbufs + (size_t)(t & 1) * B_ * H_;
                short* hnxt = hbufs + (size_t)((t & 1) ^ 1) * B_ * H_;
                gemm_bf<<<NDF_ / BN, 256, 0, stream>>>(
                    hcur, Wdf_bf, attf, nullptr, bdf,
                    NDF_, H_, H_, H_, NDF_, 1, NDF_ / BN, 0, nullptr);
                esmctx_kernel<<<dim3(2, B_), 512, 0, stream>>>(
                    att1_bf, attf, w_full, enc_bf, ctxbuf, lengths, t);
                gates_lstm<<<(4 * H_) / BN, 256, 0, stream>>>(
                    ctxbuf, hcur, hnxt, Wcat_bf, gates_pre + (size_t)t * B_ * 4 * H_,
                    cbuf, hn_all + (size_t)t * B_ * H_, lengths, t);
            }
        }
    }

    // pred: [T*B, V] in one GEMM, remapped to out[b][t][:] with mask
    gemm_bf<<<8 * 157 * (((T_ * B_) / BM + 7) / 8), 256, 0, stream>>>(
        hn_all, Wfc_bf, out, nullptr, b_fc,
        V_, H_, H_, H_, 0, (T_ * B_) / BM, 157, 1, lengths);
}

// Round 10
// 1925.206 us; speedup vs baseline: 1.7624x; 1.7624x over previous
//
#include <hip/hip_runtime.h>
#include <hip/hip_bf16.h>
#include <math.h>

#define B_   128
#define P_   196
#define ENC_ 2048
#define A_   512
#define H_   512
#define E_   512
#define V_   10000
#define T_   20
#define NDF_ 2560   /* [W_dec rows 0..511 | W_fbeta rows 512..2559] */
#define XK_  3072   /* Wcat K: E + ENC + H */
#define GK_  2560   /* per-step gates K: ENC + H (emb part precomputed) */

typedef __attribute__((ext_vector_type(8))) short bf16x8;
typedef __attribute__((ext_vector_type(4))) short bf16x4;
typedef __attribute__((ext_vector_type(4))) float f32x4;

__device__ __forceinline__ float sigmoidf_(float x) { return 1.0f / (1.0f + expf(-x)); }

__device__ __forceinline__ short f2bf(float f) {
    unsigned u = __float_as_uint(f);
    u += 0x7fffu + ((u >> 16) & 1u);
    return (short)(u >> 16);
}
__device__ __forceinline__ float bf2f(short s) {
    return __uint_as_float(((unsigned)(unsigned short)s) << 16);
}
__device__ __forceinline__ void gload_lds16(const void* g, void* l) {
    __builtin_amdgcn_global_load_lds(
        (const __attribute__((address_space(1))) void*)g,
        (__attribute__((address_space(3))) void*)l, 16, 0, 0);
}

#define BM 128
#define BN 64
#define BK 64

// shared MFMA inner compute: 64-K slab from As/Bs (XOR-swizzled layout)
#define COMPUTE64(ASP, BSP, CUR)                                               \
    _Pragma("unroll")                                                          \
    for (int kk = 0; kk < BK; kk += 32) {                                      \
        const int kb = (kk >> 3) + (lane >> 4);                                \
        bf16x8 av[4], bv[2];                                                   \
        _Pragma("unroll")                                                      \
        for (int i = 0; i < 4; i++) {                                          \
            int rr = wr * 64 + i * 16 + (lane & 15);                           \
            av[i] = *(const bf16x8*)&(ASP)[(CUR) * (BM * BK) + rr * BK         \
                    + ((kb ^ (rr & 7)) << 3)];                                 \
        }                                                                      \
        _Pragma("unroll")                                                      \
        for (int j = 0; j < 2; j++) {                                          \
            int cc = wc * 32 + j * 16 + (lane & 15);                           \
            bv[j] = *(const bf16x8*)&(BSP)[(CUR) * (BN * BK) + cc * BK         \
                    + ((kb ^ (cc & 7)) << 3)];                                 \
        }                                                                      \
        _Pragma("unroll")                                                      \
        for (int i = 0; i < 4; i++)                                            \
            _Pragma("unroll")                                                  \
            for (int j = 0; j < 2; j++)                                        \
                acc[i][j] = __builtin_amdgcn_mfma_f32_16x16x32_bf16(           \
                    av[i], bv[j], acc[i][j], 0, 0, 0);                         \
    }

// ---------------------------------------------------------------------------
// Generic GEMM: C[M,N] = A_bf16[M,K] @ B_bf16[N,K]^T + bias[N]
// mode 0: plain store; mode 1: pred remap (length-masked); mode 2: init split.
// ---------------------------------------------------------------------------
__global__ __launch_bounds__(256) void gemm_bf(
    const short* __restrict__ A, const short* __restrict__ Bw,
    float* __restrict__ Cf, short* __restrict__ Cb,
    const float* __restrict__ bias,
    int N, int K, int lda, int ldb, int ldc,
    int mtiles, int ntiles, int mode,
    const int* __restrict__ lengths)
{
    __shared__ __attribute__((aligned(16))) short As[2][BM * BK];
    __shared__ __attribute__((aligned(16))) short Bs[2][BN * BK];
    int pm, pn;
    if (mtiles == 1) { pm = 0; pn = blockIdx.x; }
    else {
        int xcd = blockIdx.x & 7, s = blockIdx.x >> 3;
        pn = s % ntiles;
        pm = (s / ntiles) * 8 + xcd;
        if (pm >= mtiles) return;
    }
    const int bm = pm * BM, bn = pn * BN;
    const int tid = threadIdx.x, w = tid >> 6, lane = tid & 63;
    const int wr = w >> 1, wc = w & 1;
    const int lr8 = lane >> 3, lk = lane & 7;

    f32x4 zero4 = {0.f, 0.f, 0.f, 0.f};
    f32x4 acc[4][2];
    #pragma unroll
    for (int i = 0; i < 4; i++)
        #pragma unroll
        for (int j = 0; j < 2; j++) acc[i][j] = zero4;

#define STAGE(buf, k0) {                                                        \
    _Pragma("unroll")                                                           \
    for (int i = 0; i < 4; i++) {                                               \
        int row0 = w * 32 + i * 8; int row = row0 + lr8;                        \
        gload_lds16(A + (size_t)(bm + row) * lda + (k0)                         \
                    + ((lk ^ (row & 7)) << 3), &As[buf][row0 * BK]);            \
    }                                                                           \
    _Pragma("unroll")                                                           \
    for (int i = 0; i < 2; i++) {                                               \
        int row0 = w * 16 + i * 8; int row = row0 + lr8;                        \
        int gn = bn + row; if (gn > N - 1) gn = N - 1;                          \
        gload_lds16(Bw + (size_t)gn * ldb + (k0)                                \
                    + ((lk ^ (row & 7)) << 3), &Bs[buf][row0 * BK]);            \
    } }

    STAGE(0, 0);
    __syncthreads();
    int cur = 0;
    for (int k0 = 0; k0 < K; k0 += BK) {
        if (k0 + BK < K) STAGE(cur ^ 1, k0 + BK);
        COMPUTE64(&As[0][0], &Bs[0][0], cur);
        __syncthreads();
        cur ^= 1;
    }
#undef STAGE

    const int lr = lane >> 4, lc = lane & 15;
    #pragma unroll
    for (int i = 0; i < 4; i++) {
        #pragma unroll
        for (int r = 0; r < 4; r++) {
            int row = bm + wr * 64 + i * 16 + lr * 4 + r;
            #pragma unroll
            for (int j = 0; j < 2; j++) {
                int col = bn + wc * 32 + j * 16 + lc;
                if (col >= N) continue;
                float v = acc[i][j][r] + bias[col];
                if (mode == 1) {
                    int tt = row >> 7, bb = row & 127;
                    float rs = (tt < lengths[bb] - 1) ? 1.0f : 0.0f;
                    Cf[(size_t)bb * T_ * V_ + (size_t)tt * V_ + col] = v * rs;
                } else if (mode == 2) {
                    if (col < H_) Cb[(size_t)row * H_ + col] = f2bf(v);
                    else          Cf[(size_t)row * H_ + (col - H_)] = v;
                } else if (Cb) {
                    Cb[(size_t)row * ldc + col] = f2bf(v);
                } else {
                    Cf[(size_t)row * ldc + col] = v;
                }
            }
        }
    }
}

// ---------------------------------------------------------------------------
// fused e + softmax + context; ONE block per b (512 threads, 8 waves).
// e-phase: 8 waves over 196 rows; ctx: 512 thr x 4 cols (bf16x4).
// Skips masked b (ctxbuf stale ok: LSTM masks h/c, pred masks out).
// ---------------------------------------------------------------------------
__global__ __launch_bounds__(512) void esmctx_kernel(
    const short* __restrict__ att1_bf, const float* __restrict__ attf,
    const float* __restrict__ wfull, const short* __restrict__ enc_bf,
    short* __restrict__ ctxbuf, const int* __restrict__ lengths, int t)
{
    __shared__ float es[P_];
    __shared__ float red[256];
    __shared__ float al[P_];
    __shared__ float sm, ss;
    const int b = blockIdx.x;
    if (t >= lengths[b] - 1) return;
    const int tid = threadIdx.x, wv = tid >> 6, lane = tid & 63;

    float a2v[8], wv8[8];
    const float* a2 = attf + (size_t)b * NDF_;
    #pragma unroll
    for (int i = 0; i < 8; i++) {
        a2v[i] = a2[lane * 8 + i];
        wv8[i] = wfull[lane * 8 + i];
    }
    for (int row = wv; row < P_; row += 8) {
        bf16x8 a1 = *(const bf16x8*)(att1_bf + ((size_t)b * P_ + row) * A_ + lane * 8);
        float s = 0.0f;
        #pragma unroll
        for (int i = 0; i < 8; i++) {
            float v = bf2f(a1[i]) + a2v[i];
            s += fmaxf(v, 0.0f) * wv8[i];
        }
        #pragma unroll
        for (int off = 32; off > 0; off >>= 1) s += __shfl_down(s, off, 64);
        if (lane == 0) es[row] = s;
    }
    __syncthreads();
    float v = (tid < P_) ? es[tid] : -1e30f;
    if (tid < 256) red[tid] = v;
    __syncthreads();
    for (int rs = 128; rs > 0; rs >>= 1) {
        if (tid < rs) red[tid] = fmaxf(red[tid], red[tid + rs]);
        __syncthreads();
    }
    if (tid == 0) sm = red[0];
    __syncthreads();
    float ex = (tid < P_) ? expf(v - sm) : 0.0f;
    if (tid < 256) red[tid] = ex;
    __syncthreads();
    for (int rs = 128; rs > 0; rs >>= 1) {
        if (tid < rs) red[tid] += red[tid + rs];
        __syncthreads();
    }
    if (tid == 0) ss = red[0];
    __syncthreads();
    if (tid < P_) al[tid] = ex / ss;
    __syncthreads();

    // ctx: 4 cols/thread, 512 threads cover all 2048 cols
    const int c0 = tid * 4;
    const short* eb = enc_bf + (size_t)b * P_ * ENC_ + c0;
    float s0 = 0, s1 = 0, s2 = 0, s3 = 0;
    for (int p = 0; p < P_; p++) {
        bf16x4 ev = *(const bf16x4*)(eb + (size_t)p * ENC_);
        float a = al[p];
        s0 += a * bf2f(ev[0]); s1 += a * bf2f(ev[1]);
        s2 += a * bf2f(ev[2]); s3 += a * bf2f(ev[3]);
    }
    const float* fb = attf + (size_t)b * NDF_ + A_;
    bf16x4 o;
    o[0] = f2bf(sigmoidf_(fb[c0 + 0]) * s0);
    o[1] = f2bf(sigmoidf_(fb[c0 + 1]) * s1);
    o[2] = f2bf(sigmoidf_(fb[c0 + 2]) * s2);
    o[3] = f2bf(sigmoidf_(fb[c0 + 3]) * s3);
    *(bf16x4*)(ctxbuf + (size_t)b * ENC_ + c0) = o;
}

// ---------------------------------------------------------------------------
// gates GEMM [128 x 2048, K=2560 (ctx|h)] + gates_pre(emb@W+b) + LSTM epilogue.
// ---------------------------------------------------------------------------
__global__ __launch_bounds__(256) void gates_lstm(
    const short* __restrict__ ctxbuf, const short* __restrict__ hcur,
    short* __restrict__ hnxt,
    const short* __restrict__ Wcat, const float* __restrict__ gpre,
    float* __restrict__ cbuf, short* __restrict__ hn_t,
    const int* __restrict__ lengths, int t)
{
    __shared__ __attribute__((aligned(16))) char smem[49152];
    short* As0 = (short*)smem;
    short* Bs0 = (short*)(smem + 32768);
    const int bn = blockIdx.x * BN;
    const int tid = threadIdx.x, w = tid >> 6, lane = tid & 63;
    const int wr = w >> 1, wc = w & 1;
    const int lr8 = lane >> 3, lk = lane & 7;

    f32x4 zero4 = {0.f, 0.f, 0.f, 0.f};
    f32x4 acc[4][2];
    #pragma unroll
    for (int i = 0; i < 4; i++)
        #pragma unroll
        for (int j = 0; j < 2; j++) acc[i][j] = zero4;

#define STAGE_G(buf, k0) {                                                      \
    const short* Ap; int Al, kk0;                                               \
    if ((k0) < ENC_) { Ap = ctxbuf; Al = ENC_; kk0 = (k0); }                    \
    else             { Ap = hcur;   Al = H_;   kk0 = (k0) - ENC_; }             \
    _Pragma("unroll")                                                           \
    for (int i = 0; i < 4; i++) {                                               \
        int row0 = w * 32 + i * 8; int row = row0 + lr8;                        \
        gload_lds16(Ap + (size_t)row * Al + kk0 + ((lk ^ (row & 7)) << 3),      \
                    &As0[(buf) * (BM * BK) + row0 * BK]);                       \
    }                                                                           \
    _Pragma("unroll")                                                           \
    for (int i = 0; i < 2; i++) {                                               \
        int row0 = w * 16 + i * 8; int row = row0 + lr8;                        \
        gload_lds16(Wcat + (size_t)(bn + row) * XK_ + E_ + (k0)                 \
                    + ((lk ^ (row & 7)) << 3),                                  \
                    &Bs0[(buf) * (BN * BK) + row0 * BK]);                       \
    } }

    STAGE_G(0, 0);
    __syncthreads();
    int cur = 0;
    for (int k0 = 0; k0 < GK_; k0 += BK) {
        if (k0 + BK < GK_) STAGE_G(cur ^ 1, k0 + BK);
        COMPUTE64(As0, Bs0, cur);
        __syncthreads();
        cur ^= 1;
    }
#undef STAGE_G

    float* gl = (float*)smem;     // 128*68*4 = 34816 B (As/Bs dead)
    const int lr = lane >> 4, lc = lane & 15;
    #pragma unroll
    for (int i = 0; i < 4; i++)
        #pragma unroll
        for (int r = 0; r < 4; r++) {
            int row = wr * 64 + i * 16 + lr * 4 + r;
            #pragma unroll
            for (int j = 0; j < 2; j++) {
                int col = wc * 32 + j * 16 + lc;
                gl[row * 68 + col] = acc[i][j][r] + gpre[(size_t)row * (4 * H_) + bn + col];
            }
        }
    __syncthreads();
    #pragma unroll
    for (int q = 0; q < 8; q++) {
        int id  = tid * 8 + q;
        int row = id >> 4;            // batch b
        int j   = id & 15;            // local hidden unit
        int jg  = (bn >> 2) + j;      // global hidden index
        float i_ = sigmoidf_(gl[row * 68 + 4 * j + 0]);
        float f_ = sigmoidf_(gl[row * 68 + 4 * j + 1]);
        float g_ = tanhf    (gl[row * 68 + 4 * j + 2]);
        float o_ = sigmoidf_(gl[row * 68 + 4 * j + 3]);
        float cn = f_ * cbuf[row * H_ + jg] + i_ * g_;
        float hv = o_ * tanhf(cn);
        hn_t[row * H_ + jg] = f2bf(hv);
        bool m = t < lengths[row] - 1;
        if (m) cbuf[row * H_ + jg] = cn;
        hnxt[row * H_ + jg] = m ? f2bf(hv) : hcur[row * H_ + jg];
    }
}

// ---------------------------------------------------------------------------
// Fused enc cast + mean: grid (2, B), 256 threads, 4 cols/thread.
// ---------------------------------------------------------------------------
__global__ __launch_bounds__(256) void castenc_mean(const float* __restrict__ enc,
                                                    short* __restrict__ enc_bf,
                                                    short* __restrict__ meanE_bf)
{
    const int b = blockIdx.y;
    const int c0 = blockIdx.x * 1024 + threadIdx.x * 4;
    const float* src = enc + (size_t)b * P_ * ENC_ + c0;
    short* dst = enc_bf + (size_t)b * P_ * ENC_ + c0;
    float s0 = 0, s1 = 0, s2 = 0, s3 = 0;
    for (int p = 0; p < P_; p++) {
        float4 f = *(const float4*)(src + (size_t)p * ENC_);
        bf16x4 v;
        v[0] = f2bf(f.x); v[1] = f2bf(f.y); v[2] = f2bf(f.z); v[3] = f2bf(f.w);
        *(bf16x4*)(dst + (size_t)p * ENC_) = v;
        s0 += f.x; s1 += f.y; s2 += f.z; s3 += f.w;
    }
    const float inv = 1.0f / (float)P_;
    bf16x4 m;
    m[0] = f2bf(s0 * inv); m[1] = f2bf(s1 * inv);
    m[2] = f2bf(s2 * inv); m[3] = f2bf(s3 * inv);
    *(bf16x4*)(meanE_bf + (size_t)b * ENC_ + c0) = m;
}

// ---------------------------------------------------------------------------
// Mega-prep: all weight casts/concats/biases/embedding in ONE kernel.
// ---------------------------------------------------------------------------
#define PB0 1024               /* W_enc cast: 512*2048          */
#define PB1 (PB0 + 2048)       /* Winit cat : 1024*2048         */
#define PB2 (PB1 + 5000)       /* W_fc cast : 10000*512         */
#define PB3 (PB2 + 1280)       /* Wdf cat   : 2560*512          */
#define PB4 (PB3 + 6144)       /* Wcat      : 2048*3072         */
#define PB5 (PB4 + 1280)       /* emb_all   : 20*128*512        */
#define PB6 (PB5 + 3)          /* bdf 2560                      */
#define PB7 (PB6 + 2)          /* bcat 2048                     */
#define PB8 (PB7 + 1)          /* binit 1024                    */

__device__ __forceinline__ void cast4(const float* __restrict__ in,
                                      short* __restrict__ out, int i4) {
    float4 f = *(const float4*)(in + i4);
    bf16x4 v;
    v[0] = f2bf(f.x); v[1] = f2bf(f.y); v[2] = f2bf(f.z); v[3] = f2bf(f.w);
    *(bf16x4*)(out + i4) = v;
}
__device__ __forceinline__ void cast4p(const float* __restrict__ src,
                                       short* __restrict__ out, int i4) {
    float4 f = *(const float4*)src;
    bf16x4 v;
    v[0] = f2bf(f.x); v[1] = f2bf(f.y); v[2] = f2bf(f.z); v[3] = f2bf(f.w);
    *(bf16x4*)(out + i4) = v;
}

__global__ __launch_bounds__(256) void prep_kernel(
    const float* __restrict__ W_enc,    const float* __restrict__ W_init_h,
    const float* __restrict__ W_init_c, const float* __restrict__ W_fc,
    const float* __restrict__ W_dec,    const float* __restrict__ W_fbeta,
    const float* __restrict__ W_ih,     const float* __restrict__ W_hh,
    const int*   __restrict__ captions, const float* __restrict__ emb_tab,
    const float* __restrict__ b_dec,    const float* __restrict__ b_fbeta,
    const float* __restrict__ b_ih,     const float* __restrict__ b_hh,
    const float* __restrict__ b_init_h, const float* __restrict__ b_init_c,
    short* __restrict__ Wenc_bf,  short* __restrict__ Winit_bf,
    short* __restrict__ Wfc_bf,   short* __restrict__ Wdf_bf,
    short* __restrict__ Wcat_bf,  short* __restrict__ emb_all,
    float* __restrict__ bdf,      float* __restrict__ bcat,
    float* __restrict__ binit)
{
    const int blk = blockIdx.x, tid = threadIdx.x;
    if (blk < PB0) {
        cast4(W_enc, Wenc_bf, blk * 1024 + tid * 4);
    } else if (blk < PB1) {
        int i4 = (blk - PB0) * 1024 + tid * 4;
        int n = i4 >> 11, k = i4 & 2047;
        const float* src = (n < H_) ? W_init_h + (size_t)n * ENC_ + k
                                    : W_init_c + (size_t)(n - H_) * ENC_ + k;
        cast4p(src, Winit_bf, i4);
    } else if (blk < PB2) {
        cast4(W_fc, Wfc_bf, (blk - PB1) * 1024 + tid * 4);
    } else if (blk < PB3) {
        int i4 = (blk - PB2) * 1024 + tid * 4;
        int n = i4 >> 9, k = i4 & 511;
        const float* src = (n < A_) ? W_dec + (size_t)n * H_ + k
                                    : W_fbeta + (size_t)(n - A_) * H_ + k;
        cast4p(src, Wdf_bf, i4);
    } else if (blk < PB4) {
        int i4 = (blk - PB3) * 1024 + tid * 4;
        int n = i4 / XK_, k = i4 - n * XK_;
        int srow = (n & 3) * H_ + (n >> 2);
        const float* src = (k < E_ + ENC_) ? W_ih + (size_t)srow * (E_ + ENC_) + k
                                           : W_hh + (size_t)srow * H_ + (k - (E_ + ENC_));
        cast4p(src, Wcat_bf, i4);
    } else if (blk < PB5) {
        int i4 = (blk - PB4) * 1024 + tid * 4;
        int col = i4 & 511;
        int bt  = i4 >> 9;
        int b   = bt & 127;
        int tt  = bt >> 7;
        int tok = captions[b * (T_ + 1) + tt];
        cast4p(emb_tab + (size_t)tok * E_ + col, emb_all, i4);
    } else if (blk < PB6) {
        int j = (blk - PB5) * 1024 + tid * 4;
        #pragma unroll
        for (int q = 0; q < 4; q++, j++)
            if (j < NDF_) bdf[j] = (j < A_) ? b_dec[j] : b_fbeta[j - A_];
    } else if (blk < PB7) {
        int j = (blk - PB6) * 1024 + tid * 4;
        #pragma unroll
        for (int q = 0; q < 4; q++, j++) {
            int srow = (j & 3) * H_ + (j >> 2);
            bcat[j] = b_ih[srow] + b_hh[srow];
        }
    } else {
        int j = tid * 4;
        #pragma unroll
        for (int q = 0; q < 4; q++, j++)
            binit[j] = (j < H_) ? b_init_h[j] : b_init_c[j - H_];
    }
}

extern "C" void kernel_launch(void* const* d_in, const int* in_sizes, int n_in,
                              void* d_out, int out_size, void* d_ws, size_t ws_size,
                              hipStream_t stream)
{
    const float* enc      = (const float*)d_in[0];
    const int*   captions = (const int*)  d_in[1];
    const int*   lengths  = (const int*)  d_in[2];
    const float* W_enc    = (const float*)d_in[3];
    const float* b_enc    = (const float*)d_in[4];
    const float* W_dec    = (const float*)d_in[5];
    const float* b_dec    = (const float*)d_in[6];
    const float* w_full   = (const float*)d_in[7];
    const float* emb_tab  = (const float*)d_in[9];
    const float* W_ih     = (const float*)d_in[10];
    const float* b_ih     = (const float*)d_in[11];
    const float* W_hh     = (const float*)d_in[12];
    const float* b_hh     = (const float*)d_in[13];
    const float* W_init_h = (const float*)d_in[14];
    const float* b_init_h = (const float*)d_in[15];
    const float* W_init_c = (const float*)d_in[16];
    const float* b_init_c = (const float*)d_in[17];
    const float* W_fbeta  = (const float*)d_in[18];
    const float* b_fbeta  = (const float*)d_in[19];
    const float* W_fc     = (const float*)d_in[20];
    const float* b_fc     = (const float*)d_in[21];
    float* out = (float*)d_out;

    char* ws = (char*)d_ws;
    size_t off = 0;
    auto alloc = [&](size_t bytes) { void* p = ws + off; off += (bytes + 255) & ~(size_t)255; return p; };
    short* enc_bf    = (short*)alloc((size_t)B_ * P_ * ENC_ * 2);
    short* att1_bf   = (short*)alloc((size_t)B_ * P_ * A_ * 2);
    short* Wenc_bf   = (short*)alloc((size_t)A_ * ENC_ * 2);
    short* Winit_bf  = (short*)alloc((size_t)2 * H_ * ENC_ * 2);
    short* Wdf_bf    = (short*)alloc((size_t)NDF_ * H_ * 2);
    short* Wcat_bf   = (short*)alloc((size_t)4 * H_ * XK_ * 2);
    short* Wfc_bf    = (short*)alloc((size_t)V_ * H_ * 2);
    float* bdf       = (float*)alloc(NDF_ * 4);
    float* bcat      = (float*)alloc(4 * H_ * 4);
    float* binit     = (float*)alloc(2 * H_ * 4);
    short* meanE_bf  = (short*)alloc((size_t)B_ * ENC_ * 2);
    float* cbuf      = (float*)alloc((size_t)B_ * H_ * 4);
    short* hbufs     = (short*)alloc((size_t)2 * B_ * H_ * 2);
    short* emb_all   = (short*)alloc((size_t)T_ * B_ * E_ * 2);
    short* hn_all    = (short*)alloc((size_t)T_ * B_ * H_ * 2);
    float* attf      = (float*)alloc((size_t)B_ * NDF_ * 4);
    short* ctxbuf    = (short*)alloc((size_t)B_ * ENC_ * 2);
    float* gates_pre = (float*)alloc((size_t)T_ * B_ * 4 * H_ * 4);  // 21 MB
    (void)ws_size;

    // ---- one-time prep
    prep_kernel<<<PB8, 256, 0, stream>>>(
        W_enc, W_init_h, W_init_c, W_fc, W_dec, W_fbeta, W_ih, W_hh,
        captions, emb_tab, b_dec, b_fbeta, b_ih, b_hh, b_init_h, b_init_c,
        Wenc_bf, Winit_bf, Wfc_bf, Wdf_bf, Wcat_bf, emb_all, bdf, bcat, binit);
    castenc_mean<<<dim3(2, B_), 256, 0, stream>>>(enc, enc_bf, meanE_bf);
    // att1 = enc_bf @ W_enc^T + b_enc -> bf16, XCD-grouped (L3-hot enc_bf)
    gemm_bf<<<8 * 8 * ((196 + 7) / 8), 256, 0, stream>>>(
        enc_bf, Wenc_bf, nullptr, att1_bf, b_enc,
        A_, ENC_, ENC_, ENC_, A_, 196, 8, 0, nullptr);
    // gates_pre[T*B, 2048] = emb_all @ Wcat[:, :512]^T + bcat  (fp32)
    gemm_bf<<<8 * 32 * (((T_ * B_) / BM + 7) / 8), 256, 0, stream>>>(
        emb_all, Wcat_bf, gates_pre, nullptr, bcat,
        4 * H_, E_, E_, XK_, 4 * H_, (T_ * B_) / BM, 32, 0, nullptr);
    // h0 -> hbufs[0] (bf16) and c0 -> cbuf (fp32) in ONE GEMM (mode 2)
    gemm_bf<<<(2 * H_) / BN, 256, 0, stream>>>(
        meanE_bf, Winit_bf, cbuf, hbufs, binit,
        2 * H_, ENC_, ENC_, ENC_, 0, 1, (2 * H_) / BN, 2, nullptr);

    for (int t = 0; t < T_; t++) {
        short* hcur = hbufs + (size_t)(t & 1) * B_ * H_;
        short* hnxt = hbufs + (size_t)((t & 1) ^ 1) * B_ * H_;
        // attf = h @ [W_dec|W_fbeta]^T + [b_dec|b_fbeta]   (MFMA GEMM)
        gemm_bf<<<NDF_ / BN, 256, 0, stream>>>(
            hcur, Wdf_bf, attf, nullptr, bdf,
            NDF_, H_, H_, H_, NDF_, 1, NDF_ / BN, 0, nullptr);
        esmctx_kernel<<<B_, 512, 0, stream>>>(
            att1_bf, attf, w_full, enc_bf, ctxbuf, lengths, t);
        gates_lstm<<<(4 * H_) / BN, 256, 0, stream>>>(
            ctxbuf, hcur, hnxt, Wcat_bf, gates_pre + (size_t)t * B_ * 4 * H_,
            cbuf, hn_all + (size_t)t * B_ * H_, lengths, t);
    }
    // pred: [T*B, V] in one GEMM, remapped to out[b][t][:] with mask
    gemm_bf<<<8 * 157 * (((T_ * B_) / BM + 7) / 8), 256, 0, stream>>>(
        hn_all, Wfc_bf, out, nullptr, b_fc,
        V_, H_, H_, H_, 0, (T_ * B_) / BM, 157, 1, lengths);
}

// Round 11
// 1819.517 us; speedup vs baseline: 1.8647x; 1.0581x over previous
//
#include <hip/hip_runtime.h>
#include <hip/hip_bf16.h>
#include <math.h>

#define B_   128
#define P_   196
#define ENC_ 2048
#define A_   512
#define H_   512
#define E_   512
#define V_   10000
#define T_   20
#define NDF_ 2560   /* [W_dec rows 0..511 | W_fbeta rows 512..2559] */
#define XK_  3072   /* Wcat K: E + ENC + H */
#define GK_  2560   /* per-step gates K: ENC + H (emb part precomputed) */

typedef __attribute__((ext_vector_type(8))) short bf16x8;
typedef __attribute__((ext_vector_type(4))) short bf16x4;
typedef __attribute__((ext_vector_type(2))) short bf16x2;
typedef __attribute__((ext_vector_type(4))) float f32x4;

__device__ __forceinline__ float sigmoidf_(float x) { return 1.0f / (1.0f + expf(-x)); }

__device__ __forceinline__ short f2bf(float f) {
    unsigned u = __float_as_uint(f);
    u += 0x7fffu + ((u >> 16) & 1u);
    return (short)(u >> 16);
}
__device__ __forceinline__ float bf2f(short s) {
    return __uint_as_float(((unsigned)(unsigned short)s) << 16);
}
__device__ __forceinline__ void gload_lds16(const void* g, void* l) {
    __builtin_amdgcn_global_load_lds(
        (const __attribute__((address_space(1))) void*)g,
        (__attribute__((address_space(3))) void*)l, 16, 0, 0);
}

#define BM 128
#define BN 64
#define BK 64

// shared MFMA inner compute: 64-K slab from As/Bs (XOR-swizzled layout)
#define COMPUTE64(ASP, BSP, CUR)                                               \
    _Pragma("unroll")                                                          \
    for (int kk = 0; kk < BK; kk += 32) {                                      \
        const int kb = (kk >> 3) + (lane >> 4);                                \
        bf16x8 av[4], bv[2];                                                   \
        _Pragma("unroll")                                                      \
        for (int i = 0; i < 4; i++) {                                          \
            int rr = wr * 64 + i * 16 + (lane & 15);                           \
            av[i] = *(const bf16x8*)&(ASP)[(CUR) * (BM * BK) + rr * BK         \
                    + ((kb ^ (rr & 7)) << 3)];                                 \
        }                                                                      \
        _Pragma("unroll")                                                      \
        for (int j = 0; j < 2; j++) {                                          \
            int cc = wc * 32 + j * 16 + (lane & 15);                           \
            bv[j] = *(const bf16x8*)&(BSP)[(CUR) * (BN * BK) + cc * BK         \
                    + ((kb ^ (cc & 7)) << 3)];                                 \
        }                                                                      \
        _Pragma("unroll")                                                      \
        for (int i = 0; i < 4; i++)                                            \
            _Pragma("unroll")                                                  \
            for (int j = 0; j < 2; j++)                                        \
                acc[i][j] = __builtin_amdgcn_mfma_f32_16x16x32_bf16(           \
                    av[i], bv[j], acc[i][j], 0, 0, 0);                         \
    }

// ---------------------------------------------------------------------------
// Generic GEMM (BM=128): C[M,N] = A_bf16 @ B_bf16^T + bias
// mode 0: plain store; mode 1: pred remap (length-masked); mode 2: init split.
// ---------------------------------------------------------------------------
__global__ __launch_bounds__(256) void gemm_bf(
    const short* __restrict__ A, const short* __restrict__ Bw,
    float* __restrict__ Cf, short* __restrict__ Cb,
    const float* __restrict__ bias,
    int N, int K, int lda, int ldb, int ldc,
    int mtiles, int ntiles, int mode,
    const int* __restrict__ lengths)
{
    __shared__ __attribute__((aligned(16))) short As[2][BM * BK];
    __shared__ __attribute__((aligned(16))) short Bs[2][BN * BK];
    int pm, pn;
    if (mtiles == 1) { pm = 0; pn = blockIdx.x; }
    else {
        int xcd = blockIdx.x & 7, s = blockIdx.x >> 3;
        pn = s % ntiles;
        pm = (s / ntiles) * 8 + xcd;
        if (pm >= mtiles) return;
    }
    const int bm = pm * BM, bn = pn * BN;
    const int tid = threadIdx.x, w = tid >> 6, lane = tid & 63;
    const int wr = w >> 1, wc = w & 1;
    const int lr8 = lane >> 3, lk = lane & 7;

    f32x4 zero4 = {0.f, 0.f, 0.f, 0.f};
    f32x4 acc[4][2];
    #pragma unroll
    for (int i = 0; i < 4; i++)
        #pragma unroll
        for (int j = 0; j < 2; j++) acc[i][j] = zero4;

#define STAGE(buf, k0) {                                                        \
    _Pragma("unroll")                                                           \
    for (int i = 0; i < 4; i++) {                                               \
        int row0 = w * 32 + i * 8; int row = row0 + lr8;                        \
        gload_lds16(A + (size_t)(bm + row) * lda + (k0)                         \
                    + ((lk ^ (row & 7)) << 3), &As[buf][row0 * BK]);            \
    }                                                                           \
    _Pragma("unroll")                                                           \
    for (int i = 0; i < 2; i++) {                                               \
        int row0 = w * 16 + i * 8; int row = row0 + lr8;                        \
        int gn = bn + row; if (gn > N - 1) gn = N - 1;                          \
        gload_lds16(Bw + (size_t)gn * ldb + (k0)                                \
                    + ((lk ^ (row & 7)) << 3), &Bs[buf][row0 * BK]);            \
    } }

    STAGE(0, 0);
    __syncthreads();
    int cur = 0;
    for (int k0 = 0; k0 < K; k0 += BK) {
        if (k0 + BK < K) STAGE(cur ^ 1, k0 + BK);
        COMPUTE64(&As[0][0], &Bs[0][0], cur);
        __syncthreads();
        cur ^= 1;
    }
#undef STAGE

    const int lr = lane >> 4, lc = lane & 15;
    #pragma unroll
    for (int i = 0; i < 4; i++) {
        #pragma unroll
        for (int r = 0; r < 4; r++) {
            int row = bm + wr * 64 + i * 16 + lr * 4 + r;
            #pragma unroll
            for (int j = 0; j < 2; j++) {
                int col = bn + wc * 32 + j * 16 + lc;
                if (col >= N) continue;
                float v = acc[i][j][r] + bias[col];
                if (mode == 1) {
                    int tt = row >> 7, bb = row & 127;
                    float rs = (tt < lengths[bb] - 1) ? 1.0f : 0.0f;
                    Cf[(size_t)bb * T_ * V_ + (size_t)tt * V_ + col] = v * rs;
                } else if (mode == 2) {
                    if (col < H_) Cb[(size_t)row * H_ + col] = f2bf(v);
                    else          Cf[(size_t)row * H_ + (col - H_)] = v;
                } else if (Cb) {
                    Cb[(size_t)row * ldc + col] = f2bf(v);
                } else {
                    Cf[(size_t)row * ldc + col] = v;
                }
            }
        }
    }
}

// ---------------------------------------------------------------------------
// BM=64 GEMM for latency-bound shapes (att1): 32 KB LDS -> 5 blocks/CU.
// bf16 output only, XCD-grouped.
// ---------------------------------------------------------------------------
__global__ __launch_bounds__(256) void gemm_bf64(
    const short* __restrict__ A, const short* __restrict__ Bw,
    short* __restrict__ Cb, const float* __restrict__ bias,
    int N, int K, int lda, int ldb, int ldc,
    int mtiles, int ntiles)
{
    __shared__ __attribute__((aligned(16))) short As[2][64 * BK];
    __shared__ __attribute__((aligned(16))) short Bs[2][BN * BK];
    int xcd = blockIdx.x & 7, s = blockIdx.x >> 3;
    int pn = s % ntiles;
    int pm = (s / ntiles) * 8 + xcd;
    if (pm >= mtiles) return;
    const int bm = pm * 64, bn = pn * BN;
    const int tid = threadIdx.x, w = tid >> 6, lane = tid & 63;
    const int wr = w >> 1, wc = w & 1;
    const int lr8 = lane >> 3, lk = lane & 7;

    f32x4 zero4 = {0.f, 0.f, 0.f, 0.f};
    f32x4 acc[2][2];
    #pragma unroll
    for (int i = 0; i < 2; i++)
        #pragma unroll
        for (int j = 0; j < 2; j++) acc[i][j] = zero4;

#define STAGE64(buf, k0) {                                                      \
    _Pragma("unroll")                                                           \
    for (int i = 0; i < 2; i++) {                                               \
        int row0 = w * 16 + i * 8; int row = row0 + lr8;                        \
        gload_lds16(A + (size_t)(bm + row) * lda + (k0)                         \
                    + ((lk ^ (row & 7)) << 3), &As[buf][row0 * BK]);            \
    }                                                                           \
    _Pragma("unroll")                                                           \
    for (int i = 0; i < 2; i++) {                                               \
        int row0 = w * 16 + i * 8; int row = row0 + lr8;                        \
        int gn = bn + row; if (gn > N - 1) gn = N - 1;                          \
        gload_lds16(Bw + (size_t)gn * ldb + (k0)                                \
                    + ((lk ^ (row & 7)) << 3), &Bs[buf][row0 * BK]);            \
    } }

    STAGE64(0, 0);
    __syncthreads();
    int cur = 0;
    for (int k0 = 0; k0 < K; k0 += BK) {
        if (k0 + BK < K) STAGE64(cur ^ 1, k0 + BK);
        #pragma unroll
        for (int kk = 0; kk < BK; kk += 32) {
            const int kb = (kk >> 3) + (lane >> 4);
            bf16x8 av[2], bv[2];
            #pragma unroll
            for (int i = 0; i < 2; i++) {
                int rr = wr * 32 + i * 16 + (lane & 15);
                av[i] = *(const bf16x8*)&As[cur][rr * BK + ((kb ^ (rr & 7)) << 3)];
            }
            #pragma unroll
            for (int j = 0; j < 2; j++) {
                int cc = wc * 32 + j * 16 + (lane & 15);
                bv[j] = *(const bf16x8*)&Bs[cur][cc * BK + ((kb ^ (cc & 7)) << 3)];
            }
            #pragma unroll
            for (int i = 0; i < 2; i++)
                #pragma unroll
                for (int j = 0; j < 2; j++)
                    acc[i][j] = __builtin_amdgcn_mfma_f32_16x16x32_bf16(
                        av[i], bv[j], acc[i][j], 0, 0, 0);
        }
        __syncthreads();
        cur ^= 1;
    }
#undef STAGE64

    const int lr = lane >> 4, lc = lane & 15;
    #pragma unroll
    for (int i = 0; i < 2; i++)
        #pragma unroll
        for (int r = 0; r < 4; r++) {
            int row = bm + wr * 32 + i * 16 + lr * 4 + r;
            #pragma unroll
            for (int j = 0; j < 2; j++) {
                int col = bn + wc * 32 + j * 16 + lc;
                if (col < N) Cb[(size_t)row * ldc + col] = f2bf(acc[i][j][r] + bias[col]);
            }
        }
}

// ---------------------------------------------------------------------------
// fused e + softmax + context; grid (2, B), 512 threads. Skips masked b.
// ---------------------------------------------------------------------------
__global__ __launch_bounds__(512) void esmctx_kernel(
    const short* __restrict__ att1_bf, const float* __restrict__ attf,
    const float* __restrict__ wfull, const short* __restrict__ enc_bf,
    short* __restrict__ ctxbuf, const int* __restrict__ lengths, int t)
{
    __shared__ float es[P_];
    __shared__ float red[256];
    __shared__ float al[P_];
    __shared__ float sm, ss;
    const int b = blockIdx.y, half = blockIdx.x;
    if (t >= lengths[b] - 1) return;
    const int tid = threadIdx.x, wv = tid >> 6, lane = tid & 63;

    float a2v[8], wv8[8];
    const float* a2 = attf + (size_t)b * NDF_;
    #pragma unroll
    for (int i = 0; i < 8; i++) {
        a2v[i] = a2[lane * 8 + i];
        wv8[i] = wfull[lane * 8 + i];
    }
    for (int row = wv; row < P_; row += 8) {
        bf16x8 a1 = *(const bf16x8*)(att1_bf + ((size_t)b * P_ + row) * A_ + lane * 8);
        float s = 0.0f;
        #pragma unroll
        for (int i = 0; i < 8; i++) {
            float v = bf2f(a1[i]) + a2v[i];
            s += fmaxf(v, 0.0f) * wv8[i];
        }
        #pragma unroll
        for (int off = 32; off > 0; off >>= 1) s += __shfl_down(s, off, 64);
        if (lane == 0) es[row] = s;
    }
    __syncthreads();
    float v = (tid < P_) ? es[tid] : -1e30f;
    if (tid < 256) red[tid] = v;
    __syncthreads();
    for (int rs = 128; rs > 0; rs >>= 1) {
        if (tid < rs) red[tid] = fmaxf(red[tid], red[tid + rs]);
        __syncthreads();
    }
    if (tid == 0) sm = red[0];
    __syncthreads();
    float ex = (tid < P_) ? expf(v - sm) : 0.0f;
    if (tid < 256) red[tid] = ex;
    __syncthreads();
    for (int rs = 128; rs > 0; rs >>= 1) {
        if (tid < rs) red[tid] += red[tid + rs];
        __syncthreads();
    }
    if (tid == 0) ss = red[0];
    __syncthreads();
    if (tid < P_) al[tid] = ex / ss;
    __syncthreads();

    const int c0 = half * 1024 + tid * 2;
    const short* eb = enc_bf + (size_t)b * P_ * ENC_ + c0;
    float s0 = 0, s1 = 0;
    for (int p = 0; p < P_; p++) {
        bf16x2 ev = *(const bf16x2*)(eb + (size_t)p * ENC_);
        float a = al[p];
        s0 += a * bf2f(ev[0]); s1 += a * bf2f(ev[1]);
    }
    const float* fb = attf + (size_t)b * NDF_ + A_;
    bf16x2 o;
    o[0] = f2bf(sigmoidf_(fb[c0 + 0]) * s0);
    o[1] = f2bf(sigmoidf_(fb[c0 + 1]) * s1);
    *(bf16x2*)(ctxbuf + (size_t)b * ENC_ + c0) = o;
}

// ---------------------------------------------------------------------------
// gates GEMM [128 x 2048, K=2560 (ctx|h)] + gates_pre(emb@W+b) + LSTM epilogue.
// ---------------------------------------------------------------------------
__global__ __launch_bounds__(256) void gates_lstm(
    const short* __restrict__ ctxbuf, const short* __restrict__ hcur,
    short* __restrict__ hnxt,
    const short* __restrict__ Wcat, const float* __restrict__ gpre,
    float* __restrict__ cbuf, short* __restrict__ hn_t,
    const int* __restrict__ lengths, int t)
{
    __shared__ __attribute__((aligned(16))) char smem[49152];
    short* As0 = (short*)smem;
    short* Bs0 = (short*)(smem + 32768);
    const int bn = blockIdx.x * BN;
    const int tid = threadIdx.x, w = tid >> 6, lane = tid & 63;
    const int wr = w >> 1, wc = w & 1;
    const int lr8 = lane >> 3, lk = lane & 7;

    f32x4 zero4 = {0.f, 0.f, 0.f, 0.f};
    f32x4 acc[4][2];
    #pragma unroll
    for (int i = 0; i < 4; i++)
        #pragma unroll
        for (int j = 0; j < 2; j++) acc[i][j] = zero4;

#define STAGE_G(buf, k0) {                                                      \
    const short* Ap; int Al, kk0;                                               \
    if ((k0) < ENC_) { Ap = ctxbuf; Al = ENC_; kk0 = (k0); }                    \
    else             { Ap = hcur;   Al = H_;   kk0 = (k0) - ENC_; }             \
    _Pragma("unroll")                                                           \
    for (int i = 0; i < 4; i++) {                                               \
        int row0 = w * 32 + i * 8; int row = row0 + lr8;                        \
        gload_lds16(Ap + (size_t)row * Al + kk0 + ((lk ^ (row & 7)) << 3),      \
                    &As0[(buf) * (BM * BK) + row0 * BK]);                       \
    }                                                                           \
    _Pragma("unroll")                                                           \
    for (int i = 0; i < 2; i++) {                                               \
        int row0 = w * 16 + i * 8; int row = row0 + lr8;                        \
        gload_lds16(Wcat + (size_t)(bn + row) * XK_ + E_ + (k0)                 \
                    + ((lk ^ (row & 7)) << 3),                                  \
                    &Bs0[(buf) * (BN * BK) + row0 * BK]);                       \
    } }

    STAGE_G(0, 0);
    __syncthreads();
    int cur = 0;
    for (int k0 = 0; k0 < GK_; k0 += BK) {
        if (k0 + BK < GK_) STAGE_G(cur ^ 1, k0 + BK);
        COMPUTE64(As0, Bs0, cur);
        __syncthreads();
        cur ^= 1;
    }
#undef STAGE_G

    float* gl = (float*)smem;     // 128*68*4 = 34816 B (As/Bs dead)
    const int lr = lane >> 4, lc = lane & 15;
    #pragma unroll
    for (int i = 0; i < 4; i++)
        #pragma unroll
        for (int r = 0; r < 4; r++) {
            int row = wr * 64 + i * 16 + lr * 4 + r;
            #pragma unroll
            for (int j = 0; j < 2; j++) {
                int col = wc * 32 + j * 16 + lc;
                gl[row * 68 + col] = acc[i][j][r] + gpre[(size_t)row * (4 * H_) + bn + col];
            }
        }
    __syncthreads();
    #pragma unroll
    for (int q = 0; q < 8; q++) {
        int id  = tid * 8 + q;
        int row = id >> 4;            // batch b
        int j   = id & 15;            // local hidden unit
        int jg  = (bn >> 2) + j;      // global hidden index
        float i_ = sigmoidf_(gl[row * 68 + 4 * j + 0]);
        float f_ = sigmoidf_(gl[row * 68 + 4 * j + 1]);
        float g_ = tanhf    (gl[row * 68 + 4 * j + 2]);
        float o_ = sigmoidf_(gl[row * 68 + 4 * j + 3]);
        float cn = f_ * cbuf[row * H_ + jg] + i_ * g_;
        float hv = o_ * tanhf(cn);
        hn_t[row * H_ + jg] = f2bf(hv);
        bool m = t < lengths[row] - 1;
        if (m) cbuf[row * H_ + jg] = cn;
        hnxt[row * H_ + jg] = m ? f2bf(hv) : hcur[row * H_ + jg];
    }
}

// ---------------------------------------------------------------------------
// Fused enc cast + mean; NON-TEMPORAL fp32 reads so the 205 MB stream doesn't
// evict the freshly written enc_bf from L3 (att1 reads it next).
// ---------------------------------------------------------------------------
__global__ __launch_bounds__(256) void castenc_mean(const float* __restrict__ enc,
                                                    short* __restrict__ enc_bf,
                                                    short* __restrict__ meanE_bf)
{
    const int b = blockIdx.y;
    const int c0 = blockIdx.x * 1024 + threadIdx.x * 4;
    const f32x4* src = (const f32x4*)(enc + (size_t)b * P_ * ENC_ + c0);
    short* dst = enc_bf + (size_t)b * P_ * ENC_ + c0;
    float s0 = 0, s1 = 0, s2 = 0, s3 = 0;
    for (int p = 0; p < P_; p++) {
        f32x4 f = __builtin_nontemporal_load(src + (size_t)p * (ENC_ / 4));
        bf16x4 v;
        v[0] = f2bf(f[0]); v[1] = f2bf(f[1]); v[2] = f2bf(f[2]); v[3] = f2bf(f[3]);
        *(bf16x4*)(dst + (size_t)p * ENC_) = v;
        s0 += f[0]; s1 += f[1]; s2 += f[2]; s3 += f[3];
    }
    const float inv = 1.0f / (float)P_;
    bf16x4 m;
    m[0] = f2bf(s0 * inv); m[1] = f2bf(s1 * inv);
    m[2] = f2bf(s2 * inv); m[3] = f2bf(s3 * inv);
    *(bf16x4*)(meanE_bf + (size_t)b * ENC_ + c0) = m;
}

// ---------------------------------------------------------------------------
// Mega-prep: all weight casts/concats/biases/embedding in ONE kernel.
// ---------------------------------------------------------------------------
#define PB0 1024               /* W_enc cast: 512*2048          */
#define PB1 (PB0 + 2048)       /* Winit cat : 1024*2048         */
#define PB2 (PB1 + 5000)       /* W_fc cast : 10000*512         */
#define PB3 (PB2 + 1280)       /* Wdf cat   : 2560*512          */
#define PB4 (PB3 + 6144)       /* Wcat      : 2048*3072         */
#define PB5 (PB4 + 1280)       /* emb_all   : 20*128*512        */
#define PB6 (PB5 + 3)          /* bdf 2560                      */
#define PB7 (PB6 + 2)          /* bcat 2048                     */
#define PB8 (PB7 + 1)          /* binit 1024                    */

__device__ __forceinline__ void cast4(const float* __restrict__ in,
                                      short* __restrict__ out, int i4) {
    float4 f = *(const float4*)(in + i4);
    bf16x4 v;
    v[0] = f2bf(f.x); v[1] = f2bf(f.y); v[2] = f2bf(f.z); v[3] = f2bf(f.w);
    *(bf16x4*)(out + i4) = v;
}
__device__ __forceinline__ void cast4p(const float* __restrict__ src,
                                       short* __restrict__ out, int i4) {
    float4 f = *(const float4*)src;
    bf16x4 v;
    v[0] = f2bf(f.x); v[1] = f2bf(f.y); v[2] = f2bf(f.z); v[3] = f2bf(f.w);
    *(bf16x4*)(out + i4) = v;
}

__global__ __launch_bounds__(256) void prep_kernel(
    const float* __restrict__ W_enc,    const float* __restrict__ W_init_h,
    const float* __restrict__ W_init_c, const float* __restrict__ W_fc,
    const float* __restrict__ W_dec,    const float* __restrict__ W_fbeta,
    const float* __restrict__ W_ih,     const float* __restrict__ W_hh,
    const int*   __restrict__ captions, const float* __restrict__ emb_tab,
    const float* __restrict__ b_dec,    const float* __restrict__ b_fbeta,
    const float* __restrict__ b_ih,     const float* __restrict__ b_hh,
    const float* __restrict__ b_init_h, const float* __restrict__ b_init_c,
    short* __restrict__ Wenc_bf,  short* __restrict__ Winit_bf,
    short* __restrict__ Wfc_bf,   short* __restrict__ Wdf_bf,
    short* __restrict__ Wcat_bf,  short* __restrict__ emb_all,
    float* __restrict__ bdf,      float* __restrict__ bcat,
    float* __restrict__ binit)
{
    const int blk = blockIdx.x, tid = threadIdx.x;
    if (blk < PB0) {
        cast4(W_enc, Wenc_bf, blk * 1024 + tid * 4);
    } else if (blk < PB1) {
        int i4 = (blk - PB0) * 1024 + tid * 4;
        int n = i4 >> 11, k = i4 & 2047;
        const float* src = (n < H_) ? W_init_h + (size_t)n * ENC_ + k
                                    : W_init_c + (size_t)(n - H_) * ENC_ + k;
        cast4p(src, Winit_bf, i4);
    } else if (blk < PB2) {
        cast4(W_fc, Wfc_bf, (blk - PB1) * 1024 + tid * 4);
    } else if (blk < PB3) {
        int i4 = (blk - PB2) * 1024 + tid * 4;
        int n = i4 >> 9, k = i4 & 511;
        const float* src = (n < A_) ? W_dec + (size_t)n * H_ + k
                                    : W_fbeta + (size_t)(n - A_) * H_ + k;
        cast4p(src, Wdf_bf, i4);
    } else if (blk < PB4) {
        int i4 = (blk - PB3) * 1024 + tid * 4;
        int n = i4 / XK_, k = i4 - n * XK_;
        int srow = (n & 3) * H_ + (n >> 2);
        const float* src = (k < E_ + ENC_) ? W_ih + (size_t)srow * (E_ + ENC_) + k
                                           : W_hh + (size_t)srow * H_ + (k - (E_ + ENC_));
        cast4p(src, Wcat_bf, i4);
    } else if (blk < PB5) {
        int i4 = (blk - PB4) * 1024 + tid * 4;
        int col = i4 & 511;
        int bt  = i4 >> 9;
        int b   = bt & 127;
        int tt  = bt >> 7;
        int tok = captions[b * (T_ + 1) + tt];
        cast4p(emb_tab + (size_t)tok * E_ + col, emb_all, i4);
    } else if (blk < PB6) {
        int j = (blk - PB5) * 1024 + tid * 4;
        #pragma unroll
        for (int q = 0; q < 4; q++, j++)
            if (j < NDF_) bdf[j] = (j < A_) ? b_dec[j] : b_fbeta[j - A_];
    } else if (blk < PB7) {
        int j = (blk - PB6) * 1024 + tid * 4;
        #pragma unroll
        for (int q = 0; q < 4; q++, j++) {
            int srow = (j & 3) * H_ + (j >> 2);
            bcat[j] = b_ih[srow] + b_hh[srow];
        }
    } else {
        int j = tid * 4;
        #pragma unroll
        for (int q = 0; q < 4; q++, j++)
            binit[j] = (j < H_) ? b_init_h[j] : b_init_c[j - H_];
    }
}

extern "C" void kernel_launch(void* const* d_in, const int* in_sizes, int n_in,
                              void* d_out, int out_size, void* d_ws, size_t ws_size,
                              hipStream_t stream)
{
    const float* enc      = (const float*)d_in[0];
    const int*   captions = (const int*)  d_in[1];
    const int*   lengths  = (const int*)  d_in[2];
    const float* W_enc    = (const float*)d_in[3];
    const float* b_enc    = (const float*)d_in[4];
    const float* W_dec    = (const float*)d_in[5];
    const float* b_dec    = (const float*)d_in[6];
    const float* w_full   = (const float*)d_in[7];
    const float* emb_tab  = (const float*)d_in[9];
    const float* W_ih     = (const float*)d_in[10];
    const float* b_ih     = (const float*)d_in[11];
    const float* W_hh     = (const float*)d_in[12];
    const float* b_hh     = (const float*)d_in[13];
    const float* W_init_h = (const float*)d_in[14];
    const float* b_init_h = (const float*)d_in[15];
    const float* W_init_c = (const float*)d_in[16];
    const float* b_init_c = (const float*)d_in[17];
    const float* W_fbeta  = (const float*)d_in[18];
    const float* b_fbeta  = (const float*)d_in[19];
    const float* W_fc     = (const float*)d_in[20];
    const float* b_fc     = (const float*)d_in[21];
    float* out = (float*)d_out;

    char* ws = (char*)d_ws;
    size_t off = 0;
    auto alloc = [&](size_t bytes) { void* p = ws + off; off += (bytes + 255) & ~(size_t)255; return p; };
    short* enc_bf    = (short*)alloc((size_t)B_ * P_ * ENC_ * 2);
    short* att1_bf   = (short*)alloc((size_t)B_ * P_ * A_ * 2);
    short* Wenc_bf   = (short*)alloc((size_t)A_ * ENC_ * 2);
    short* Winit_bf  = (short*)alloc((size_t)2 * H_ * ENC_ * 2);
    short* Wdf_bf    = (short*)alloc((size_t)NDF_ * H_ * 2);
    short* Wcat_bf   = (short*)alloc((size_t)4 * H_ * XK_ * 2);
    short* Wfc_bf    = (short*)alloc((size_t)V_ * H_ * 2);
    float* bdf       = (float*)alloc(NDF_ * 4);
    float* bcat      = (float*)alloc(4 * H_ * 4);
    float* binit     = (float*)alloc(2 * H_ * 4);
    short* meanE_bf  = (short*)alloc((size_t)B_ * ENC_ * 2);
    float* cbuf      = (float*)alloc((size_t)B_ * H_ * 4);
    short* hbufs     = (short*)alloc((size_t)2 * B_ * H_ * 2);
    short* emb_all   = (short*)alloc((size_t)T_ * B_ * E_ * 2);
    short* hn_all    = (short*)alloc((size_t)T_ * B_ * H_ * 2);
    float* attf      = (float*)alloc((size_t)B_ * NDF_ * 4);
    short* ctxbuf    = (short*)alloc((size_t)B_ * ENC_ * 2);
    float* gates_pre = (float*)alloc((size_t)T_ * B_ * 4 * H_ * 4);  // 21 MB
    (void)ws_size;

    // ---- one-time prep
    prep_kernel<<<PB8, 256, 0, stream>>>(
        W_enc, W_init_h, W_init_c, W_fc, W_dec, W_fbeta, W_ih, W_hh,
        captions, emb_tab, b_dec, b_fbeta, b_ih, b_hh, b_init_h, b_init_c,
        Wenc_bf, Winit_bf, Wfc_bf, Wdf_bf, Wcat_bf, emb_all, bdf, bcat, binit);
    castenc_mean<<<dim3(2, B_), 256, 0, stream>>>(enc, enc_bf, meanE_bf);
    // att1 = enc_bf @ W_enc^T + b_enc -> bf16; BM=64 tile (occupancy for latency)
    gemm_bf64<<<8 * 8 * ((392 + 7) / 8), 256, 0, stream>>>(
        enc_bf, Wenc_bf, att1_bf, b_enc,
        A_, ENC_, ENC_, ENC_, A_, 392, 8);
    // gates_pre[T*B, 2048] = emb_all @ Wcat[:, :512]^T + bcat  (fp32)
    gemm_bf<<<8 * 32 * (((T_ * B_) / BM + 7) / 8), 256, 0, stream>>>(
        emb_all, Wcat_bf, gates_pre, nullptr, bcat,
        4 * H_, E_, E_, XK_, 4 * H_, (T_ * B_) / BM, 32, 0, nullptr);
    // h0 -> hbufs[0] (bf16) and c0 -> cbuf (fp32) in ONE GEMM (mode 2)
    gemm_bf<<<(2 * H_) / BN, 256, 0, stream>>>(
        meanE_bf, Winit_bf, cbuf, hbufs, binit,
        2 * H_, ENC_, ENC_, ENC_, 0, 1, (2 * H_) / BN, 2, nullptr);

    for (int t = 0; t < T_; t++) {
        short* hcur = hbufs + (size_t)(t & 1) * B_ * H_;
        short* hnxt = hbufs + (size_t)((t & 1) ^ 1) * B_ * H_;
        // attf = h @ [W_dec|W_fbeta]^T + [b_dec|b_fbeta]   (MFMA GEMM)
        gemm_bf<<<NDF_ / BN, 256, 0, stream>>>(
            hcur, Wdf_bf, attf, nullptr, bdf,
            NDF_, H_, H_, H_, NDF_, 1, NDF_ / BN, 0, nullptr);
        esmctx_kernel<<<dim3(2, B_), 512, 0, stream>>>(
            att1_bf, attf, w_full, enc_bf, ctxbuf, lengths, t);
        gates_lstm<<<(4 * H_) / BN, 256, 0, stream>>>(
            ctxbuf, hcur, hnxt, Wcat_bf, gates_pre + (size_t)t * B_ * 4 * H_,
            cbuf, hn_all + (size_t)t * B_ * H_, lengths, t);
    }
    // pred: [T*B, V] in one GEMM, remapped to out[b][t][:] with mask
    gemm_bf<<<8 * 157 * (((T_ * B_) / BM + 7) / 8), 256, 0, stream>>>(
        hn_all, Wfc_bf, out, nullptr, b_fc,
        V_, H_, H_, H_, 0, (T_ * B_) / BM, 157, 1, lengths);
}

// Round 12
// 1590.772 us; speedup vs baseline: 2.1329x; 1.1438x over previous
//
#include <hip/hip_runtime.h>
#include <hip/hip_bf16.h>
#include <math.h>

#define B_   128
#define P_   196
#define ENC_ 2048
#define A_   512
#define H_   512
#define E_   512
#define V_   10000
#define T_   20
#define NDF_ 2560   /* [W_dec rows 0..511 | W_fbeta rows 512..2559] */
#define XK_  3072   /* Wcat K: E + ENC + H */
#define GK_  2560   /* per-step gates K: ENC + H (emb part precomputed) */

typedef __attribute__((ext_vector_type(8))) short bf16x8;
typedef __attribute__((ext_vector_type(4))) short bf16x4;
typedef __attribute__((ext_vector_type(2))) short bf16x2;
typedef __attribute__((ext_vector_type(4))) float f32x4;

__device__ __forceinline__ float sigmoidf_(float x) { return 1.0f / (1.0f + expf(-x)); }

__device__ __forceinline__ short f2bf(float f) {
    unsigned u = __float_as_uint(f);
    u += 0x7fffu + ((u >> 16) & 1u);
    return (short)(u >> 16);
}
__device__ __forceinline__ float bf2f(short s) {
    return __uint_as_float(((unsigned)(unsigned short)s) << 16);
}
__device__ __forceinline__ void gload_lds16(const void* g, void* l) {
    __builtin_amdgcn_global_load_lds(
        (const __attribute__((address_space(1))) void*)g,
        (__attribute__((address_space(3))) void*)l, 16, 0, 0);
}

#define BM 128
#define BN 64
#define BK 64

// shared MFMA inner compute: 64-K slab from As/Bs (XOR-swizzled layout)
#define COMPUTE64(ASP, BSP, CUR)                                               \
    _Pragma("unroll")                                                          \
    for (int kk = 0; kk < BK; kk += 32) {                                      \
        const int kb = (kk >> 3) + (lane >> 4);                                \
        bf16x8 av[4], bv[2];                                                   \
        _Pragma("unroll")                                                      \
        for (int i = 0; i < 4; i++) {                                          \
            int rr = wr * 64 + i * 16 + (lane & 15);                           \
            av[i] = *(const bf16x8*)&(ASP)[(CUR) * (BM * BK) + rr * BK         \
                    + ((kb ^ (rr & 7)) << 3)];                                 \
        }                                                                      \
        _Pragma("unroll")                                                      \
        for (int j = 0; j < 2; j++) {                                          \
            int cc = wc * 32 + j * 16 + (lane & 15);                           \
            bv[j] = *(const bf16x8*)&(BSP)[(CUR) * (BN * BK) + cc * BK         \
                    + ((kb ^ (cc & 7)) << 3)];                                 \
        }                                                                      \
        _Pragma("unroll")                                                      \
        for (int i = 0; i < 4; i++)                                            \
            _Pragma("unroll")                                                  \
            for (int j = 0; j < 2; j++)                                        \
                acc[i][j] = __builtin_amdgcn_mfma_f32_16x16x32_bf16(           \
                    av[i], bv[j], acc[i][j], 0, 0, 0);                         \
    }

// ---------------------------------------------------------------------------
// Generic GEMM (BM=128): C[M,N] = A_bf16 @ B_bf16^T + bias
// mode 0: plain store; mode 1: pred remap (length-masked); mode 2: init split.
// ---------------------------------------------------------------------------
__global__ __launch_bounds__(256) void gemm_bf(
    const short* __restrict__ A, const short* __restrict__ Bw,
    float* __restrict__ Cf, short* __restrict__ Cb,
    const float* __restrict__ bias,
    int N, int K, int lda, int ldb, int ldc,
    int mtiles, int ntiles, int mode,
    const int* __restrict__ lengths)
{
    __shared__ __attribute__((aligned(16))) short As[2][BM * BK];
    __shared__ __attribute__((aligned(16))) short Bs[2][BN * BK];
    int pm, pn;
    if (mtiles == 1) { pm = 0; pn = blockIdx.x; }
    else {
        int xcd = blockIdx.x & 7, s = blockIdx.x >> 3;
        pn = s % ntiles;
        pm = (s / ntiles) * 8 + xcd;
        if (pm >= mtiles) return;
    }
    const int bm = pm * BM, bn = pn * BN;
    const int tid = threadIdx.x, w = tid >> 6, lane = tid & 63;
    const int wr = w >> 1, wc = w & 1;
    const int lr8 = lane >> 3, lk = lane & 7;

    f32x4 zero4 = {0.f, 0.f, 0.f, 0.f};
    f32x4 acc[4][2];
    #pragma unroll
    for (int i = 0; i < 4; i++)
        #pragma unroll
        for (int j = 0; j < 2; j++) acc[i][j] = zero4;

#define STAGE(buf, k0) {                                                        \
    _Pragma("unroll")                                                           \
    for (int i = 0; i < 4; i++) {                                               \
        int row0 = w * 32 + i * 8; int row = row0 + lr8;                        \
        gload_lds16(A + (size_t)(bm + row) * lda + (k0)                         \
                    + ((lk ^ (row & 7)) << 3), &As[buf][row0 * BK]);            \
    }                                                                           \
    _Pragma("unroll")                                                           \
    for (int i = 0; i < 2; i++) {                                               \
        int row0 = w * 16 + i * 8; int row = row0 + lr8;                        \
        int gn = bn + row; if (gn > N - 1) gn = N - 1;                          \
        gload_lds16(Bw + (size_t)gn * ldb + (k0)                                \
                    + ((lk ^ (row & 7)) << 3), &Bs[buf][row0 * BK]);            \
    } }

    STAGE(0, 0);
    __syncthreads();
    int cur = 0;
    for (int k0 = 0; k0 < K; k0 += BK) {
        if (k0 + BK < K) STAGE(cur ^ 1, k0 + BK);
        COMPUTE64(&As[0][0], &Bs[0][0], cur);
        __syncthreads();
        cur ^= 1;
    }
#undef STAGE

    const int lr = lane >> 4, lc = lane & 15;
    #pragma unroll
    for (int i = 0; i < 4; i++) {
        #pragma unroll
        for (int r = 0; r < 4; r++) {
            int row = bm + wr * 64 + i * 16 + lr * 4 + r;
            #pragma unroll
            for (int j = 0; j < 2; j++) {
                int col = bn + wc * 32 + j * 16 + lc;
                if (col >= N) continue;
                float v = acc[i][j][r] + bias[col];
                if (mode == 1) {
                    int tt = row >> 7, bb = row & 127;
                    float rs = (tt < lengths[bb] - 1) ? 1.0f : 0.0f;
                    Cf[(size_t)bb * T_ * V_ + (size_t)tt * V_ + col] = v * rs;
                } else if (mode == 2) {
                    if (col < H_) Cb[(size_t)row * H_ + col] = f2bf(v);
                    else          Cf[(size_t)row * H_ + (col - H_)] = v;
                } else if (Cb) {
                    Cb[(size_t)row * ldc + col] = f2bf(v);
                } else {
                    Cf[(size_t)row * ldc + col] = v;
                }
            }
        }
    }
}

// ---------------------------------------------------------------------------
// BM=64 GEMM for latency-bound shapes (att1, attf): 32 KB LDS, bf16 out,
// XCD-grouped decode.
// ---------------------------------------------------------------------------
__global__ __launch_bounds__(256) void gemm_bf64(
    const short* __restrict__ A, const short* __restrict__ Bw,
    short* __restrict__ Cb, const float* __restrict__ bias,
    int N, int K, int lda, int ldb, int ldc,
    int mtiles, int ntiles)
{
    __shared__ __attribute__((aligned(16))) short As[2][64 * BK];
    __shared__ __attribute__((aligned(16))) short Bs[2][BN * BK];
    int xcd = blockIdx.x & 7, s = blockIdx.x >> 3;
    int pn = s % ntiles;
    int pm = (s / ntiles) * 8 + xcd;
    if (pm >= mtiles) return;
    const int bm = pm * 64, bn = pn * BN;
    const int tid = threadIdx.x, w = tid >> 6, lane = tid & 63;
    const int wr = w >> 1, wc = w & 1;
    const int lr8 = lane >> 3, lk = lane & 7;

    f32x4 zero4 = {0.f, 0.f, 0.f, 0.f};
    f32x4 acc[2][2];
    #pragma unroll
    for (int i = 0; i < 2; i++)
        #pragma unroll
        for (int j = 0; j < 2; j++) acc[i][j] = zero4;

#define STAGE64(buf, k0) {                                                      \
    _Pragma("unroll")                                                           \
    for (int i = 0; i < 2; i++) {                                               \
        int row0 = w * 16 + i * 8; int row = row0 + lr8;                        \
        gload_lds16(A + (size_t)(bm + row) * lda + (k0)                         \
                    + ((lk ^ (row & 7)) << 3), &As[buf][row0 * BK]);            \
    }                                                                           \
    _Pragma("unroll")                                                           \
    for (int i = 0; i < 2; i++) {                                               \
        int row0 = w * 16 + i * 8; int row = row0 + lr8;                        \
        int gn = bn + row; if (gn > N - 1) gn = N - 1;                          \
        gload_lds16(Bw + (size_t)gn * ldb + (k0)                                \
                    + ((lk ^ (row & 7)) << 3), &Bs[buf][row0 * BK]);            \
    } }

    STAGE64(0, 0);
    __syncthreads();
    int cur = 0;
    for (int k0 = 0; k0 < K; k0 += BK) {
        if (k0 + BK < K) STAGE64(cur ^ 1, k0 + BK);
        #pragma unroll
        for (int kk = 0; kk < BK; kk += 32) {
            const int kb = (kk >> 3) + (lane >> 4);
            bf16x8 av[2], bv[2];
            #pragma unroll
            for (int i = 0; i < 2; i++) {
                int rr = wr * 32 + i * 16 + (lane & 15);
                av[i] = *(const bf16x8*)&As[cur][rr * BK + ((kb ^ (rr & 7)) << 3)];
            }
            #pragma unroll
            for (int j = 0; j < 2; j++) {
                int cc = wc * 32 + j * 16 + (lane & 15);
                bv[j] = *(const bf16x8*)&Bs[cur][cc * BK + ((kb ^ (cc & 7)) << 3)];
            }
            #pragma unroll
            for (int i = 0; i < 2; i++)
                #pragma unroll
                for (int j = 0; j < 2; j++)
                    acc[i][j] = __builtin_amdgcn_mfma_f32_16x16x32_bf16(
                        av[i], bv[j], acc[i][j], 0, 0, 0);
        }
        __syncthreads();
        cur ^= 1;
    }
#undef STAGE64

    const int lr = lane >> 4, lc = lane & 15;
    #pragma unroll
    for (int i = 0; i < 2; i++)
        #pragma unroll
        for (int r = 0; r < 4; r++) {
            int row = bm + wr * 32 + i * 16 + lr * 4 + r;
            #pragma unroll
            for (int j = 0; j < 2; j++) {
                int col = bn + wc * 32 + j * 16 + lc;
                if (col < N) Cb[(size_t)row * ldc + col] = f2bf(acc[i][j][r] + bias[col]);
            }
        }
}

// ---------------------------------------------------------------------------
// fused e + softmax + context; grid (2, B), 512 threads. attf is bf16.
// Skips masked b.
// ---------------------------------------------------------------------------
__global__ __launch_bounds__(512) void esmctx_kernel(
    const short* __restrict__ att1_bf, const short* __restrict__ attf_bf,
    const float* __restrict__ wfull, const short* __restrict__ enc_bf,
    short* __restrict__ ctxbuf, const int* __restrict__ lengths, int t)
{
    __shared__ float es[P_];
    __shared__ float red[256];
    __shared__ float al[P_];
    __shared__ float sm, ss;
    const int b = blockIdx.y, half = blockIdx.x;
    if (t >= lengths[b] - 1) return;
    const int tid = threadIdx.x, wv = tid >> 6, lane = tid & 63;

    float a2v[8], wv8[8];
    {
        bf16x8 a2x = *(const bf16x8*)(attf_bf + (size_t)b * NDF_ + lane * 8);
        #pragma unroll
        for (int i = 0; i < 8; i++) {
            a2v[i] = bf2f(a2x[i]);
            wv8[i] = wfull[lane * 8 + i];
        }
    }
    for (int row = wv; row < P_; row += 8) {
        bf16x8 a1 = *(const bf16x8*)(att1_bf + ((size_t)b * P_ + row) * A_ + lane * 8);
        float s = 0.0f;
        #pragma unroll
        for (int i = 0; i < 8; i++) {
            float v = bf2f(a1[i]) + a2v[i];
            s += fmaxf(v, 0.0f) * wv8[i];
        }
        #pragma unroll
        for (int off = 32; off > 0; off >>= 1) s += __shfl_down(s, off, 64);
        if (lane == 0) es[row] = s;
    }
    __syncthreads();
    float v = (tid < P_) ? es[tid] : -1e30f;
    if (tid < 256) red[tid] = v;
    __syncthreads();
    for (int rs = 128; rs > 0; rs >>= 1) {
        if (tid < rs) red[tid] = fmaxf(red[tid], red[tid + rs]);
        __syncthreads();
    }
    if (tid == 0) sm = red[0];
    __syncthreads();
    float ex = (tid < P_) ? expf(v - sm) : 0.0f;
    if (tid < 256) red[tid] = ex;
    __syncthreads();
    for (int rs = 128; rs > 0; rs >>= 1) {
        if (tid < rs) red[tid] += red[tid + rs];
        __syncthreads();
    }
    if (tid == 0) ss = red[0];
    __syncthreads();
    if (tid < P_) al[tid] = ex / ss;
    __syncthreads();

    const int c0 = half * 1024 + tid * 2;
    const short* eb = enc_bf + (size_t)b * P_ * ENC_ + c0;
    float s0 = 0, s1 = 0;
    for (int p = 0; p < P_; p++) {
        bf16x2 ev = *(const bf16x2*)(eb + (size_t)p * ENC_);
        float a = al[p];
        s0 += a * bf2f(ev[0]); s1 += a * bf2f(ev[1]);
    }
    const short* fb = attf_bf + (size_t)b * NDF_ + A_;
    bf16x2 o;
    o[0] = f2bf(sigmoidf_(bf2f(fb[c0 + 0])) * s0);
    o[1] = f2bf(sigmoidf_(bf2f(fb[c0 + 1])) * s1);
    *(bf16x2*)(ctxbuf + (size_t)b * ENC_ + c0) = o;
}

// ---------------------------------------------------------------------------
// gates GEMM with BM=64 (64 blocks = 2 M-tiles x 32 N-tiles) + LSTM epilogue.
// K=2560 streams from {ctxbuf | hcur}; gpre holds emb@W + bias (fp32).
// ---------------------------------------------------------------------------
__global__ __launch_bounds__(256) void gates_lstm64(
    const short* __restrict__ ctxbuf, const short* __restrict__ hcur,
    short* __restrict__ hnxt,
    const short* __restrict__ Wcat, const float* __restrict__ gpre,
    float* __restrict__ cbuf, short* __restrict__ hn_t,
    const int* __restrict__ lengths, int t)
{
    __shared__ __attribute__((aligned(16))) char smem[32768];
    short* As0 = (short*)smem;                 // [2][64*64] = 16 KB
    short* Bs0 = (short*)(smem + 16384);       // [2][64*64] = 16 KB
    const int pm = blockIdx.x & 1, pn = blockIdx.x >> 1;
    const int bm = pm * 64, bn = pn * BN;
    const int tid = threadIdx.x, w = tid >> 6, lane = tid & 63;
    const int wr = w >> 1, wc = w & 1;
    const int lr8 = lane >> 3, lk = lane & 7;

    f32x4 zero4 = {0.f, 0.f, 0.f, 0.f};
    f32x4 acc[2][2];
    #pragma unroll
    for (int i = 0; i < 2; i++)
        #pragma unroll
        for (int j = 0; j < 2; j++) acc[i][j] = zero4;

#define STAGE_G64(buf, k0) {                                                    \
    const short* Ap; int Al, kk0;                                               \
    if ((k0) < ENC_) { Ap = ctxbuf; Al = ENC_; kk0 = (k0); }                    \
    else             { Ap = hcur;   Al = H_;   kk0 = (k0) - ENC_; }             \
    _Pragma("unroll")                                                           \
    for (int i = 0; i < 2; i++) {                                               \
        int row0 = w * 16 + i * 8; int row = row0 + lr8;                        \
        gload_lds16(Ap + (size_t)(bm + row) * Al + kk0                          \
                    + ((lk ^ (row & 7)) << 3),                                  \
                    &As0[(buf) * 4096 + row0 * BK]);                            \
    }                                                                           \
    _Pragma("unroll")                                                           \
    for (int i = 0; i < 2; i++) {                                               \
        int row0 = w * 16 + i * 8; int row = row0 + lr8;                        \
        gload_lds16(Wcat + (size_t)(bn + row) * XK_ + E_ + (k0)                 \
                    + ((lk ^ (row & 7)) << 3),                                  \
                    &Bs0[(buf) * 4096 + row0 * BK]);                            \
    } }

    STAGE_G64(0, 0);
    __syncthreads();
    int cur = 0;
    for (int k0 = 0; k0 < GK_; k0 += BK) {
        if (k0 + BK < GK_) STAGE_G64(cur ^ 1, k0 + BK);
        #pragma unroll
        for (int kk = 0; kk < BK; kk += 32) {
            const int kb = (kk >> 3) + (lane >> 4);
            bf16x8 av[2], bv[2];
            #pragma unroll
            for (int i = 0; i < 2; i++) {
                int rr = wr * 32 + i * 16 + (lane & 15);
                av[i] = *(const bf16x8*)&As0[cur * 4096 + rr * BK + ((kb ^ (rr & 7)) << 3)];
            }
            #pragma unroll
            for (int j = 0; j < 2; j++) {
                int cc = wc * 32 + j * 16 + (lane & 15);
                bv[j] = *(const bf16x8*)&Bs0[cur * 4096 + cc * BK + ((kb ^ (cc & 7)) << 3)];
            }
            #pragma unroll
            for (int i = 0; i < 2; i++)
                #pragma unroll
                for (int j = 0; j < 2; j++)
                    acc[i][j] = __builtin_amdgcn_mfma_f32_16x16x32_bf16(
                        av[i], bv[j], acc[i][j], 0, 0, 0);
        }
        __syncthreads();
        cur ^= 1;
    }
#undef STAGE_G64

    float* gl = (float*)smem;     // 64*68*4 = 17408 B (As/Bs dead)
    const int lr = lane >> 4, lc = lane & 15;
    #pragma unroll
    for (int i = 0; i < 2; i++)
        #pragma unroll
        for (int r = 0; r < 4; r++) {
            int row = wr * 32 + i * 16 + lr * 4 + r;         // local 0..63
            #pragma unroll
            for (int j = 0; j < 2; j++) {
                int col = wc * 32 + j * 16 + lc;
                gl[row * 68 + col] = acc[i][j][r]
                    + gpre[(size_t)(bm + row) * (4 * H_) + bn + col];
            }
        }
    __syncthreads();
    #pragma unroll
    for (int q = 0; q < 4; q++) {
        int id    = tid * 4 + q;      // 0..1023
        int row_l = id >> 4;          // local batch row 0..63
        int j     = id & 15;          // local hidden unit
        int row_g = bm + row_l;       // global batch
        int jg    = (bn >> 2) + j;    // global hidden index
        float i_ = sigmoidf_(gl[row_l * 68 + 4 * j + 0]);
        float f_ = sigmoidf_(gl[row_l * 68 + 4 * j + 1]);
        float g_ = tanhf    (gl[row_l * 68 + 4 * j + 2]);
        float o_ = sigmoidf_(gl[row_l * 68 + 4 * j + 3]);
        float cn = f_ * cbuf[row_g * H_ + jg] + i_ * g_;
        float hv = o_ * tanhf(cn);
        hn_t[row_g * H_ + jg] = f2bf(hv);
        bool m = t < lengths[row_g] - 1;
        if (m) cbuf[row_g * H_ + jg] = cn;
        hnxt[row_g * H_ + jg] = m ? f2bf(hv) : hcur[row_g * H_ + jg];
    }
}

// ---------------------------------------------------------------------------
// Fused enc cast + mean; non-temporal fp32 reads (keep enc_bf L3-resident).
// ---------------------------------------------------------------------------
__global__ __launch_bounds__(256) void castenc_mean(const float* __restrict__ enc,
                                                    short* __restrict__ enc_bf,
                                                    short* __restrict__ meanE_bf)
{
    const int b = blockIdx.y;
    const int c0 = blockIdx.x * 1024 + threadIdx.x * 4;
    const f32x4* src = (const f32x4*)(enc + (size_t)b * P_ * ENC_ + c0);
    short* dst = enc_bf + (size_t)b * P_ * ENC_ + c0;
    float s0 = 0, s1 = 0, s2 = 0, s3 = 0;
    for (int p = 0; p < P_; p++) {
        f32x4 f = __builtin_nontemporal_load(src + (size_t)p * (ENC_ / 4));
        bf16x4 v;
        v[0] = f2bf(f[0]); v[1] = f2bf(f[1]); v[2] = f2bf(f[2]); v[3] = f2bf(f[3]);
        *(bf16x4*)(dst + (size_t)p * ENC_) = v;
        s0 += f[0]; s1 += f[1]; s2 += f[2]; s3 += f[3];
    }
    const float inv = 1.0f / (float)P_;
    bf16x4 m;
    m[0] = f2bf(s0 * inv); m[1] = f2bf(s1 * inv);
    m[2] = f2bf(s2 * inv); m[3] = f2bf(s3 * inv);
    *(bf16x4*)(meanE_bf + (size_t)b * ENC_ + c0) = m;
}

// ---------------------------------------------------------------------------
// Mega-prep: all weight casts/concats/biases/embedding in ONE kernel.
// ---------------------------------------------------------------------------
#define PB0 1024               /* W_enc cast: 512*2048          */
#define PB1 (PB0 + 2048)       /* Winit cat : 1024*2048         */
#define PB2 (PB1 + 5000)       /* W_fc cast : 10000*512         */
#define PB3 (PB2 + 1280)       /* Wdf cat   : 2560*512          */
#define PB4 (PB3 + 6144)       /* Wcat      : 2048*3072         */
#define PB5 (PB4 + 1280)       /* emb_all   : 20*128*512        */
#define PB6 (PB5 + 3)          /* bdf 2560                      */
#define PB7 (PB6 + 2)          /* bcat 2048                     */
#define PB8 (PB7 + 1)          /* binit 1024                    */

__device__ __forceinline__ void cast4(const float* __restrict__ in,
                                      short* __restrict__ out, int i4) {
    float4 f = *(const float4*)(in + i4);
    bf16x4 v;
    v[0] = f2bf(f.x); v[1] = f2bf(f.y); v[2] = f2bf(f.z); v[3] = f2bf(f.w);
    *(bf16x4*)(out + i4) = v;
}
__device__ __forceinline__ void cast4p(const float* __restrict__ src,
                                       short* __restrict__ out, int i4) {
    float4 f = *(const float4*)src;
    bf16x4 v;
    v[0] = f2bf(f.x); v[1] = f2bf(f.y); v[2] = f2bf(f.z); v[3] = f2bf(f.w);
    *(bf16x4*)(out + i4) = v;
}

__global__ __launch_bounds__(256) void prep_kernel(
    const float* __restrict__ W_enc,    const float* __restrict__ W_init_h,
    const float* __restrict__ W_init_c, const float* __restrict__ W_fc,
    const float* __restrict__ W_dec,    const float* __restrict__ W_fbeta,
    const float* __restrict__ W_ih,     const float* __restrict__ W_hh,
    const int*   __restrict__ captions, const float* __restrict__ emb_tab,
    const float* __restrict__ b_dec,    const float* __restrict__ b_fbeta,
    const float* __restrict__ b_ih,     const float* __restrict__ b_hh,
    const float* __restrict__ b_init_h, const float* __restrict__ b_init_c,
    short* __restrict__ Wenc_bf,  short* __restrict__ Winit_bf,
    short* __restrict__ Wfc_bf,   short* __restrict__ Wdf_bf,
    short* __restrict__ Wcat_bf,  short* __restrict__ emb_all,
    float* __restrict__ bdf,      float* __restrict__ bcat,
    float* __restrict__ binit)
{
    const int blk = blockIdx.x, tid = threadIdx.x;
    if (blk < PB0) {
        cast4(W_enc, Wenc_bf, blk * 1024 + tid * 4);
    } else if (blk < PB1) {
        int i4 = (blk - PB0) * 1024 + tid * 4;
        int n = i4 >> 11, k = i4 & 2047;
        const float* src = (n < H_) ? W_init_h + (size_t)n * ENC_ + k
                                    : W_init_c + (size_t)(n - H_) * ENC_ + k;
        cast4p(src, Winit_bf, i4);
    } else if (blk < PB2) {
        cast4(W_fc, Wfc_bf, (blk - PB1) * 1024 + tid * 4);
    } else if (blk < PB3) {
        int i4 = (blk - PB2) * 1024 + tid * 4;
        int n = i4 >> 9, k = i4 & 511;
        const float* src = (n < A_) ? W_dec + (size_t)n * H_ + k
                                    : W_fbeta + (size_t)(n - A_) * H_ + k;
        cast4p(src, Wdf_bf, i4);
    } else if (blk < PB4) {
        int i4 = (blk - PB3) * 1024 + tid * 4;
        int n = i4 / XK_, k = i4 - n * XK_;
        int srow = (n & 3) * H_ + (n >> 2);
        const float* src = (k < E_ + ENC_) ? W_ih + (size_t)srow * (E_ + ENC_) + k
                                           : W_hh + (size_t)srow * H_ + (k - (E_ + ENC_));
        cast4p(src, Wcat_bf, i4);
    } else if (blk < PB5) {
        int i4 = (blk - PB4) * 1024 + tid * 4;
        int col = i4 & 511;
        int bt  = i4 >> 9;
        int b   = bt & 127;
        int tt  = bt >> 7;
        int tok = captions[b * (T_ + 1) + tt];
        cast4p(emb_tab + (size_t)tok * E_ + col, emb_all, i4);
    } else if (blk < PB6) {
        int j = (blk - PB5) * 1024 + tid * 4;
        #pragma unroll
        for (int q = 0; q < 4; q++, j++)
            if (j < NDF_) bdf[j] = (j < A_) ? b_dec[j] : b_fbeta[j - A_];
    } else if (blk < PB7) {
        int j = (blk - PB6) * 1024 + tid * 4;
        #pragma unroll
        for (int q = 0; q < 4; q++, j++) {
            int srow = (j & 3) * H_ + (j >> 2);
            bcat[j] = b_ih[srow] + b_hh[srow];
        }
    } else {
        int j = tid * 4;
        #pragma unroll
        for (int q = 0; q < 4; q++, j++)
            binit[j] = (j < H_) ? b_init_h[j] : b_init_c[j - H_];
    }
}

extern "C" void kernel_launch(void* const* d_in, const int* in_sizes, int n_in,
                              void* d_out, int out_size, void* d_ws, size_t ws_size,
                              hipStream_t stream)
{
    const float* enc      = (const float*)d_in[0];
    const int*   captions = (const int*)  d_in[1];
    const int*   lengths  = (const int*)  d_in[2];
    const float* W_enc    = (const float*)d_in[3];
    const float* b_enc    = (const float*)d_in[4];
    const float* W_dec    = (const float*)d_in[5];
    const float* b_dec    = (const float*)d_in[6];
    const float* w_full   = (const float*)d_in[7];
    const float* emb_tab  = (const float*)d_in[9];
    const float* W_ih     = (const float*)d_in[10];
    const float* b_ih     = (const float*)d_in[11];
    const float* W_hh     = (const float*)d_in[12];
    const float* b_hh     = (const float*)d_in[13];
    const float* W_init_h = (const float*)d_in[14];
    const float* b_init_h = (const float*)d_in[15];
    const float* W_init_c = (const float*)d_in[16];
    const float* b_init_c = (const float*)d_in[17];
    const float* W_fbeta  = (const float*)d_in[18];
    const float* b_fbeta  = (const float*)d_in[19];
    const float* W_fc     = (const float*)d_in[20];
    const float* b_fc     = (const float*)d_in[21];
    float* out = (float*)d_out;

    char* ws = (char*)d_ws;
    size_t off = 0;
    auto alloc = [&](size_t bytes) { void* p = ws + off; off += (bytes + 255) & ~(size_t)255; return p; };
    short* enc_bf    = (short*)alloc((size_t)B_ * P_ * ENC_ * 2);
    short* att1_bf   = (short*)alloc((size_t)B_ * P_ * A_ * 2);
    short* Wenc_bf   = (short*)alloc((size_t)A_ * ENC_ * 2);
    short* Winit_bf  = (short*)alloc((size_t)2 * H_ * ENC_ * 2);
    short* Wdf_bf    = (short*)alloc((size_t)NDF_ * H_ * 2);
    short* Wcat_bf   = (short*)alloc((size_t)4 * H_ * XK_ * 2);
    short* Wfc_bf    = (short*)alloc((size_t)V_ * H_ * 2);
    float* bdf       = (float*)alloc(NDF_ * 4);
    float* bcat      = (float*)alloc(4 * H_ * 4);
    float* binit     = (float*)alloc(2 * H_ * 4);
    short* meanE_bf  = (short*)alloc((size_t)B_ * ENC_ * 2);
    float* cbuf      = (float*)alloc((size_t)B_ * H_ * 4);
    short* hbufs     = (short*)alloc((size_t)2 * B_ * H_ * 2);
    short* emb_all   = (short*)alloc((size_t)T_ * B_ * E_ * 2);
    short* hn_all    = (short*)alloc((size_t)T_ * B_ * H_ * 2);
    short* attf_bf   = (short*)alloc((size_t)B_ * NDF_ * 2);
    short* ctxbuf    = (short*)alloc((size_t)B_ * ENC_ * 2);
    float* gates_pre = (float*)alloc((size_t)T_ * B_ * 4 * H_ * 4);  // 21 MB
    (void)ws_size;

    // ---- one-time prep
    prep_kernel<<<PB8, 256, 0, stream>>>(
        W_enc, W_init_h, W_init_c, W_fc, W_dec, W_fbeta, W_ih, W_hh,
        captions, emb_tab, b_dec, b_fbeta, b_ih, b_hh, b_init_h, b_init_c,
        Wenc_bf, Winit_bf, Wfc_bf, Wdf_bf, Wcat_bf, emb_all, bdf, bcat, binit);
    castenc_mean<<<dim3(2, B_), 256, 0, stream>>>(enc, enc_bf, meanE_bf);
    // att1 = enc_bf @ W_enc^T + b_enc -> bf16; BM=64 (occupancy for latency)
    gemm_bf64<<<8 * 8 * ((392 + 7) / 8), 256, 0, stream>>>(
        enc_bf, Wenc_bf, att1_bf, b_enc,
        A_, ENC_, ENC_, ENC_, A_, 392, 8);
    // gates_pre[T*B, 2048] = emb_all @ Wcat[:, :512]^T + bcat  (fp32)
    gemm_bf<<<8 * 32 * (((T_ * B_) / BM + 7) / 8), 256, 0, stream>>>(
        emb_all, Wcat_bf, gates_pre, nullptr, bcat,
        4 * H_, E_, E_, XK_, 4 * H_, (T_ * B_) / BM, 32, 0, nullptr);
    // h0 -> hbufs[0] (bf16) and c0 -> cbuf (fp32) in ONE GEMM (mode 2)
    gemm_bf<<<(2 * H_) / BN, 256, 0, stream>>>(
        meanE_bf, Winit_bf, cbuf, hbufs, binit,
        2 * H_, ENC_, ENC_, ENC_, 0, 1, (2 * H_) / BN, 2, nullptr);

    for (int t = 0; t < T_; t++) {
        short* hcur = hbufs + (size_t)(t & 1) * B_ * H_;
        short* hnxt = hbufs + (size_t)((t & 1) ^ 1) * B_ * H_;
        // attf = h @ [W_dec|W_fbeta]^T + bdf -> bf16; BM=64 (2 M-tiles x 40 N)
        gemm_bf64<<<8 * 40 * 1, 256, 0, stream>>>(
            hcur, Wdf_bf, attf_bf, bdf,
            NDF_, H_, H_, H_, NDF_, 2, 40);
        esmctx_kernel<<<dim3(2, B_), 512, 0, stream>>>(
            att1_bf, attf_bf, w_full, enc_bf, ctxbuf, lengths, t);
        gates_lstm64<<<64, 256, 0, stream>>>(
            ctxbuf, hcur, hnxt, Wcat_bf, gates_pre + (size_t)t * B_ * 4 * H_,
            cbuf, hn_all + (size_t)t * B_ * H_, lengths, t);
    }
    // pred: [T*B, V] in one GEMM, remapped to out[b][t][:] with mask
    gemm_bf<<<8 * 157 * (((T_ * B_) / BM + 7) / 8), 256, 0, stream>>>(
        hn_all, Wfc_bf, out, nullptr, b_fc,
        V_, H_, H_, H_, 0, (T_ * B_) / BM, 157, 1, lengths);
}

// Round 13
// 1554.064 us; speedup vs baseline: 2.1833x; 1.0236x over previous
//
#include <hip/hip_runtime.h>
#include <hip/hip_bf16.h>
#include <math.h>

#define B_   128
#define P_   196
#define ENC_ 2048
#define A_   512
#define H_   512
#define E_   512
#define V_   10000
#define T_   20
#define NDF_ 2560   /* [W_dec rows 0..511 | W_fbeta rows 512..2559] */
#define XK_  3072   /* Wcat K: E + ENC + H */
#define GK_  2560   /* per-step gates K: ENC + H (emb part precomputed) */

typedef __attribute__((ext_vector_type(8))) short bf16x8;
typedef __attribute__((ext_vector_type(4))) short bf16x4;
typedef __attribute__((ext_vector_type(2))) short bf16x2;
typedef __attribute__((ext_vector_type(4))) float f32x4;

__device__ __forceinline__ float sigmoidf_(float x) { return 1.0f / (1.0f + expf(-x)); }

__device__ __forceinline__ short f2bf(float f) {
    unsigned u = __float_as_uint(f);
    u += 0x7fffu + ((u >> 16) & 1u);
    return (short)(u >> 16);
}
__device__ __forceinline__ float bf2f(short s) {
    return __uint_as_float(((unsigned)(unsigned short)s) << 16);
}
__device__ __forceinline__ void gload_lds16(const void* g, void* l) {
    __builtin_amdgcn_global_load_lds(
        (const __attribute__((address_space(1))) void*)g,
        (__attribute__((address_space(3))) void*)l, 16, 0, 0);
}

#define BM 128
#define BN 64
#define BK 64

// shared MFMA inner compute: 64-K slab from As/Bs (BK=64, 8-slot XOR swizzle)
#define COMPUTE64(ASP, BSP, CUR)                                               \
    _Pragma("unroll")                                                          \
    for (int kk = 0; kk < BK; kk += 32) {                                      \
        const int kb = (kk >> 3) + (lane >> 4);                                \
        bf16x8 av[4], bv[2];                                                   \
        _Pragma("unroll")                                                      \
        for (int i = 0; i < 4; i++) {                                          \
            int rr = wr * 64 + i * 16 + (lane & 15);                           \
            av[i] = *(const bf16x8*)&(ASP)[(CUR) * (BM * BK) + rr * BK         \
                    + ((kb ^ (rr & 7)) << 3)];                                 \
        }                                                                      \
        _Pragma("unroll")                                                      \
        for (int j = 0; j < 2; j++) {                                          \
            int cc = wc * 32 + j * 16 + (lane & 15);                           \
            bv[j] = *(const bf16x8*)&(BSP)[(CUR) * (BN * BK) + cc * BK         \
                    + ((kb ^ (cc & 7)) << 3)];                                 \
        }                                                                      \
        _Pragma("unroll")                                                      \
        for (int i = 0; i < 4; i++)                                            \
            _Pragma("unroll")                                                  \
            for (int j = 0; j < 2; j++)                                        \
                acc[i][j] = __builtin_amdgcn_mfma_f32_16x16x32_bf16(           \
                    av[i], bv[j], acc[i][j], 0, 0, 0);                         \
    }

// ---------------------------------------------------------------------------
// Generic GEMM (BM=128, BK=64): mode 0 plain, 1 pred-remap, 2 init-split.
// ---------------------------------------------------------------------------
__global__ __launch_bounds__(256) void gemm_bf(
    const short* __restrict__ A, const short* __restrict__ Bw,
    float* __restrict__ Cf, short* __restrict__ Cb,
    const float* __restrict__ bias,
    int N, int K, int lda, int ldb, int ldc,
    int mtiles, int ntiles, int mode,
    const int* __restrict__ lengths)
{
    __shared__ __attribute__((aligned(16))) short As[2][BM * BK];
    __shared__ __attribute__((aligned(16))) short Bs[2][BN * BK];
    int pm, pn;
    if (mtiles == 1) { pm = 0; pn = blockIdx.x; }
    else {
        int xcd = blockIdx.x & 7, s = blockIdx.x >> 3;
        pn = s % ntiles;
        pm = (s / ntiles) * 8 + xcd;
        if (pm >= mtiles) return;
    }
    const int bm = pm * BM, bn = pn * BN;
    const int tid = threadIdx.x, w = tid >> 6, lane = tid & 63;
    const int wr = w >> 1, wc = w & 1;
    const int lr8 = lane >> 3, lk = lane & 7;

    f32x4 zero4 = {0.f, 0.f, 0.f, 0.f};
    f32x4 acc[4][2];
    #pragma unroll
    for (int i = 0; i < 4; i++)
        #pragma unroll
        for (int j = 0; j < 2; j++) acc[i][j] = zero4;

#define STAGE(buf, k0) {                                                        \
    _Pragma("unroll")                                                           \
    for (int i = 0; i < 4; i++) {                                               \
        int row0 = w * 32 + i * 8; int row = row0 + lr8;                        \
        gload_lds16(A + (size_t)(bm + row) * lda + (k0)                         \
                    + ((lk ^ (row & 7)) << 3), &As[buf][row0 * BK]);            \
    }                                                                           \
    _Pragma("unroll")                                                           \
    for (int i = 0; i < 2; i++) {                                               \
        int row0 = w * 16 + i * 8; int row = row0 + lr8;                        \
        int gn = bn + row; if (gn > N - 1) gn = N - 1;                          \
        gload_lds16(Bw + (size_t)gn * ldb + (k0)                                \
                    + ((lk ^ (row & 7)) << 3), &Bs[buf][row0 * BK]);            \
    } }

    STAGE(0, 0);
    __syncthreads();
    int cur = 0;
    for (int k0 = 0; k0 < K; k0 += BK) {
        if (k0 + BK < K) STAGE(cur ^ 1, k0 + BK);
        COMPUTE64(&As[0][0], &Bs[0][0], cur);
        __syncthreads();
        cur ^= 1;
    }
#undef STAGE

    const int lr = lane >> 4, lc = lane & 15;
    #pragma unroll
    for (int i = 0; i < 4; i++) {
        #pragma unroll
        for (int r = 0; r < 4; r++) {
            int row = bm + wr * 64 + i * 16 + lr * 4 + r;
            #pragma unroll
            for (int j = 0; j < 2; j++) {
                int col = bn + wc * 32 + j * 16 + lc;
                if (col >= N) continue;
                float v = acc[i][j][r] + bias[col];
                if (mode == 1) {
                    int tt = row >> 7, bb = row & 127;
                    float rs = (tt < lengths[bb] - 1) ? 1.0f : 0.0f;
                    Cf[(size_t)bb * T_ * V_ + (size_t)tt * V_ + col] = v * rs;
                } else if (mode == 2) {
                    if (col < H_) Cb[(size_t)row * H_ + col] = f2bf(v);
                    else          Cf[(size_t)row * H_ + (col - H_)] = v;
                } else if (Cb) {
                    Cb[(size_t)row * ldc + col] = f2bf(v);
                } else {
                    Cf[(size_t)row * ldc + col] = v;
                }
            }
        }
    }
}

// ---------------------------------------------------------------------------
// BM=64 BK=64 GEMM (att1): 32 KB LDS -> 5 blocks/CU (occupancy-proven, R11).
// ---------------------------------------------------------------------------
__global__ __launch_bounds__(256) void gemm_bf64(
    const short* __restrict__ A, const short* __restrict__ Bw,
    short* __restrict__ Cb, const float* __restrict__ bias,
    int N, int K, int lda, int ldb, int ldc,
    int mtiles, int ntiles)
{
    __shared__ __attribute__((aligned(16))) short As[2][64 * BK];
    __shared__ __attribute__((aligned(16))) short Bs[2][BN * BK];
    int xcd = blockIdx.x & 7, s = blockIdx.x >> 3;
    int pn = s % ntiles;
    int pm = (s / ntiles) * 8 + xcd;
    if (pm >= mtiles) return;
    const int bm = pm * 64, bn = pn * BN;
    const int tid = threadIdx.x, w = tid >> 6, lane = tid & 63;
    const int wr = w >> 1, wc = w & 1;
    const int lr8 = lane >> 3, lk = lane & 7;

    f32x4 zero4 = {0.f, 0.f, 0.f, 0.f};
    f32x4 acc[2][2];
    #pragma unroll
    for (int i = 0; i < 2; i++)
        #pragma unroll
        for (int j = 0; j < 2; j++) acc[i][j] = zero4;

#define STAGE64(buf, k0) {                                                      \
    _Pragma("unroll")                                                           \
    for (int i = 0; i < 2; i++) {                                               \
        int row0 = w * 16 + i * 8; int row = row0 + lr8;                        \
        gload_lds16(A + (size_t)(bm + row) * lda + (k0)                         \
                    + ((lk ^ (row & 7)) << 3), &As[buf][row0 * BK]);            \
    }                                                                           \
    _Pragma("unroll")                                                           \
    for (int i = 0; i < 2; i++) {                                               \
        int row0 = w * 16 + i * 8; int row = row0 + lr8;                        \
        int gn = bn + row; if (gn > N - 1) gn = N - 1;                          \
        gload_lds16(Bw + (size_t)gn * ldb + (k0)                                \
                    + ((lk ^ (row & 7)) << 3), &Bs[buf][row0 * BK]);            \
    } }

    STAGE64(0, 0);
    __syncthreads();
    int cur = 0;
    for (int k0 = 0; k0 < K; k0 += BK) {
        if (k0 + BK < K) STAGE64(cur ^ 1, k0 + BK);
        #pragma unroll
        for (int kk = 0; kk < BK; kk += 32) {
            const int kb = (kk >> 3) + (lane >> 4);
            bf16x8 av[2], bv[2];
            #pragma unroll
            for (int i = 0; i < 2; i++) {
                int rr = wr * 32 + i * 16 + (lane & 15);
                av[i] = *(const bf16x8*)&As[cur][rr * BK + ((kb ^ (rr & 7)) << 3)];
            }
            #pragma unroll
            for (int j = 0; j < 2; j++) {
                int cc = wc * 32 + j * 16 + (lane & 15);
                bv[j] = *(const bf16x8*)&Bs[cur][cc * BK + ((kb ^ (cc & 7)) << 3)];
            }
            #pragma unroll
            for (int i = 0; i < 2; i++)
                #pragma unroll
                for (int j = 0; j < 2; j++)
                    acc[i][j] = __builtin_amdgcn_mfma_f32_16x16x32_bf16(
                        av[i], bv[j], acc[i][j], 0, 0, 0);
        }
        __syncthreads();
        cur ^= 1;
    }
#undef STAGE64

    const int lr = lane >> 4, lc = lane & 15;
    #pragma unroll
    for (int i = 0; i < 2; i++)
        #pragma unroll
        for (int r = 0; r < 4; r++) {
            int row = bm + wr * 32 + i * 16 + lr * 4 + r;
            #pragma unroll
            for (int j = 0; j < 2; j++) {
                int col = bn + wc * 32 + j * 16 + lc;
                if (col < N) Cb[(size_t)row * ldc + col] = f2bf(acc[i][j][r] + bias[col]);
            }
        }
}

// ---------------------------------------------------------------------------
// BM=64 BK=128 GEMM (attf): 4 K-iters for K=512 -> half the barrier drains.
// 16-slot XOR swizzle (sl ^ (row&15)); 2-way bank alias = free.
// ---------------------------------------------------------------------------
__global__ __launch_bounds__(256) void gemm_bf64k(
    const short* __restrict__ A, const short* __restrict__ Bw,
    short* __restrict__ Cb, const float* __restrict__ bias,
    int N, int K, int lda, int ldb, int ldc,
    int mtiles, int ntiles)
{
    __shared__ __attribute__((aligned(16))) short As[2][8192];   // 32 KB
    __shared__ __attribute__((aligned(16))) short Bs[2][8192];   // 32 KB
    int xcd = blockIdx.x & 7, s = blockIdx.x >> 3;
    int pn = s % ntiles;
    int pm = (s / ntiles) * 8 + xcd;
    if (pm >= mtiles) return;
    const int bm = pm * 64, bn = pn * 64;
    const int tid = threadIdx.x, lane = tid & 63;
    const int wr = (tid >> 6) >> 1, wc = (tid >> 6) & 1;

    f32x4 zero4 = {0.f, 0.f, 0.f, 0.f};
    f32x4 acc[2][2];
    #pragma unroll
    for (int i = 0; i < 2; i++)
        #pragma unroll
        for (int j = 0; j < 2; j++) acc[i][j] = zero4;

#define STAGEK(buf, k0) {                                                       \
    _Pragma("unroll")                                                           \
    for (int i = 0; i < 4; i++) {                                               \
        int wb  = i * 256 + (tid & ~63);                                        \
        int row = (wb >> 4) + (lane >> 4);                                      \
        int sl  = lane & 15;                                                    \
        gload_lds16(A + (size_t)(bm + row) * lda + (k0)                         \
                    + ((sl ^ (row & 15)) << 3), &As[buf][wb * 8]);              \
    }                                                                           \
    _Pragma("unroll")                                                           \
    for (int i = 0; i < 4; i++) {                                               \
        int wb  = i * 256 + (tid & ~63);                                        \
        int row = (wb >> 4) + (lane >> 4);                                      \
        int sl  = lane & 15;                                                    \
        int gn  = bn + row; if (gn > N - 1) gn = N - 1;                         \
        gload_lds16(Bw + (size_t)gn * ldb + (k0)                                \
                    + ((sl ^ (row & 15)) << 3), &Bs[buf][wb * 8]);              \
    } }

    STAGEK(0, 0);
    __syncthreads();
    int cur = 0;
    for (int k0 = 0; k0 < K; k0 += 128) {
        if (k0 + 128 < K) STAGEK(cur ^ 1, k0 + 128);
        #pragma unroll
        for (int kk = 0; kk < 128; kk += 32) {
            const int kb = (kk >> 3) + (lane >> 4);       // 0..15
            bf16x8 av[2], bv[2];
            #pragma unroll
            for (int i = 0; i < 2; i++) {
                int rr = wr * 32 + i * 16 + (lane & 15);
                av[i] = *(const bf16x8*)&As[cur][rr * 128 + ((kb ^ (rr & 15)) << 3)];
            }
            #pragma unroll
            for (int j = 0; j < 2; j++) {
                int cc = wc * 32 + j * 16 + (lane & 15);
                bv[j] = *(const bf16x8*)&Bs[cur][cc * 128 + ((kb ^ (cc & 15)) << 3)];
            }
            #pragma unroll
            for (int i = 0; i < 2; i++)
                #pragma unroll
                for (int j = 0; j < 2; j++)
                    acc[i][j] = __builtin_amdgcn_mfma_f32_16x16x32_bf16(
                        av[i], bv[j], acc[i][j], 0, 0, 0);
        }
        __syncthreads();
        cur ^= 1;
    }
#undef STAGEK

    const int lr = lane >> 4, lc = lane & 15;
    #pragma unroll
    for (int i = 0; i < 2; i++)
        #pragma unroll
        for (int r = 0; r < 4; r++) {
            int row = bm + wr * 32 + i * 16 + lr * 4 + r;
            #pragma unroll
            for (int j = 0; j < 2; j++) {
                int col = bn + wc * 32 + j * 16 + lc;
                if (col < N) Cb[(size_t)row * ldc + col] = f2bf(acc[i][j][r] + bias[col]);
            }
        }
}

// ---------------------------------------------------------------------------
// fused e + softmax + context; grid (2, B), 512 threads. attf is bf16.
// ---------------------------------------------------------------------------
__global__ __launch_bounds__(512) void esmctx_kernel(
    const short* __restrict__ att1_bf, const short* __restrict__ attf_bf,
    const float* __restrict__ wfull, const short* __restrict__ enc_bf,
    short* __restrict__ ctxbuf, const int* __restrict__ lengths, int t)
{
    __shared__ float es[P_];
    __shared__ float red[256];
    __shared__ float al[P_];
    __shared__ float sm, ss;
    const int b = blockIdx.y, half = blockIdx.x;
    if (t >= lengths[b] - 1) return;
    const int tid = threadIdx.x, wv = tid >> 6, lane = tid & 63;

    float a2v[8], wv8[8];
    {
        bf16x8 a2x = *(const bf16x8*)(attf_bf + (size_t)b * NDF_ + lane * 8);
        #pragma unroll
        for (int i = 0; i < 8; i++) {
            a2v[i] = bf2f(a2x[i]);
            wv8[i] = wfull[lane * 8 + i];
        }
    }
    for (int row = wv; row < P_; row += 8) {
        bf16x8 a1 = *(const bf16x8*)(att1_bf + ((size_t)b * P_ + row) * A_ + lane * 8);
        float s = 0.0f;
        #pragma unroll
        for (int i = 0; i < 8; i++) {
            float v = bf2f(a1[i]) + a2v[i];
            s += fmaxf(v, 0.0f) * wv8[i];
        }
        #pragma unroll
        for (int off = 32; off > 0; off >>= 1) s += __shfl_down(s, off, 64);
        if (lane == 0) es[row] = s;
    }
    __syncthreads();
    float v = (tid < P_) ? es[tid] : -1e30f;
    if (tid < 256) red[tid] = v;
    __syncthreads();
    for (int rs = 128; rs > 0; rs >>= 1) {
        if (tid < rs) red[tid] = fmaxf(red[tid], red[tid + rs]);
        __syncthreads();
    }
    if (tid == 0) sm = red[0];
    __syncthreads();
    float ex = (tid < P_) ? expf(v - sm) : 0.0f;
    if (tid < 256) red[tid] = ex;
    __syncthreads();
    for (int rs = 128; rs > 0; rs >>= 1) {
        if (tid < rs) red[tid] += red[tid + rs];
        __syncthreads();
    }
    if (tid == 0) ss = red[0];
    __syncthreads();
    if (tid < P_) al[tid] = ex / ss;
    __syncthreads();

    const int c0 = half * 1024 + tid * 2;
    const short* eb = enc_bf + (size_t)b * P_ * ENC_ + c0;
    float s0 = 0, s1 = 0;
    for (int p = 0; p < P_; p++) {
        bf16x2 ev = *(const bf16x2*)(eb + (size_t)p * ENC_);
        float a = al[p];
        s0 += a * bf2f(ev[0]); s1 += a * bf2f(ev[1]);
    }
    const short* fb = attf_bf + (size_t)b * NDF_ + A_;
    bf16x2 o;
    o[0] = f2bf(sigmoidf_(bf2f(fb[c0 + 0])) * s0);
    o[1] = f2bf(sigmoidf_(bf2f(fb[c0 + 1])) * s1);
    *(bf16x2*)(ctxbuf + (size_t)b * ENC_ + c0) = o;
}

// ---------------------------------------------------------------------------
// gates GEMM BM=64 BK=128 (20 K-iters) + fused LSTM epilogue.
// Grid 64 blocks (2 M x 32 N). gpre = emb@W + bias (fp32).
// ---------------------------------------------------------------------------
__global__ __launch_bounds__(256) void gates_lstm128(
    const short* __restrict__ ctxbuf, const short* __restrict__ hcur,
    short* __restrict__ hnxt,
    const short* __restrict__ Wcat, const float* __restrict__ gpre,
    float* __restrict__ cbuf, short* __restrict__ hn_t,
    const int* __restrict__ lengths, int t)
{
    __shared__ __attribute__((aligned(16))) short As[2][8192];   // 32 KB
    __shared__ __attribute__((aligned(16))) short Bs[2][8192];   // 32 KB
    const int pm = blockIdx.x & 1, pn = blockIdx.x >> 1;
    const int bm = pm * 64, bn = pn * BN;
    const int tid = threadIdx.x, lane = tid & 63;
    const int wr = (tid >> 6) >> 1, wc = (tid >> 6) & 1;

    f32x4 zero4 = {0.f, 0.f, 0.f, 0.f};
    f32x4 acc[2][2];
    #pragma unroll
    for (int i = 0; i < 2; i++)
        #pragma unroll
        for (int j = 0; j < 2; j++) acc[i][j] = zero4;

#define STAGE_GK(buf, k0) {                                                     \
    const short* Ap; int Al, kk0;                                               \
    if ((k0) < ENC_) { Ap = ctxbuf; Al = ENC_; kk0 = (k0); }                    \
    else             { Ap = hcur;   Al = H_;   kk0 = (k0) - ENC_; }             \
    _Pragma("unroll")                                                           \
    for (int i = 0; i < 4; i++) {                                               \
        int wb  = i * 256 + (tid & ~63);                                        \
        int row = (wb >> 4) + (lane >> 4);                                      \
        int sl  = lane & 15;                                                    \
        gload_lds16(Ap + (size_t)(bm + row) * Al + kk0                          \
                    + ((sl ^ (row & 15)) << 3), &As[buf][wb * 8]);              \
    }                                                                           \
    _Pragma("unroll")                                                           \
    for (int i = 0; i < 4; i++) {                                               \
        int wb  = i * 256 + (tid & ~63);                                        \
        int row = (wb >> 4) + (lane >> 4);                                      \
        int sl  = lane & 15;                                                    \
        gload_lds16(Wcat + (size_t)(bn + row) * XK_ + E_ + (k0)                 \
                    + ((sl ^ (row & 15)) << 3), &Bs[buf][wb * 8]);              \
    } }

    STAGE_GK(0, 0);
    __syncthreads();
    int cur = 0;
    for (int k0 = 0; k0 < GK_; k0 += 128) {
        if (k0 + 128 < GK_) STAGE_GK(cur ^ 1, k0 + 128);
        #pragma unroll
        for (int kk = 0; kk < 128; kk += 32) {
            const int kb = (kk >> 3) + (lane >> 4);
            bf16x8 av[2], bv[2];
            #pragma unroll
            for (int i = 0; i < 2; i++) {
                int rr = wr * 32 + i * 16 + (lane & 15);
                av[i] = *(const bf16x8*)&As[cur][rr * 128 + ((kb ^ (rr & 15)) << 3)];
            }
            #pragma unroll
            for (int j = 0; j < 2; j++) {
                int cc = wc * 32 + j * 16 + (lane & 15);
                bv[j] = *(const bf16x8*)&Bs[cur][cc * 128 + ((kb ^ (cc & 15)) << 3)];
            }
            #pragma unroll
            for (int i = 0; i < 2; i++)
                #pragma unroll
                for (int j = 0; j < 2; j++)
                    acc[i][j] = __builtin_amdgcn_mfma_f32_16x16x32_bf16(
                        av[i], bv[j], acc[i][j], 0, 0, 0);
        }
        __syncthreads();
        cur ^= 1;
    }
#undef STAGE_GK

    float* gl = (float*)&As[0][0];    // 64*68*4 = 17408 B (As/Bs dead)
    const int lr = lane >> 4, lc = lane & 15;
    #pragma unroll
    for (int i = 0; i < 2; i++)
        #pragma unroll
        for (int r = 0; r < 4; r++) {
            int row = wr * 32 + i * 16 + lr * 4 + r;         // local 0..63
            #pragma unroll
            for (int j = 0; j < 2; j++) {
                int col = wc * 32 + j * 16 + lc;
                gl[row * 68 + col] = acc[i][j][r]
                    + gpre[(size_t)(bm + row) * (4 * H_) + bn + col];
            }
        }
    __syncthreads();
    #pragma unroll
    for (int q = 0; q < 4; q++) {
        int id    = tid * 4 + q;      // 0..1023
        int row_l = id >> 4;          // local batch row 0..63
        int j     = id & 15;          // local hidden unit
        int row_g = bm + row_l;       // global batch
        int jg    = (bn >> 2) + j;    // global hidden index
        float i_ = sigmoidf_(gl[row_l * 68 + 4 * j + 0]);
        float f_ = sigmoidf_(gl[row_l * 68 + 4 * j + 1]);
        float g_ = tanhf    (gl[row_l * 68 + 4 * j + 2]);
        float o_ = sigmoidf_(gl[row_l * 68 + 4 * j + 3]);
        float cn = f_ * cbuf[row_g * H_ + jg] + i_ * g_;
        float hv = o_ * tanhf(cn);
        hn_t[row_g * H_ + jg] = f2bf(hv);
        bool m = t < lengths[row_g] - 1;
        if (m) cbuf[row_g * H_ + jg] = cn;
        hnxt[row_g * H_ + jg] = m ? f2bf(hv) : hcur[row_g * H_ + jg];
    }
}

// ---------------------------------------------------------------------------
// Fused enc cast + mean; non-temporal fp32 reads (keep enc_bf L3-resident).
// ---------------------------------------------------------------------------
__global__ __launch_bounds__(256) void castenc_mean(const float* __restrict__ enc,
                                                    short* __restrict__ enc_bf,
                                                    short* __restrict__ meanE_bf)
{
    const int b = blockIdx.y;
    const int c0 = blockIdx.x * 1024 + threadIdx.x * 4;
    const f32x4* src = (const f32x4*)(enc + (size_t)b * P_ * ENC_ + c0);
    short* dst = enc_bf + (size_t)b * P_ * ENC_ + c0;
    float s0 = 0, s1 = 0, s2 = 0, s3 = 0;
    for (int p = 0; p < P_; p++) {
        f32x4 f = __builtin_nontemporal_load(src + (size_t)p * (ENC_ / 4));
        bf16x4 v;
        v[0] = f2bf(f[0]); v[1] = f2bf(f[1]); v[2] = f2bf(f[2]); v[3] = f2bf(f[3]);
        *(bf16x4*)(dst + (size_t)p * ENC_) = v;
        s0 += f[0]; s1 += f[1]; s2 += f[2]; s3 += f[3];
    }
    const float inv = 1.0f / (float)P_;
    bf16x4 m;
    m[0] = f2bf(s0 * inv); m[1] = f2bf(s1 * inv);
    m[2] = f2bf(s2 * inv); m[3] = f2bf(s3 * inv);
    *(bf16x4*)(meanE_bf + (size_t)b * ENC_ + c0) = m;
}

// ---------------------------------------------------------------------------
// Mega-prep: all weight casts/concats/biases/embedding in ONE kernel.
// ---------------------------------------------------------------------------
#define PB0 1024               /* W_enc cast: 512*2048          */
#define PB1 (PB0 + 2048)       /* Winit cat : 1024*2048         */
#define PB2 (PB1 + 5000)       /* W_fc cast : 10000*512         */
#define PB3 (PB2 + 1280)       /* Wdf cat   : 2560*512          */
#define PB4 (PB3 + 6144)       /* Wcat      : 2048*3072         */
#define PB5 (PB4 + 1280)       /* emb_all   : 20*128*512        */
#define PB6 (PB5 + 3)          /* bdf 2560                      */
#define PB7 (PB6 + 2)          /* bcat 2048                     */
#define PB8 (PB7 + 1)          /* binit 1024                    */

__device__ __forceinline__ void cast4(const float* __restrict__ in,
                                      short* __restrict__ out, int i4) {
    float4 f = *(const float4*)(in + i4);
    bf16x4 v;
    v[0] = f2bf(f.x); v[1] = f2bf(f.y); v[2] = f2bf(f.z); v[3] = f2bf(f.w);
    *(bf16x4*)(out + i4) = v;
}
__device__ __forceinline__ void cast4p(const float* __restrict__ src,
                                       short* __restrict__ out, int i4) {
    float4 f = *(const float4*)src;
    bf16x4 v;
    v[0] = f2bf(f.x); v[1] = f2bf(f.y); v[2] = f2bf(f.z); v[3] = f2bf(f.w);
    *(bf16x4*)(out + i4) = v;
}

__global__ __launch_bounds__(256) void prep_kernel(
    const float* __restrict__ W_enc,    const float* __restrict__ W_init_h,
    const float* __restrict__ W_init_c, const float* __restrict__ W_fc,
    const float* __restrict__ W_dec,    const float* __restrict__ W_fbeta,
    const float* __restrict__ W_ih,     const float* __restrict__ W_hh,
    const int*   __restrict__ captions, const float* __restrict__ emb_tab,
    const float* __restrict__ b_dec,    const float* __restrict__ b_fbeta,
    const float* __restrict__ b_ih,     const float* __restrict__ b_hh,
    const float* __restrict__ b_init_h, const float* __restrict__ b_init_c,
    short* __restrict__ Wenc_bf,  short* __restrict__ Winit_bf,
    short* __restrict__ Wfc_bf,   short* __restrict__ Wdf_bf,
    short* __restrict__ Wcat_bf,  short* __restrict__ emb_all,
    float* __restrict__ bdf,      float* __restrict__ bcat,
    float* __restrict__ binit)
{
    const int blk = blockIdx.x, tid = threadIdx.x;
    if (blk < PB0) {
        cast4(W_enc, Wenc_bf, blk * 1024 + tid * 4);
    } else if (blk < PB1) {
        int i4 = (blk - PB0) * 1024 + tid * 4;
        int n = i4 >> 11, k = i4 & 2047;
        const float* src = (n < H_) ? W_init_h + (size_t)n * ENC_ + k
                                    : W_init_c + (size_t)(n - H_) * ENC_ + k;
        cast4p(src, Winit_bf, i4);
    } else if (blk < PB2) {
        cast4(W_fc, Wfc_bf, (blk - PB1) * 1024 + tid * 4);
    } else if (blk < PB3) {
        int i4 = (blk - PB2) * 1024 + tid * 4;
        int n = i4 >> 9, k = i4 & 511;
        const float* src = (n < A_) ? W_dec + (size_t)n * H_ + k
                                    : W_fbeta + (size_t)(n - A_) * H_ + k;
        cast4p(src, Wdf_bf, i4);
    } else if (blk < PB4) {
        int i4 = (blk - PB3) * 1024 + tid * 4;
        int n = i4 / XK_, k = i4 - n * XK_;
        int srow = (n & 3) * H_ + (n >> 2);
        const float* src = (k < E_ + ENC_) ? W_ih + (size_t)srow * (E_ + ENC_) + k
                                           : W_hh + (size_t)srow * H_ + (k - (E_ + ENC_));
        cast4p(src, Wcat_bf, i4);
    } else if (blk < PB5) {
        int i4 = (blk - PB4) * 1024 + tid * 4;
        int col = i4 & 511;
        int bt  = i4 >> 9;
        int b   = bt & 127;
        int tt  = bt >> 7;
        int tok = captions[b * (T_ + 1) + tt];
        cast4p(emb_tab + (size_t)tok * E_ + col, emb_all, i4);
    } else if (blk < PB6) {
        int j = (blk - PB5) * 1024 + tid * 4;
        #pragma unroll
        for (int q = 0; q < 4; q++, j++)
            if (j < NDF_) bdf[j] = (j < A_) ? b_dec[j] : b_fbeta[j - A_];
    } else if (blk < PB7) {
        int j = (blk - PB6) * 1024 + tid * 4;
        #pragma unroll
        for (int q = 0; q < 4; q++, j++) {
            int srow = (j & 3) * H_ + (j >> 2);
            bcat[j] = b_ih[srow] + b_hh[srow];
        }
    } else {
        int j = tid * 4;
        #pragma unroll
        for (int q = 0; q < 4; q++, j++)
            binit[j] = (j < H_) ? b_init_h[j] : b_init_c[j - H_];
    }
}

extern "C" void kernel_launch(void* const* d_in, const int* in_sizes, int n_in,
                              void* d_out, int out_size, void* d_ws, size_t ws_size,
                              hipStream_t stream)
{
    const float* enc      = (const float*)d_in[0];
    const int*   captions = (const int*)  d_in[1];
    const int*   lengths  = (const int*)  d_in[2];
    const float* W_enc    = (const float*)d_in[3];
    const float* b_enc    = (const float*)d_in[4];
    const float* W_dec    = (const float*)d_in[5];
    const float* b_dec    = (const float*)d_in[6];
    const float* w_full   = (const float*)d_in[7];
    const float* emb_tab  = (const float*)d_in[9];
    const float* W_ih     = (const float*)d_in[10];
    const float* b_ih     = (const float*)d_in[11];
    const float* W_hh     = (const float*)d_in[12];
    const float* b_hh     = (const float*)d_in[13];
    const float* W_init_h = (const float*)d_in[14];
    const float* b_init_h = (const float*)d_in[15];
    const float* W_init_c = (const float*)d_in[16];
    const float* b_init_c = (const float*)d_in[17];
    const float* W_fbeta  = (const float*)d_in[18];
    const float* b_fbeta  = (const float*)d_in[19];
    const float* W_fc     = (const float*)d_in[20];
    const float* b_fc     = (const float*)d_in[21];
    float* out = (float*)d_out;

    char* ws = (char*)d_ws;
    size_t off = 0;
    auto alloc = [&](size_t bytes) { void* p = ws + off; off += (bytes + 255) & ~(size_t)255; return p; };
    short* enc_bf    = (short*)alloc((size_t)B_ * P_ * ENC_ * 2);
    short* att1_bf   = (short*)alloc((size_t)B_ * P_ * A_ * 2);
    short* Wenc_bf   = (short*)alloc((size_t)A_ * ENC_ * 2);
    short* Winit_bf  = (short*)alloc((size_t)2 * H_ * ENC_ * 2);
    short* Wdf_bf    = (short*)alloc((size_t)NDF_ * H_ * 2);
    short* Wcat_bf   = (short*)alloc((size_t)4 * H_ * XK_ * 2);
    short* Wfc_bf    = (short*)alloc((size_t)V_ * H_ * 2);
    float* bdf       = (float*)alloc(NDF_ * 4);
    float* bcat      = (float*)alloc(4 * H_ * 4);
    float* binit     = (float*)alloc(2 * H_ * 4);
    short* meanE_bf  = (short*)alloc((size_t)B_ * ENC_ * 2);
    float* cbuf      = (float*)alloc((size_t)B_ * H_ * 4);
    short* hbufs     = (short*)alloc((size_t)2 * B_ * H_ * 2);
    short* emb_all   = (short*)alloc((size_t)T_ * B_ * E_ * 2);
    short* hn_all    = (short*)alloc((size_t)T_ * B_ * H_ * 2);
    short* attf_bf   = (short*)alloc((size_t)B_ * NDF_ * 2);
    short* ctxbuf    = (short*)alloc((size_t)B_ * ENC_ * 2);
    float* gates_pre = (float*)alloc((size_t)T_ * B_ * 4 * H_ * 4);  // 21 MB
    (void)ws_size;

    // ---- one-time prep
    prep_kernel<<<PB8, 256, 0, stream>>>(
        W_enc, W_init_h, W_init_c, W_fc, W_dec, W_fbeta, W_ih, W_hh,
        captions, emb_tab, b_dec, b_fbeta, b_ih, b_hh, b_init_h, b_init_c,
        Wenc_bf, Winit_bf, Wfc_bf, Wdf_bf, Wcat_bf, emb_all, bdf, bcat, binit);
    castenc_mean<<<dim3(2, B_), 256, 0, stream>>>(enc, enc_bf, meanE_bf);
    // att1 = enc_bf @ W_enc^T + b_enc -> bf16; BM=64 BK=64 (R11 proven)
    gemm_bf64<<<8 * 8 * ((392 + 7) / 8), 256, 0, stream>>>(
        enc_bf, Wenc_bf, att1_bf, b_enc,
        A_, ENC_, ENC_, ENC_, A_, 392, 8);
    // gates_pre[T*B, 2048] = emb_all @ Wcat[:, :512]^T + bcat  (fp32)
    gemm_bf<<<8 * 32 * (((T_ * B_) / BM + 7) / 8), 256, 0, stream>>>(
        emb_all, Wcat_bf, gates_pre, nullptr, bcat,
        4 * H_, E_, E_, XK_, 4 * H_, (T_ * B_) / BM, 32, 0, nullptr);
    // h0 -> hbufs[0] (bf16) and c0 -> cbuf (fp32) in ONE GEMM (mode 2)
    gemm_bf<<<(2 * H_) / BN, 256, 0, stream>>>(
        meanE_bf, Winit_bf, cbuf, hbufs, binit,
        2 * H_, ENC_, ENC_, ENC_, 0, 1, (2 * H_) / BN, 2, nullptr);

    for (int t = 0; t < T_; t++) {
        short* hcur = hbufs + (size_t)(t & 1) * B_ * H_;
        short* hnxt = hbufs + (size_t)((t & 1) ^ 1) * B_ * H_;
        // attf = h @ [W_dec|W_fbeta]^T + bdf -> bf16; BM=64 BK=128 (4 K-iters)
        gemm_bf64k<<<8 * 40, 256, 0, stream>>>(
            hcur, Wdf_bf, attf_bf, bdf,
            NDF_, H_, H_, H_, NDF_, 2, 40);
        esmctx_kernel<<<dim3(2, B_), 512, 0, stream>>>(
            att1_bf, attf_bf, w_full, enc_bf, ctxbuf, lengths, t);
        gates_lstm128<<<64, 256, 0, stream>>>(
            ctxbuf, hcur, hnxt, Wcat_bf, gates_pre + (size_t)t * B_ * 4 * H_,
            cbuf, hn_all + (size_t)t * B_ * H_, lengths, t);
    }
    // pred: [T*B, V] in one GEMM, remapped to out[b][t][:] with mask
    gemm_bf<<<8 * 157 * (((T_ * B_) / BM + 7) / 8), 256, 0, stream>>>(
        hn_all, Wfc_bf, out, nullptr, b_fc,
        V_, H_, H_, H_, 0, (T_ * B_) / BM, 157, 1, lengths);
}

// Round 14
// 1547.608 us; speedup vs baseline: 2.1924x; 1.0042x over previous
//
#include <hip/hip_runtime.h>
#include <hip/hip_bf16.h>
#include <math.h>

#define B_   128
#define P_   196
#define ENC_ 2048
#define A_   512
#define H_   512
#define E_   512
#define V_   10000
#define T_   20
#define NDF_ 2560   /* [W_dec rows 0..511 | W_fbeta rows 512..2559] */
#define XK_  3072   /* Wcat K: E + ENC + H */
#define GK_  2560   /* per-step gates K: ENC + H (emb part precomputed) */

typedef __attribute__((ext_vector_type(8))) short bf16x8;
typedef __attribute__((ext_vector_type(4))) short bf16x4;
typedef __attribute__((ext_vector_type(2))) short bf16x2;
typedef __attribute__((ext_vector_type(4))) float f32x4;

__device__ __forceinline__ float sigmoidf_(float x) { return 1.0f / (1.0f + expf(-x)); }

__device__ __forceinline__ short f2bf(float f) {
    unsigned u = __float_as_uint(f);
    u += 0x7fffu + ((u >> 16) & 1u);
    return (short)(u >> 16);
}
__device__ __forceinline__ float bf2f(short s) {
    return __uint_as_float(((unsigned)(unsigned short)s) << 16);
}
__device__ __forceinline__ void gload_lds16(const void* g, void* l) {
    __builtin_amdgcn_global_load_lds(
        (const __attribute__((address_space(1))) void*)g,
        (__attribute__((address_space(3))) void*)l, 16, 0, 0);
}

#define BM 128
#define BN 64
#define BK 64

// shared MFMA inner compute: 64-K slab from As/Bs (BK=64, 8-slot XOR swizzle)
#define COMPUTE64(ASP, BSP, CUR)                                               \
    _Pragma("unroll")                                                          \
    for (int kk = 0; kk < BK; kk += 32) {                                      \
        const int kb = (kk >> 3) + (lane >> 4);                                \
        bf16x8 av[4], bv[2];                                                   \
        _Pragma("unroll")                                                      \
        for (int i = 0; i < 4; i++) {                                          \
            int rr = wr * 64 + i * 16 + (lane & 15);                           \
            av[i] = *(const bf16x8*)&(ASP)[(CUR) * (BM * BK) + rr * BK         \
                    + ((kb ^ (rr & 7)) << 3)];                                 \
        }                                                                      \
        _Pragma("unroll")                                                      \
        for (int j = 0; j < 2; j++) {                                          \
            int cc = wc * 32 + j * 16 + (lane & 15);                           \
            bv[j] = *(const bf16x8*)&(BSP)[(CUR) * (BN * BK) + cc * BK         \
                    + ((kb ^ (cc & 7)) << 3)];                                 \
        }                                                                      \
        _Pragma("unroll")                                                      \
        for (int i = 0; i < 4; i++)                                            \
            _Pragma("unroll")                                                  \
            for (int j = 0; j < 2; j++)                                        \
                acc[i][j] = __builtin_amdgcn_mfma_f32_16x16x32_bf16(           \
                    av[i], bv[j], acc[i][j], 0, 0, 0);                         \
    }

// ---------------------------------------------------------------------------
// Generic GEMM (BM=128, BK=64): mode 0 plain, 1 pred-remap, 2 init-split.
// ---------------------------------------------------------------------------
__global__ __launch_bounds__(256) void gemm_bf(
    const short* __restrict__ A, const short* __restrict__ Bw,
    float* __restrict__ Cf, short* __restrict__ Cb,
    const float* __restrict__ bias,
    int N, int K, int lda, int ldb, int ldc,
    int mtiles, int ntiles, int mode,
    const int* __restrict__ lengths)
{
    __shared__ __attribute__((aligned(16))) short As[2][BM * BK];
    __shared__ __attribute__((aligned(16))) short Bs[2][BN * BK];
    int pm, pn;
    if (mtiles == 1) { pm = 0; pn = blockIdx.x; }
    else {
        int xcd = blockIdx.x & 7, s = blockIdx.x >> 3;
        pn = s % ntiles;
        pm = (s / ntiles) * 8 + xcd;
        if (pm >= mtiles) return;
    }
    const int bm = pm * BM, bn = pn * BN;
    const int tid = threadIdx.x, w = tid >> 6, lane = tid & 63;
    const int wr = w >> 1, wc = w & 1;
    const int lr8 = lane >> 3, lk = lane & 7;

    f32x4 zero4 = {0.f, 0.f, 0.f, 0.f};
    f32x4 acc[4][2];
    #pragma unroll
    for (int i = 0; i < 4; i++)
        #pragma unroll
        for (int j = 0; j < 2; j++) acc[i][j] = zero4;

#define STAGE(buf, k0) {                                                        \
    _Pragma("unroll")                                                           \
    for (int i = 0; i < 4; i++) {                                               \
        int row0 = w * 32 + i * 8; int row = row0 + lr8;                        \
        gload_lds16(A + (size_t)(bm + row) * lda + (k0)                         \
                    + ((lk ^ (row & 7)) << 3), &As[buf][row0 * BK]);            \
    }                                                                           \
    _Pragma("unroll")                                                           \
    for (int i = 0; i < 2; i++) {                                               \
        int row0 = w * 16 + i * 8; int row = row0 + lr8;                        \
        int gn = bn + row; if (gn > N - 1) gn = N - 1;                          \
        gload_lds16(Bw + (size_t)gn * ldb + (k0)                                \
                    + ((lk ^ (row & 7)) << 3), &Bs[buf][row0 * BK]);            \
    } }

    STAGE(0, 0);
    __syncthreads();
    int cur = 0;
    for (int k0 = 0; k0 < K; k0 += BK) {
        if (k0 + BK < K) STAGE(cur ^ 1, k0 + BK);
        COMPUTE64(&As[0][0], &Bs[0][0], cur);
        __syncthreads();
        cur ^= 1;
    }
#undef STAGE

    const int lr = lane >> 4, lc = lane & 15;
    #pragma unroll
    for (int i = 0; i < 4; i++) {
        #pragma unroll
        for (int r = 0; r < 4; r++) {
            int row = bm + wr * 64 + i * 16 + lr * 4 + r;
            #pragma unroll
            for (int j = 0; j < 2; j++) {
                int col = bn + wc * 32 + j * 16 + lc;
                if (col >= N) continue;
                float v = acc[i][j][r] + bias[col];
                if (mode == 1) {
                    int tt = row >> 7, bb = row & 127;
                    float rs = (tt < lengths[bb] - 1) ? 1.0f : 0.0f;
                    Cf[(size_t)bb * T_ * V_ + (size_t)tt * V_ + col] = v * rs;
                } else if (mode == 2) {
                    if (col < H_) Cb[(size_t)row * H_ + col] = f2bf(v);
                    else          Cf[(size_t)row * H_ + (col - H_)] = v;
                } else if (Cb) {
                    Cb[(size_t)row * ldc + col] = f2bf(v);
                } else {
                    Cf[(size_t)row * ldc + col] = v;
                }
            }
        }
    }
}

// ---------------------------------------------------------------------------
// BM=64 BK=64 GEMM (att1): 32 KB LDS -> 5 blocks/CU (occupancy-proven, R11).
// ---------------------------------------------------------------------------
__global__ __launch_bounds__(256) void gemm_bf64(
    const short* __restrict__ A, const short* __restrict__ Bw,
    short* __restrict__ Cb, const float* __restrict__ bias,
    int N, int K, int lda, int ldb, int ldc,
    int mtiles, int ntiles)
{
    __shared__ __attribute__((aligned(16))) short As[2][64 * BK];
    __shared__ __attribute__((aligned(16))) short Bs[2][BN * BK];
    int xcd = blockIdx.x & 7, s = blockIdx.x >> 3;
    int pn = s % ntiles;
    int pm = (s / ntiles) * 8 + xcd;
    if (pm >= mtiles) return;
    const int bm = pm * 64, bn = pn * BN;
    const int tid = threadIdx.x, w = tid >> 6, lane = tid & 63;
    const int wr = w >> 1, wc = w & 1;
    const int lr8 = lane >> 3, lk = lane & 7;

    f32x4 zero4 = {0.f, 0.f, 0.f, 0.f};
    f32x4 acc[2][2];
    #pragma unroll
    for (int i = 0; i < 2; i++)
        #pragma unroll
        for (int j = 0; j < 2; j++) acc[i][j] = zero4;

#define STAGE64(buf, k0) {                                                      \
    _Pragma("unroll")                                                           \
    for (int i = 0; i < 2; i++) {                                               \
        int row0 = w * 16 + i * 8; int row = row0 + lr8;                        \
        gload_lds16(A + (size_t)(bm + row) * lda + (k0)                         \
                    + ((lk ^ (row & 7)) << 3), &As[buf][row0 * BK]);            \
    }                                                                           \
    _Pragma("unroll")                                                           \
    for (int i = 0; i < 2; i++) {                                               \
        int row0 = w * 16 + i * 8; int row = row0 + lr8;                        \
        int gn = bn + row; if (gn > N - 1) gn = N - 1;                          \
        gload_lds16(Bw + (size_t)gn * ldb + (k0)                                \
                    + ((lk ^ (row & 7)) << 3), &Bs[buf][row0 * BK]);            \
    } }

    STAGE64(0, 0);
    __syncthreads();
    int cur = 0;
    for (int k0 = 0; k0 < K; k0 += BK) {
        if (k0 + BK < K) STAGE64(cur ^ 1, k0 + BK);
        #pragma unroll
        for (int kk = 0; kk < BK; kk += 32) {
            const int kb = (kk >> 3) + (lane >> 4);
            bf16x8 av[2], bv[2];
            #pragma unroll
            for (int i = 0; i < 2; i++) {
                int rr = wr * 32 + i * 16 + (lane & 15);
                av[i] = *(const bf16x8*)&As[cur][rr * BK + ((kb ^ (rr & 7)) << 3)];
            }
            #pragma unroll
            for (int j = 0; j < 2; j++) {
                int cc = wc * 32 + j * 16 + (lane & 15);
                bv[j] = *(const bf16x8*)&Bs[cur][cc * BK + ((kb ^ (cc & 7)) << 3)];
            }
            #pragma unroll
            for (int i = 0; i < 2; i++)
                #pragma unroll
                for (int j = 0; j < 2; j++)
                    acc[i][j] = __builtin_amdgcn_mfma_f32_16x16x32_bf16(
                        av[i], bv[j], acc[i][j], 0, 0, 0);
        }
        __syncthreads();
        cur ^= 1;
    }
#undef STAGE64

    const int lr = lane >> 4, lc = lane & 15;
    #pragma unroll
    for (int i = 0; i < 2; i++)
        #pragma unroll
        for (int r = 0; r < 4; r++) {
            int row = bm + wr * 32 + i * 16 + lr * 4 + r;
            #pragma unroll
            for (int j = 0; j < 2; j++) {
                int col = bn + wc * 32 + j * 16 + lc;
                if (col < N) Cb[(size_t)row * ldc + col] = f2bf(acc[i][j][r] + bias[col]);
            }
        }
}

// ---------------------------------------------------------------------------
// BM=64 BK=128 GEMM (attf): 4 K-iters for K=512.
// mtiles==2 -> direct decode (spreads over ALL XCDs; old xcd-decode crowded
// all work onto 2 XCDs). 16-slot XOR swizzle.
// ---------------------------------------------------------------------------
__global__ __launch_bounds__(256) void gemm_bf64k(
    const short* __restrict__ A, const short* __restrict__ Bw,
    short* __restrict__ Cb, const float* __restrict__ bias,
    int N, int K, int lda, int ldb, int ldc,
    int mtiles, int ntiles)
{
    __shared__ __attribute__((aligned(16))) short As[2][8192];   // 32 KB
    __shared__ __attribute__((aligned(16))) short Bs[2][8192];   // 32 KB
    int pm, pn;
    if (mtiles == 2) { pm = blockIdx.x & 1; pn = blockIdx.x >> 1; }
    else {
        int xcd = blockIdx.x & 7, s = blockIdx.x >> 3;
        pn = s % ntiles;
        pm = (s / ntiles) * 8 + xcd;
        if (pm >= mtiles) return;
    }
    const int bm = pm * 64, bn = pn * 64;
    const int tid = threadIdx.x, lane = tid & 63;
    const int wr = (tid >> 6) >> 1, wc = (tid >> 6) & 1;

    f32x4 zero4 = {0.f, 0.f, 0.f, 0.f};
    f32x4 acc[2][2];
    #pragma unroll
    for (int i = 0; i < 2; i++)
        #pragma unroll
        for (int j = 0; j < 2; j++) acc[i][j] = zero4;

#define STAGEK(buf, k0) {                                                       \
    _Pragma("unroll")                                                           \
    for (int i = 0; i < 4; i++) {                                               \
        int wb  = i * 256 + (tid & ~63);                                        \
        int row = (wb >> 4) + (lane >> 4);                                      \
        int sl  = lane & 15;                                                    \
        gload_lds16(A + (size_t)(bm + row) * lda + (k0)                         \
                    + ((sl ^ (row & 15)) << 3), &As[buf][wb * 8]);              \
    }                                                                           \
    _Pragma("unroll")                                                           \
    for (int i = 0; i < 4; i++) {                                               \
        int wb  = i * 256 + (tid & ~63);                                        \
        int row = (wb >> 4) + (lane >> 4);                                      \
        int sl  = lane & 15;                                                    \
        int gn  = bn + row; if (gn > N - 1) gn = N - 1;                         \
        gload_lds16(Bw + (size_t)gn * ldb + (k0)                                \
                    + ((sl ^ (row & 15)) << 3), &Bs[buf][wb * 8]);              \
    } }

    STAGEK(0, 0);
    __syncthreads();
    int cur = 0;
    for (int k0 = 0; k0 < K; k0 += 128) {
        if (k0 + 128 < K) STAGEK(cur ^ 1, k0 + 128);
        #pragma unroll
        for (int kk = 0; kk < 128; kk += 32) {
            const int kb = (kk >> 3) + (lane >> 4);       // 0..15
            bf16x8 av[2], bv[2];
            #pragma unroll
            for (int i = 0; i < 2; i++) {
                int rr = wr * 32 + i * 16 + (lane & 15);
                av[i] = *(const bf16x8*)&As[cur][rr * 128 + ((kb ^ (rr & 15)) << 3)];
            }
            #pragma unroll
            for (int j = 0; j < 2; j++) {
                int cc = wc * 32 + j * 16 + (lane & 15);
                bv[j] = *(const bf16x8*)&Bs[cur][cc * 128 + ((kb ^ (cc & 15)) << 3)];
            }
            #pragma unroll
            for (int i = 0; i < 2; i++)
                #pragma unroll
                for (int j = 0; j < 2; j++)
                    acc[i][j] = __builtin_amdgcn_mfma_f32_16x16x32_bf16(
                        av[i], bv[j], acc[i][j], 0, 0, 0);
        }
        __syncthreads();
        cur ^= 1;
    }
#undef STAGEK

    const int lr = lane >> 4, lc = lane & 15;
    #pragma unroll
    for (int i = 0; i < 2; i++)
        #pragma unroll
        for (int r = 0; r < 4; r++) {
            int row = bm + wr * 32 + i * 16 + lr * 4 + r;
            #pragma unroll
            for (int j = 0; j < 2; j++) {
                int col = bn + wc * 32 + j * 16 + lc;
                if (col < N) Cb[(size_t)row * ldc + col] = f2bf(acc[i][j][r] + bias[col]);
            }
        }
}

// ---------------------------------------------------------------------------
// fused e + softmax + context; 1D grid 256, XCD-pair swizzle:
// xcd = id&7, s = id>>3, b = xcd*16 + (s>>1), half = s&1 -> both halves of b
// land on the same XCD (att1[b] 200 KB L2-shared).
// ---------------------------------------------------------------------------
__global__ __launch_bounds__(512) void esmctx_kernel(
    const short* __restrict__ att1_bf, const short* __restrict__ attf_bf,
    const float* __restrict__ wfull, const short* __restrict__ enc_bf,
    short* __restrict__ ctxbuf, const int* __restrict__ lengths, int t)
{
    __shared__ float es[P_];
    __shared__ float red[256];
    __shared__ float al[P_];
    __shared__ float sm, ss;
    const int id = blockIdx.x;
    const int b = (id & 7) * 16 + ((id >> 3) >> 1);
    const int half = (id >> 3) & 1;
    if (t >= lengths[b] - 1) return;
    const int tid = threadIdx.x, wv = tid >> 6, lane = tid & 63;

    float a2v[8], wv8[8];
    {
        bf16x8 a2x = *(const bf16x8*)(attf_bf + (size_t)b * NDF_ + lane * 8);
        #pragma unroll
        for (int i = 0; i < 8; i++) {
            a2v[i] = bf2f(a2x[i]);
            wv8[i] = wfull[lane * 8 + i];
        }
    }
    for (int row = wv; row < P_; row += 8) {
        bf16x8 a1 = *(const bf16x8*)(att1_bf + ((size_t)b * P_ + row) * A_ + lane * 8);
        float s = 0.0f;
        #pragma unroll
        for (int i = 0; i < 8; i++) {
            float v = bf2f(a1[i]) + a2v[i];
            s += fmaxf(v, 0.0f) * wv8[i];
        }
        #pragma unroll
        for (int off = 32; off > 0; off >>= 1) s += __shfl_down(s, off, 64);
        if (lane == 0) es[row] = s;
    }
    __syncthreads();
    float v = (tid < P_) ? es[tid] : -1e30f;
    if (tid < 256) red[tid] = v;
    __syncthreads();
    for (int rs = 128; rs > 0; rs >>= 1) {
        if (tid < rs) red[tid] = fmaxf(red[tid], red[tid + rs]);
        __syncthreads();
    }
    if (tid == 0) sm = red[0];
    __syncthreads();
    float ex = (tid < P_) ? expf(v - sm) : 0.0f;
    if (tid < 256) red[tid] = ex;
    __syncthreads();
    for (int rs = 128; rs > 0; rs >>= 1) {
        if (tid < rs) red[tid] += red[tid + rs];
        __syncthreads();
    }
    if (tid == 0) ss = red[0];
    __syncthreads();
    if (tid < P_) al[tid] = ex / ss;
    __syncthreads();

    const int c0 = half * 1024 + tid * 2;
    const short* eb = enc_bf + (size_t)b * P_ * ENC_ + c0;
    float s0 = 0, s1 = 0;
    for (int p = 0; p < P_; p++) {
        bf16x2 ev = *(const bf16x2*)(eb + (size_t)p * ENC_);
        float a = al[p];
        s0 += a * bf2f(ev[0]); s1 += a * bf2f(ev[1]);
    }
    const short* fb = attf_bf + (size_t)b * NDF_ + A_;
    bf16x2 o;
    o[0] = f2bf(sigmoidf_(bf2f(fb[c0 + 0])) * s0);
    o[1] = f2bf(sigmoidf_(bf2f(fb[c0 + 1])) * s1);
    *(bf16x2*)(ctxbuf + (size_t)b * ENC_ + c0) = o;
}

// ---------------------------------------------------------------------------
// gates GEMM BM=64 BK=128 (20 K-iters) + fused LSTM epilogue. Grid 64.
// XCD-pair swizzle: pm = (id>>3)&1, pn = (id&7)+((id>>4)<<3) -> the two pm
// blocks of a pn share their 327 KB Wcat slice in one XCD's L2.
// ---------------------------------------------------------------------------
__global__ __launch_bounds__(256) void gates_lstm128(
    const short* __restrict__ ctxbuf, const short* __restrict__ hcur,
    short* __restrict__ hnxt,
    const short* __restrict__ Wcat, const float* __restrict__ gpre,
    float* __restrict__ cbuf, short* __restrict__ hn_t,
    const int* __restrict__ lengths, int t)
{
    __shared__ __attribute__((aligned(16))) short As[2][8192];   // 32 KB
    __shared__ __attribute__((aligned(16))) short Bs[2][8192];   // 32 KB
    const int id = blockIdx.x;
    const int pm = (id >> 3) & 1;
    const int pn = (id & 7) + ((id >> 4) << 3);
    const int bm = pm * 64, bn = pn * BN;
    const int tid = threadIdx.x, lane = tid & 63;
    const int wr = (tid >> 6) >> 1, wc = (tid >> 6) & 1;

    f32x4 zero4 = {0.f, 0.f, 0.f, 0.f};
    f32x4 acc[2][2];
    #pragma unroll
    for (int i = 0; i < 2; i++)
        #pragma unroll
        for (int j = 0; j < 2; j++) acc[i][j] = zero4;

#define STAGE_GK(buf, k0) {                                                     \
    const short* Ap; int Al, kk0;                                               \
    if ((k0) < ENC_) { Ap = ctxbuf; Al = ENC_; kk0 = (k0); }                    \
    else             { Ap = hcur;   Al = H_;   kk0 = (k0) - ENC_; }             \
    _Pragma("unroll")                                                           \
    for (int i = 0; i < 4; i++) {                                               \
        int wb  = i * 256 + (tid & ~63);                                        \
        int row = (wb >> 4) + (lane >> 4);                                      \
        int sl  = lane & 15;                                                    \
        gload_lds16(Ap + (size_t)(bm + row) * Al + kk0                          \
                    + ((sl ^ (row & 15)) << 3), &As[buf][wb * 8]);              \
    }                                                                           \
    _Pragma("unroll")                                                           \
    for (int i = 0; i < 4; i++) {                                               \
        int wb  = i * 256 + (tid & ~63);                                        \
        int row = (wb >> 4) + (lane >> 4);                                      \
        int sl  = lane & 15;                                                    \
        gload_lds16(Wcat + (size_t)(bn + row) * XK_ + E_ + (k0)                 \
                    + ((sl ^ (row & 15)) << 3), &Bs[buf][wb * 8]);              \
    } }

    STAGE_GK(0, 0);
    __syncthreads();
    int cur = 0;
    for (int k0 = 0; k0 < GK_; k0 += 128) {
        if (k0 + 128 < GK_) STAGE_GK(cur ^ 1, k0 + 128);
        #pragma unroll
        for (int kk = 0; kk < 128; kk += 32) {
            const int kb = (kk >> 3) + (lane >> 4);
            bf16x8 av[2], bv[2];
            #pragma unroll
            for (int i = 0; i < 2; i++) {
                int rr = wr * 32 + i * 16 + (lane & 15);
                av[i] = *(const bf16x8*)&As[cur][rr * 128 + ((kb ^ (rr & 15)) << 3)];
            }
            #pragma unroll
            for (int j = 0; j < 2; j++) {
                int cc = wc * 32 + j * 16 + (lane & 15);
                bv[j] = *(const bf16x8*)&Bs[cur][cc * 128 + ((kb ^ (cc & 15)) << 3)];
            }
            #pragma unroll
            for (int i = 0; i < 2; i++)
                #pragma unroll
                for (int j = 0; j < 2; j++)
                    acc[i][j] = __builtin_amdgcn_mfma_f32_16x16x32_bf16(
                        av[i], bv[j], acc[i][j], 0, 0, 0);
        }
        __syncthreads();
        cur ^= 1;
    }
#undef STAGE_GK

    float* gl = (float*)&As[0][0];    // 64*68*4 = 17408 B (As/Bs dead)
    const int lr = lane >> 4, lc = lane & 15;
    #pragma unroll
    for (int i = 0; i < 2; i++)
        #pragma unroll
        for (int r = 0; r < 4; r++) {
            int row = wr * 32 + i * 16 + lr * 4 + r;         // local 0..63
            #pragma unroll
            for (int j = 0; j < 2; j++) {
                int col = wc * 32 + j * 16 + lc;
                gl[row * 68 + col] = acc[i][j][r]
                    + gpre[(size_t)(bm + row) * (4 * H_) + bn + col];
            }
        }
    __syncthreads();
    #pragma unroll
    for (int q = 0; q < 4; q++) {
        int idq   = tid * 4 + q;      // 0..1023
        int row_l = idq >> 4;         // local batch row 0..63
        int j     = idq & 15;         // local hidden unit
        int row_g = bm + row_l;       // global batch
        int jg    = (bn >> 2) + j;    // global hidden index
        float i_ = sigmoidf_(gl[row_l * 68 + 4 * j + 0]);
        float f_ = sigmoidf_(gl[row_l * 68 + 4 * j + 1]);
        float g_ = tanhf    (gl[row_l * 68 + 4 * j + 2]);
        float o_ = sigmoidf_(gl[row_l * 68 + 4 * j + 3]);
        float cn = f_ * cbuf[row_g * H_ + jg] + i_ * g_;
        float hv = o_ * tanhf(cn);
        hn_t[row_g * H_ + jg] = f2bf(hv);
        bool m = t < lengths[row_g] - 1;
        if (m) cbuf[row_g * H_ + jg] = cn;
        hnxt[row_g * H_ + jg] = m ? f2bf(hv) : hcur[row_g * H_ + jg];
    }
}

// ---------------------------------------------------------------------------
// Fused enc cast + mean; non-temporal fp32 reads (keep enc_bf L3-resident).
// ---------------------------------------------------------------------------
__global__ __launch_bounds__(256) void castenc_mean(const float* __restrict__ enc,
                                                    short* __restrict__ enc_bf,
                                                    short* __restrict__ meanE_bf)
{
    const int b = blockIdx.y;
    const int c0 = blockIdx.x * 1024 + threadIdx.x * 4;
    const f32x4* src = (const f32x4*)(enc + (size_t)b * P_ * ENC_ + c0);
    short* dst = enc_bf + (size_t)b * P_ * ENC_ + c0;
    float s0 = 0, s1 = 0, s2 = 0, s3 = 0;
    for (int p = 0; p < P_; p++) {
        f32x4 f = __builtin_nontemporal_load(src + (size_t)p * (ENC_ / 4));
        bf16x4 v;
        v[0] = f2bf(f[0]); v[1] = f2bf(f[1]); v[2] = f2bf(f[2]); v[3] = f2bf(f[3]);
        *(bf16x4*)(dst + (size_t)p * ENC_) = v;
        s0 += f[0]; s1 += f[1]; s2 += f[2]; s3 += f[3];
    }
    const float inv = 1.0f / (float)P_;
    bf16x4 m;
    m[0] = f2bf(s0 * inv); m[1] = f2bf(s1 * inv);
    m[2] = f2bf(s2 * inv); m[3] = f2bf(s3 * inv);
    *(bf16x4*)(meanE_bf + (size_t)b * ENC_ + c0) = m;
}

// ---------------------------------------------------------------------------
// Mega-prep: all weight casts/concats/biases/embedding in ONE kernel.
// ---------------------------------------------------------------------------
#define PB0 1024               /* W_enc cast: 512*2048          */
#define PB1 (PB0 + 2048)       /* Winit cat : 1024*2048         */
#define PB2 (PB1 + 5000)       /* W_fc cast : 10000*512         */
#define PB3 (PB2 + 1280)       /* Wdf cat   : 2560*512          */
#define PB4 (PB3 + 6144)       /* Wcat      : 2048*3072         */
#define PB5 (PB4 + 1280)       /* emb_all   : 20*128*512        */
#define PB6 (PB5 + 3)          /* bdf 2560                      */
#define PB7 (PB6 + 2)          /* bcat 2048                     */
#define PB8 (PB7 + 1)          /* binit 1024                    */

__device__ __forceinline__ void cast4(const float* __restrict__ in,
                                      short* __restrict__ out, int i4) {
    float4 f = *(const float4*)(in + i4);
    bf16x4 v;
    v[0] = f2bf(f.x); v[1] = f2bf(f.y); v[2] = f2bf(f.z); v[3] = f2bf(f.w);
    *(bf16x4*)(out + i4) = v;
}
__device__ __forceinline__ void cast4p(const float* __restrict__ src,
                                       short* __restrict__ out, int i4) {
    float4 f = *(const float4*)src;
    bf16x4 v;
    v[0] = f2bf(f.x); v[1] = f2bf(f.y); v[2] = f2bf(f.z); v[3] = f2bf(f.w);
    *(bf16x4*)(out + i4) = v;
}

__global__ __launch_bounds__(256) void prep_kernel(
    const float* __restrict__ W_enc,    const float* __restrict__ W_init_h,
    const float* __restrict__ W_init_c, const float* __restrict__ W_fc,
    const float* __restrict__ W_dec,    const float* __restrict__ W_fbeta,
    const float* __restrict__ W_ih,     const float* __restrict__ W_hh,
    const int*   __restrict__ captions, const float* __restrict__ emb_tab,
    const float* __restrict__ b_dec,    const float* __restrict__ b_fbeta,
    const float* __restrict__ b_ih,     const float* __restrict__ b_hh,
    const float* __restrict__ b_init_h, const float* __restrict__ b_init_c,
    short* __restrict__ Wenc_bf,  short* __restrict__ Winit_bf,
    short* __restrict__ Wfc_bf,   short* __restrict__ Wdf_bf,
    short* __restrict__ Wcat_bf,  short* __restrict__ emb_all,
    float* __restrict__ bdf,      float* __restrict__ bcat,
    float* __restrict__ binit)
{
    const int blk = blockIdx.x, tid = threadIdx.x;
    if (blk < PB0) {
        cast4(W_enc, Wenc_bf, blk * 1024 + tid * 4);
    } else if (blk < PB1) {
        int i4 = (blk - PB0) * 1024 + tid * 4;
        int n = i4 >> 11, k = i4 & 2047;
        const float* src = (n < H_) ? W_init_h + (size_t)n * ENC_ + k
                                    : W_init_c + (size_t)(n - H_) * ENC_ + k;
        cast4p(src, Winit_bf, i4);
    } else if (blk < PB2) {
        cast4(W_fc, Wfc_bf, (blk - PB1) * 1024 + tid * 4);
    } else if (blk < PB3) {
        int i4 = (blk - PB2) * 1024 + tid * 4;
        int n = i4 >> 9, k = i4 & 511;
        const float* src = (n < A_) ? W_dec + (size_t)n * H_ + k
                                    : W_fbeta + (size_t)(n - A_) * H_ + k;
        cast4p(src, Wdf_bf, i4);
    } else if (blk < PB4) {
        int i4 = (blk - PB3) * 1024 + tid * 4;
        int n = i4 / XK_, k = i4 - n * XK_;
        int srow = (n & 3) * H_ + (n >> 2);
        const float* src = (k < E_ + ENC_) ? W_ih + (size_t)srow * (E_ + ENC_) + k
                                           : W_hh + (size_t)srow * H_ + (k - (E_ + ENC_));
        cast4p(src, Wcat_bf, i4);
    } else if (blk < PB5) {
        int i4 = (blk - PB4) * 1024 + tid * 4;
        int col = i4 & 511;
        int bt  = i4 >> 9;
        int b   = bt & 127;
        int tt  = bt >> 7;
        int tok = captions[b * (T_ + 1) + tt];
        cast4p(emb_tab + (size_t)tok * E_ + col, emb_all, i4);
    } else if (blk < PB6) {
        int j = (blk - PB5) * 1024 + tid * 4;
        #pragma unroll
        for (int q = 0; q < 4; q++, j++)
            if (j < NDF_) bdf[j] = (j < A_) ? b_dec[j] : b_fbeta[j - A_];
    } else if (blk < PB7) {
        int j = (blk - PB6) * 1024 + tid * 4;
        #pragma unroll
        for (int q = 0; q < 4; q++, j++) {
            int srow = (j & 3) * H_ + (j >> 2);
            bcat[j] = b_ih[srow] + b_hh[srow];
        }
    } else {
        int j = tid * 4;
        #pragma unroll
        for (int q = 0; q < 4; q++, j++)
            binit[j] = (j < H_) ? b_init_h[j] : b_init_c[j - H_];
    }
}

extern "C" void kernel_launch(void* const* d_in, const int* in_sizes, int n_in,
                              void* d_out, int out_size, void* d_ws, size_t ws_size,
                              hipStream_t stream)
{
    const float* enc      = (const float*)d_in[0];
    const int*   captions = (const int*)  d_in[1];
    const int*   lengths  = (const int*)  d_in[2];
    const float* W_enc    = (const float*)d_in[3];
    const float* b_enc    = (const float*)d_in[4];
    const float* W_dec    = (const float*)d_in[5];
    const float* b_dec    = (const float*)d_in[6];
    const float* w_full   = (const float*)d_in[7];
    const float* emb_tab  = (const float*)d_in[9];
    const float* W_ih     = (const float*)d_in[10];
    const float* b_ih     = (const float*)d_in[11];
    const float* W_hh     = (const float*)d_in[12];
    const float* b_hh     = (const float*)d_in[13];
    const float* W_init_h = (const float*)d_in[14];
    const float* b_init_h = (const float*)d_in[15];
    const float* W_init_c = (const float*)d_in[16];
    const float* b_init_c = (const float*)d_in[17];
    const float* W_fbeta  = (const float*)d_in[18];
    const float* b_fbeta  = (const float*)d_in[19];
    const float* W_fc     = (const float*)d_in[20];
    const float* b_fc     = (const float*)d_in[21];
    float* out = (float*)d_out;

    char* ws = (char*)d_ws;
    size_t off = 0;
    auto alloc = [&](size_t bytes) { void* p = ws + off; off += (bytes + 255) & ~(size_t)255; return p; };
    short* enc_bf    = (short*)alloc((size_t)B_ * P_ * ENC_ * 2);
    short* att1_bf   = (short*)alloc((size_t)B_ * P_ * A_ * 2);
    short* Wenc_bf   = (short*)alloc((size_t)A_ * ENC_ * 2);
    short* Winit_bf  = (short*)alloc((size_t)2 * H_ * ENC_ * 2);
    short* Wdf_bf    = (short*)alloc((size_t)NDF_ * H_ * 2);
    short* Wcat_bf   = (short*)alloc((size_t)4 * H_ * XK_ * 2);
    short* Wfc_bf    = (short*)alloc((size_t)V_ * H_ * 2);
    float* bdf       = (float*)alloc(NDF_ * 4);
    float* bcat      = (float*)alloc(4 * H_ * 4);
    float* binit     = (float*)alloc(2 * H_ * 4);
    short* meanE_bf  = (short*)alloc((size_t)B_ * ENC_ * 2);
    float* cbuf      = (float*)alloc((size_t)B_ * H_ * 4);
    short* hbufs     = (short*)alloc((size_t)2 * B_ * H_ * 2);
    short* emb_all   = (short*)alloc((size_t)T_ * B_ * E_ * 2);
    short* hn_all    = (short*)alloc((size_t)T_ * B_ * H_ * 2);
    short* attf_bf   = (short*)alloc((size_t)B_ * NDF_ * 2);
    short* ctxbuf    = (short*)alloc((size_t)B_ * ENC_ * 2);
    float* gates_pre = (float*)alloc((size_t)T_ * B_ * 4 * H_ * 4);  // 21 MB
    (void)ws_size;

    // ---- one-time prep
    prep_kernel<<<PB8, 256, 0, stream>>>(
        W_enc, W_init_h, W_init_c, W_fc, W_dec, W_fbeta, W_ih, W_hh,
        captions, emb_tab, b_dec, b_fbeta, b_ih, b_hh, b_init_h, b_init_c,
        Wenc_bf, Winit_bf, Wfc_bf, Wdf_bf, Wcat_bf, emb_all, bdf, bcat, binit);
    castenc_mean<<<dim3(2, B_), 256, 0, stream>>>(enc, enc_bf, meanE_bf);
    // att1 = enc_bf @ W_enc^T + b_enc -> bf16; BM=64 BK=64 (R11 proven)
    gemm_bf64<<<8 * 8 * ((392 + 7) / 8), 256, 0, stream>>>(
        enc_bf, Wenc_bf, att1_bf, b_enc,
        A_, ENC_, ENC_, ENC_, A_, 392, 8);
    // gates_pre[T*B, 2048] = emb_all @ Wcat[:, :512]^T + bcat  (fp32)
    gemm_bf<<<8 * 32 * (((T_ * B_) / BM + 7) / 8), 256, 0, stream>>>(
        emb_all, Wcat_bf, gates_pre, nullptr, bcat,
        4 * H_, E_, E_, XK_, 4 * H_, (T_ * B_) / BM, 32, 0, nullptr);
    // h0 -> hbufs[0] (bf16) and c0 -> cbuf (fp32) in ONE GEMM (mode 2)
    gemm_bf<<<(2 * H_) / BN, 256, 0, stream>>>(
        meanE_bf, Winit_bf, cbuf, hbufs, binit,
        2 * H_, ENC_, ENC_, ENC_, 0, 1, (2 * H_) / BN, 2, nullptr);

    for (int t = 0; t < T_; t++) {
        short* hcur = hbufs + (size_t)(t & 1) * B_ * H_;
        short* hnxt = hbufs + (size_t)((t & 1) ^ 1) * B_ * H_;
        // attf = h @ [W_dec|W_fbeta]^T + bdf -> bf16; BM=64 BK=128, 80 blocks
        // spread over ALL XCDs (direct decode)
        gemm_bf64k<<<80, 256, 0, stream>>>(
            hcur, Wdf_bf, attf_bf, bdf,
            NDF_, H_, H_, H_, NDF_, 2, 40);
        esmctx_kernel<<<256, 512, 0, stream>>>(
            att1_bf, attf_bf, w_full, enc_bf, ctxbuf, lengths, t);
        gates_lstm128<<<64, 256, 0, stream>>>(
            ctxbuf, hcur, hnxt, Wcat_bf, gates_pre + (size_t)t * B_ * 4 * H_,
            cbuf, hn_all + (size_t)t * B_ * H_, lengths, t);
    }
    // pred: [T*B, V] in one GEMM, remapped to out[b][t][:] with mask
    gemm_bf<<<8 * 157 * (((T_ * B_) / BM + 7) / 8), 256, 0, stream>>>(
        hn_all, Wfc_bf, out, nullptr, b_fc,
        V_, H_, H_, H_, 0, (T_ * B_) / BM, 157, 1, lengths);
}